// Round 11
// baseline (378.897 us; speedup 1.0000x reference)
//
#include <hip/hip_runtime.h>
#include <hip/hip_bf16.h>
#include <math.h>

typedef __bf16 bf16_t;
typedef __attribute__((ext_vector_type(8))) __bf16 bf16x8;
typedef __attribute__((ext_vector_type(4))) float f32x4;

#define GAS __attribute__((address_space(1)))
#define LAS __attribute__((address_space(3)))

#define BB 2
#define TT 1024
#define CC 2048
#define HH 6
#define KK 128
#define VV 256
#define KD 768
#define VD 1536
#define NQKV 3072
#define NCAT 4608
#define NC 16     // chunks per sequence
#define CL 64     // chunk length

__device__ __forceinline__ void gload_lds16(const void* g, void* l) {
  __builtin_amdgcn_global_load_lds((const GAS void*)g, (LAS void*)l, 16, 0, 0);
}

// scalar read of swizzled [64][128] bf16 tile element (t, kk)
__device__ __forceinline__ float ksh_get(const bf16_t* ksh, int t, int kk) {
  return (float)*(const bf16_t*)((const char*)ksh + t * 256 +
           ((((kk >> 3) ^ (t & 7)) * 16) + (kk & 7) * 2));
}

// ---------- f32 -> bf16 convert ----------
__global__ void k_cvt_bf16(const float* __restrict__ in, bf16_t* __restrict__ out, int n) {
  int i = (blockIdx.x * blockDim.x + threadIdx.x) * 4;
  if (i + 3 < n) {
    float4 v = *(const float4*)(in + i);
    out[i + 0] = (bf16_t)v.x;
    out[i + 1] = (bf16_t)v.y;
    out[i + 2] = (bf16_t)v.z;
    out[i + 3] = (bf16_t)v.w;
  }
}

// ---------- transpose [Kd,Nd] f32 -> [Nd,Kd] bf16 ----------
__global__ void k_transpose_cvt(const float* __restrict__ in, bf16_t* __restrict__ out,
                                int Kd, int Nd) {
  __shared__ float t[32][33];
  int n0 = blockIdx.x * 32, k0 = blockIdx.y * 32;
  int tx = threadIdx.x, ty = threadIdx.y;
#pragma unroll
  for (int i = 0; i < 32; i += 8)
    t[ty + i][tx] = in[(size_t)(k0 + ty + i) * Nd + n0 + tx];
  __syncthreads();
#pragma unroll
  for (int i = 0; i < 32; i += 8)
    out[(size_t)(n0 + ty + i) * Kd + k0 + tx] = (bf16_t)t[tx][ty + i];
}

// ---------- bf16 MFMA GEMM: C[M,N] = A[M,K] * B^T (B is [N,K]) ----------
__global__ __launch_bounds__(256, 2)
void k_gemm_bt(const bf16_t* __restrict__ A, const bf16_t* __restrict__ B,
               float* __restrict__ C, int M, int N, int K) {
  __shared__ __align__(16) bf16_t As[128 * 32];
  __shared__ __align__(16) bf16_t Bs[128 * 32];
  int tid = threadIdx.x;
  int wave = tid >> 6, lane = tid & 63;
  int wm = wave >> 1, wn = wave & 1;
  int by = blockIdx.y, bx = blockIdx.x;
  const bf16_t* Abase = A + (size_t)by * 128 * K;
  const bf16_t* Bbase = B + (size_t)bx * 128 * K;
  int kc = tid & 3;

  f32x4 acc[4][4];
#pragma unroll
  for (int i = 0; i < 4; ++i)
#pragma unroll
    for (int j = 0; j < 4; ++j) acc[i][j] = (f32x4){0.f, 0.f, 0.f, 0.f};

  for (int k0 = 0; k0 < K; k0 += 32) {
#pragma unroll
    for (int r = 0; r < 2; ++r) {
      int rowe = r * 64 + (tid >> 2);
      const bf16_t* ga = Abase + (size_t)rowe * K + k0 + kc * 8;
      const bf16_t* gb = Bbase + (size_t)rowe * K + k0 + kc * 8;
      gload_lds16(ga, As + (size_t)(r * 256 + wave * 64) * 8);
      gload_lds16(gb, Bs + (size_t)(r * 256 + wave * 64) * 8);
    }
    __syncthreads();
    int kg = lane >> 4, lr = lane & 15;
    bf16x8 af[4], bfv[4];
#pragma unroll
    for (int i = 0; i < 4; ++i) {
      af[i]  = *(const bf16x8*)(As + ((wm * 64 + i * 16 + lr) * 32 + kg * 8));
      bfv[i] = *(const bf16x8*)(Bs + ((wn * 64 + i * 16 + lr) * 32 + kg * 8));
    }
#pragma unroll
    for (int i = 0; i < 4; ++i)
#pragma unroll
      for (int j = 0; j < 4; ++j)
        acc[i][j] = __builtin_amdgcn_mfma_f32_16x16x32_bf16(af[i], bfv[j], acc[i][j], 0, 0, 0);
    __syncthreads();
  }

#pragma unroll
  for (int i = 0; i < 4; ++i) {
    int r0 = by * 128 + wm * 64 + i * 16 + ((lane >> 4) << 2);
#pragma unroll
    for (int j = 0; j < 4; ++j) {
      int c = bx * 128 + wn * 64 + j * 16 + (lane & 15);
      float* Cp = C + (size_t)r0 * N + c;
#pragma unroll
      for (int q = 0; q < 4; ++q) Cp[(size_t)q * N] = acc[i][j][q];
    }
  }
}

// ---------- beta / g ----------
__global__ __launch_bounds__(64)
void k_ab(const float* __restrict__ hidden, const float* __restrict__ Wa,
          const float* __restrict__ Wb, const float* __restrict__ A_log,
          const float* __restrict__ dt_bias, float* __restrict__ g_out,
          float* __restrict__ beta_out) {
  int row = blockIdx.x;
  int lane = threadIdx.x;
  float accA[6] = {0, 0, 0, 0, 0, 0};
  float accB[6] = {0, 0, 0, 0, 0, 0};
  const float* h = hidden + (size_t)row * CC;
  for (int c = lane; c < CC; c += 64) {
    float x = h[c];
    const float* wa = Wa + c * 6;
    const float* wb = Wb + c * 6;
#pragma unroll
    for (int j = 0; j < 6; ++j) {
      accA[j] += x * wa[j];
      accB[j] += x * wb[j];
    }
  }
#pragma unroll
  for (int j = 0; j < 6; ++j) {
    for (int off = 32; off; off >>= 1) {
      accA[j] += __shfl_down(accA[j], off);
      accB[j] += __shfl_down(accB[j], off);
    }
  }
  if (lane == 0) {
#pragma unroll
    for (int j = 0; j < 6; ++j) {
      float a = accA[j] + dt_bias[j];
      float sp = (a > 20.f) ? a : log1pf(expf(a));
      g_out[(size_t)row * 6 + j] = -expf(A_log[j]) * sp;
      beta_out[(size_t)row * 6 + j] = 1.f / (1.f + expf(-accB[j]));
    }
  }
}

// ---------- depthwise causal conv(4) + SiLU (+ optional L2 norm); optional f32/bf16 outs ----------
__global__ void k_conv_silu(const float* __restrict__ pre, int ldpre, int col0,
                            const float* __restrict__ w, float* __restrict__ out,
                            bf16_t* __restrict__ out16, int ld_out, int do_norm) {
  int row = blockIdx.x;     // b*T + t
  int t = row & (TT - 1);
  int h = blockIdx.y;
  int kk = threadIdx.x;
  int perH = blockDim.x;
  int ch = h * perH + kk;
  const float* wp = w + ch * 4;
  float y = 0.f;
#pragma unroll
  for (int i = 0; i < 4; ++i) {
    int tt = t - 3 + i;
    if (tt >= 0) y += wp[i] * pre[(size_t)(row - 3 + i) * ldpre + col0 + ch];
  }
  float s = y / (1.f + expf(-y));
  if (do_norm) {
    float ss = s * s;
#pragma unroll
    for (int off = 32; off; off >>= 1) ss += __shfl_down(ss, off);
    __shared__ float red[2];
    if ((threadIdx.x & 63) == 0) red[threadIdx.x >> 6] = ss;
    __syncthreads();
    float nrm = sqrtf(red[0] + red[1]);
    s = s / (nrm + 1e-6f);
  }
  if (out) out[(size_t)row * ld_out + ch] = s;
  if (out16) out16[(size_t)row * ld_out + ch] = (bf16_t)s;
}

// ============ chunked gated delta rule ============
// Pass 1 (T-matrix form; scratch-free): T = (I+M)^{-1} built by wave 0 with the
// solve columns held in LDS xl[s][c] (65-float row stride: 64 lanes touch 64
// consecutive dwords per step -> conflict-free; M-row reads are wave-uniform
// broadcasts). hipcc provably refuses to promote a 64-float per-thread array
// (R6/R9/R10: scratch chain = 85us), so LDS is the deterministic home.
// Application X = T @ R stays pure register MFMA (verified R10).
__global__ __launch_bounds__(256, 1)
void k_chunk1(const bf16_t* __restrict__ kb16, float* dv,
              const float* __restrict__ gdec, const float* __restrict__ beta,
              bf16_t* __restrict__ Wn16, bf16_t* __restrict__ khatT16,
              float* __restrict__ bcum) {
  __shared__ __align__(16) bf16_t ksh[64 * 128];   // 16KB [t][k] swizzled
  __shared__ __align__(16) float Msf[64 * 68];     // 17KB [t][s] f32 (+4 pad, 16B-aligned rows)
  __shared__ __align__(16) bf16_t Tl[64 * 64];     // 8KB  T = (I+M)^{-1}, bf16, swizzled [t][s]
  __shared__ __align__(16) float xl[64 * 65];      // 16.6KB solve columns [s][c], stride 65
  __shared__ float bc[64], bet[64];

  int tid = threadIdx.x;
  int bh = blockIdx.y, c = blockIdx.x;
  int b = bh / HH, h = bh % HH;
  int r0 = b * TT + c * CL;
  size_t cb = (size_t)bh * NC + c;
  int wq = tid >> 6, l = tid & 63;
  int lr = l & 15, lg = l >> 4;

  // ---- phase A: stage k chunk (pre-XOR'd source -> swizzled LDS), g-cumsum ----
#pragma unroll
  for (int it = 0; it < 4; ++it) {
    int idx = it * 256 + tid;
    int t = idx >> 4, p = idx & 15;
    int kslot = p ^ (t & 7);
    gload_lds16(kb16 + (size_t)(r0 + t) * KD + h * KK + kslot * 8,
                ksh + (size_t)(it * 256 + wq * 64) * 8);
  }
  if (tid < 64) {
    float val = gdec[(size_t)(r0 + tid) * HH + h];
    bet[tid] = beta[(size_t)(r0 + tid) * HH + h];
#pragma unroll
    for (int off = 1; off < 64; off <<= 1) {
      float o = __shfl_up(val, off, 64);
      if (tid >= off) val += o;
    }
    bc[tid] = val;
    bcum[cb * CL + tid] = val;
  }
  __syncthreads();
  float bL = bc[63];

  // ---- phase B: M via MFMA -> Msf f32 ----
  {
    f32x4 pacc[4];
#pragma unroll
    for (int sf = 0; sf < 4; ++sf) pacc[sf] = (f32x4){0.f, 0.f, 0.f, 0.f};
#pragma unroll
    for (int ks_ = 0; ks_ < 4; ++ks_) {
      int trow = wq * 16 + lr;
      bf16x8 aK = *(const bf16x8*)((const char*)ksh + trow * 256 + (((ks_ * 4 + lg) * 16) ^ ((trow & 7) << 4)));
#pragma unroll
      for (int sf = 0; sf < 4; ++sf) {
        int srow = sf * 16 + lr;
        bf16x8 bK = *(const bf16x8*)((const char*)ksh + srow * 256 + (((ks_ * 4 + lg) * 16) ^ ((srow & 7) << 4)));
        pacc[sf] = __builtin_amdgcn_mfma_f32_16x16x32_bf16(aK, bK, pacc[sf], 0, 0, 0);
      }
    }
#pragma unroll
    for (int sf = 0; sf < 4; ++sf)
#pragma unroll
      for (int q = 0; q < 4; ++q) {
        int t = wq * 16 + lg * 4 + q;
        int s = sf * 16 + lr;
        Msf[t * 68 + s] = (s < t) ? bet[t] * __expf(bc[t] - bc[s]) * pacc[sf][q] : 0.f;
      }
  }
  __syncthreads();

  // ---- phase C: wave 0 builds T columns in LDS (conflict-free layout);
  //               waves 1-2 produce khatT16 ----
  if (tid < 64) {
    const int c64 = tid;
#pragma unroll
    for (int s = 0; s < 64; ++s) xl[s * 65 + c64] = (s == c64) ? 1.f : 0.f;
#pragma unroll
    for (int rb = 0; rb < 4; ++rb) {
#pragma unroll
      for (int rr = 0; rr < 16; ++rr) {
        if (rb == 0 && rr == 0) continue;
        const int r = rb * 16 + rr;
        const f32x4* mrow = (const f32x4*)&Msf[r * 68];
        float a0 = 0.f, a1 = 0.f, a2 = 0.f, a3 = 0.f;
        const int n4 = (r + 3) >> 2;   // Msf zeros at/above diag make over-read safe
#pragma unroll
        for (int s4 = 0; s4 < n4; ++s4) {
          f32x4 m = mrow[s4];
          a0 += m[0] * xl[(s4 * 4 + 0) * 65 + c64];
          a1 += m[1] * xl[(s4 * 4 + 1) * 65 + c64];
          a2 += m[2] * xl[(s4 * 4 + 2) * 65 + c64];
          a3 += m[3] * xl[(s4 * 4 + 3) * 65 + c64];
        }
        xl[r * 65 + c64] -= (a0 + a1) + (a2 + a3);
      }
    }
#pragma unroll
    for (int t = 0; t < 64; ++t)
      *(bf16_t*)((char*)Tl + t * 128 + ((c64 * 2) ^ ((t & 7) << 4))) = (bf16_t)xl[t * 65 + c64];
  } else if (tid < 192) {
    int kk = tid - 64;
    bf16_t* kout = khatT16 + cb * (size_t)(KK * CL) + (size_t)kk * CL;
#pragma unroll
    for (int t8 = 0; t8 < 8; ++t8) {
      union { bf16x8 v; bf16_t e[8]; } u;
#pragma unroll
      for (int e = 0; e < 8; ++e) {
        int t = t8 * 8 + e;
        u.e[e] = (bf16_t)(__expf(bL - bc[t]) * ksh_get(ksh, t, kk));
      }
      *(bf16x8*)(kout + t8 * 8) = u.v;
    }
  }
  __syncthreads();

  // ---- phase D: load R frags, X = T @ R all-register MFMA (verified R10) ----
  float bets[2][8], rks[2][8];
#pragma unroll
  for (int p = 0; p < 2; ++p)
#pragma unroll
    for (int e = 0; e < 8; ++e) {
      int s = p * 32 + lg * 8 + e;
      bets[p][e] = bet[s];
      rks[p][e] = bets[p][e] * __expf(bc[s]);
    }

  bf16x8 tfr[4][2];
#pragma unroll
  for (int ti = 0; ti < 4; ++ti) {
    int trow = ti * 16 + lr;
#pragma unroll
    for (int p = 0; p < 2; ++p)
      tfr[ti][p] = *(const bf16x8*)((const char*)Tl + trow * 128 +
                      (((p * 4 + lg) * 16) ^ ((trow & 7) << 4)));
  }

#pragma unroll
  for (int nt = 0; nt < 6; ++nt) {
    int n0 = wq * 96 + nt * 16;
    int n = n0 + lr;
    bool isv = (n0 < 256);
    bf16x8 rfr[2];
    if (isv) {
      const float* dvc = dv + (size_t)r0 * VD + h * VV + n;
#pragma unroll
      for (int p = 0; p < 2; ++p) {
        union { bf16x8 v; bf16_t e[8]; } u;
#pragma unroll
        for (int e = 0; e < 8; ++e) {
          int s = p * 32 + lg * 8 + e;
          u.e[e] = (bf16_t)(bets[p][e] * dvc[(size_t)s * VD]);
        }
        rfr[p] = u.v;
      }
    } else {
      int kk = n - 256;
#pragma unroll
      for (int p = 0; p < 2; ++p) {
        union { bf16x8 v; bf16_t e[8]; } u;
#pragma unroll
        for (int e = 0; e < 8; ++e) {
          int s = p * 32 + lg * 8 + e;
          u.e[e] = (bf16_t)(rks[p][e] * ksh_get(ksh, s, kk));
        }
        rfr[p] = u.v;
      }
    }
#pragma unroll
    for (int ti = 0; ti < 4; ++ti) {
      f32x4 acc = (f32x4){0.f, 0.f, 0.f, 0.f};
#pragma unroll
      for (int p = 0; p < 2; ++p)
        acc = __builtin_amdgcn_mfma_f32_16x16x32_bf16(tfr[ti][p], rfr[p], acc, 0, 0, 0);
      if (isv) {
#pragma unroll
        for (int q = 0; q < 4; ++q) {
          int t = ti * 16 + lg * 4 + q;
          dv[(size_t)(r0 + t) * VD + h * VV + n] = acc[q];
        }
      } else {
        int kk = n - 256;
#pragma unroll
        for (int q = 0; q < 4; ++q) {
          int t = ti * 16 + lg * 4 + q;
          Wn16[(cb * CL + t) * KK + kk] = (bf16_t)(-acc[q]);
        }
      }
    }
  }
}

// Pass 2: MFMA state propagation. Grid (8 vtiles of 32, 12 bh), 256 thr (4 waves).
__global__ __launch_bounds__(256, 1)
void k_chunk2(const float* __restrict__ dv, const bf16_t* __restrict__ Wn16,
              const bf16_t* __restrict__ khatT16, const float* __restrict__ bcum,
              bf16_t* __restrict__ states, bf16_t* __restrict__ Zt) {
  __shared__ __align__(16) bf16_t St[32 * 128];   // [v][k], XOR-swizzled
  __shared__ __align__(16) bf16_t Zl[32 * 64];    // [v][t], XOR-swizzled
  int tid = threadIdx.x;
  int vt = blockIdx.x, bh = blockIdx.y;
  int b = bh / HH, h = bh % HH;
  int wq = tid >> 6, l = tid & 63;
  int lr = l & 15, lg = l >> 4;

  f32x4 acc[2][2];
#pragma unroll
  for (int kf = 0; kf < 2; ++kf)
#pragma unroll
    for (int vf = 0; vf < 2; ++vf) acc[kf][vf] = (f32x4){0.f, 0.f, 0.f, 0.f};

  for (int c = 0; c < NC; ++c) {
    size_t cb = (size_t)bh * NC + c;
    int r0 = b * TT + c * CL;
    float ebL = __expf(bcum[cb * CL + 63]);

#pragma unroll
    for (int kf = 0; kf < 2; ++kf)
#pragma unroll
      for (int vf = 0; vf < 2; ++vf)
#pragma unroll
        for (int q = 0; q < 4; ++q) {
          int k = wq * 32 + kf * 16 + lg * 4 + q;
          int v = vf * 16 + lr;
          *(bf16_t*)((char*)St + v * 256 + ((k * 2) ^ ((v & 7) << 4))) = (bf16_t)acc[kf][vf][q];
        }
    __syncthreads();

#pragma unroll
    for (int it = 0; it < 2; ++it) {
      int idx = tid + it * 256;
      int v = idx >> 4, slot = idx & 15;
      bf16x8 val = *(const bf16x8*)((const char*)St + v * 256 + ((slot * 16) ^ ((v & 7) << 4)));
      *(bf16x8*)(states + ((size_t)cb * 256 + vt * 32 + v) * 128 + slot * 8) = val;
    }

    f32x4 zacc[2];
#pragma unroll
    for (int vf = 0; vf < 2; ++vf)
#pragma unroll
      for (int q = 0; q < 4; ++q) {
        int t = wq * 16 + lg * 4 + q;
        zacc[vf][q] = dv[(size_t)(r0 + t) * VD + h * VV + vt * 32 + vf * 16 + lr];
      }
#pragma unroll
    for (int ks_ = 0; ks_ < 4; ++ks_) {
      bf16x8 aW = *(const bf16x8*)(Wn16 + (cb * CL + wq * 16 + lr) * KK + ks_ * 32 + lg * 8);
#pragma unroll
      for (int vf = 0; vf < 2; ++vf) {
        int v = vf * 16 + lr;
        bf16x8 bS = *(const bf16x8*)((const char*)St + v * 256 + (((ks_ * 32 + lg * 8) * 2) ^ ((v & 7) << 4)));
        zacc[vf] = __builtin_amdgcn_mfma_f32_16x16x32_bf16(aW, bS, zacc[vf], 0, 0, 0);
      }
    }
#pragma unroll
    for (int vf = 0; vf < 2; ++vf)
#pragma unroll
      for (int q = 0; q < 4; ++q) {
        int t = wq * 16 + lg * 4 + q;
        int v = vf * 16 + lr;
        *(bf16_t*)((char*)Zl + v * 128 + ((t * 2) ^ ((v & 7) << 4))) = (bf16_t)zacc[vf][q];
      }
    __syncthreads();

    {
      int v = tid >> 3, slot = tid & 7;
      bf16x8 val = *(const bf16x8*)((const char*)Zl + v * 128 + ((slot * 16) ^ ((v & 7) << 4)));
      *(bf16x8*)(Zt + ((size_t)cb * 256 + vt * 32 + v) * 64 + slot * 8) = val;
    }
#pragma unroll
    for (int kf = 0; kf < 2; ++kf)
#pragma unroll
      for (int vf = 0; vf < 2; ++vf)
#pragma unroll
        for (int q = 0; q < 4; ++q) acc[kf][vf][q] *= ebL;
#pragma unroll
    for (int ts = 0; ts < 2; ++ts) {
      bf16x8 aK[2], bZ[2];
#pragma unroll
      for (int kf = 0; kf < 2; ++kf)
        aK[kf] = *(const bf16x8*)(khatT16 + (cb * KK + wq * 32 + kf * 16 + lr) * CL + ts * 32 + lg * 8);
#pragma unroll
      for (int vf = 0; vf < 2; ++vf) {
        int v = vf * 16 + lr;
        bZ[vf] = *(const bf16x8*)((const char*)Zl + v * 128 + (((ts * 32 + lg * 8) * 2) ^ ((v & 7) << 4)));
      }
#pragma unroll
      for (int kf = 0; kf < 2; ++kf)
#pragma unroll
        for (int vf = 0; vf < 2; ++vf)
          acc[kf][vf] = __builtin_amdgcn_mfma_f32_16x16x32_bf16(aK[kf], bZ[vf], acc[kf][vf], 0, 0, 0);
    }
  }
}

// Pass 3: o = e^{b_t} q^T S0 + P Z (MFMA) + fused gated RMSNorm -> ovd bf16.
__global__ __launch_bounds__(256, 1)
void k_chunk3(const bf16_t* __restrict__ qb16, const bf16_t* __restrict__ kb16,
              const bf16_t* __restrict__ Zt, const bf16_t* __restrict__ states,
              const float* __restrict__ bcum, const float* __restrict__ fgate,
              const float* __restrict__ onorm_w, bf16_t* __restrict__ ovd) {
  __shared__ __align__(16) bf16_t qs[64 * 128];   // [t][k] swizzled via pre-XOR source
  __shared__ __align__(16) bf16_t ksh[64 * 128];
  __shared__ __align__(16) bf16_t Pl[64 * 64];    // [t][s] swizzled
  __shared__ float bcs[64];
  __shared__ float sred[4][64];

  int tid = threadIdx.x;
  int c = blockIdx.x, bh = blockIdx.y;
  int b = bh / HH, h = bh % HH;
  int r0 = b * TT + c * CL;
  size_t cb = (size_t)bh * NC + c;
  int wq = tid >> 6, l = tid & 63;
  int lr = l & 15, lg = l >> 4;

  if (tid < 64) bcs[tid] = bcum[cb * CL + tid];
#pragma unroll
  for (int it = 0; it < 4; ++it) {
    int idx = it * 256 + tid;
    int t = idx >> 4, p = idx & 15;
    int kslot = p ^ (t & 7);
    gload_lds16(qb16 + (size_t)(r0 + t) * KD + h * KK + kslot * 8,
                qs + (size_t)(it * 256 + wq * 64) * 8);
    gload_lds16(kb16 + (size_t)(r0 + t) * KD + h * KK + kslot * 8,
                ksh + (size_t)(it * 256 + wq * 64) * 8);
  }
  __syncthreads();

  f32x4 pacc[4];
#pragma unroll
  for (int sf = 0; sf < 4; ++sf) pacc[sf] = (f32x4){0.f, 0.f, 0.f, 0.f};
#pragma unroll
  for (int ks_ = 0; ks_ < 4; ++ks_) {
    int trow = wq * 16 + lr;
    bf16x8 aQ = *(const bf16x8*)((const char*)qs + trow * 256 + (((ks_ * 4 + lg) * 16) ^ ((trow & 7) << 4)));
#pragma unroll
    for (int sf = 0; sf < 4; ++sf) {
      int srow = sf * 16 + lr;
      bf16x8 bK = *(const bf16x8*)((const char*)ksh + srow * 256 + (((ks_ * 4 + lg) * 16) ^ ((srow & 7) << 4)));
      pacc[sf] = __builtin_amdgcn_mfma_f32_16x16x32_bf16(aQ, bK, pacc[sf], 0, 0, 0);
    }
  }
#pragma unroll
  for (int sf = 0; sf < 4; ++sf)
#pragma unroll
    for (int q = 0; q < 4; ++q) {
      int t = wq * 16 + lg * 4 + q;
      int s = sf * 16 + lr;
      float val = (s <= t) ? pacc[sf][q] * __expf(bcs[t] - bcs[s]) : 0.f;
      *(bf16_t*)((char*)Pl + t * 128 + ((s * 2) ^ ((t & 7) << 4))) = (bf16_t)val;
    }
  __syncthreads();

  f32x4 oacc[4][4];
#pragma unroll
  for (int ti = 0; ti < 4; ++ti)
#pragma unroll
    for (int vj = 0; vj < 4; ++vj) oacc[ti][vj] = (f32x4){0.f, 0.f, 0.f, 0.f};

#pragma unroll
  for (int ks_ = 0; ks_ < 4; ++ks_) {
    bf16x8 aQ[4];
#pragma unroll
    for (int ti = 0; ti < 4; ++ti) {
      int t = ti * 16 + lr;
      union { bf16x8 v; bf16_t e[8]; } u;
      u.v = *(const bf16x8*)((const char*)qs + t * 256 + (((ks_ * 4 + lg) * 16) ^ ((t & 7) << 4)));
      float eb = __expf(bcs[t]);
#pragma unroll
      for (int e = 0; e < 8; ++e) u.e[e] = (bf16_t)((float)u.e[e] * eb);
      aQ[ti] = u.v;
    }
#pragma unroll
    for (int vj = 0; vj < 4; ++vj) {
      int vrow = wq * 64 + vj * 16 + lr;
      bf16x8 bS = *(const bf16x8*)(states + ((size_t)cb * 256 + vrow) * 128 + ks_ * 32 + lg * 8);
#pragma unroll
      for (int ti = 0; ti < 4; ++ti)
        oacc[ti][vj] = __builtin_amdgcn_mfma_f32_16x16x32_bf16(aQ[ti], bS, oacc[ti][vj], 0, 0, 0);
    }
  }
#pragma unroll
  for (int ts = 0; ts < 2; ++ts) {
    bf16x8 aP[4];
#pragma unroll
    for (int ti = 0; ti < 4; ++ti) {
      int t = ti * 16 + lr;
      aP[ti] = *(const bf16x8*)((const char*)Pl + t * 128 + (((ts * 4 + lg) * 16) ^ ((t & 7) << 4)));
    }
#pragma unroll
    for (int vj = 0; vj < 4; ++vj) {
      int vrow = wq * 64 + vj * 16 + lr;
      bf16x8 bZ = *(const bf16x8*)(Zt + ((size_t)cb * 256 + vrow) * 64 + ts * 32 + lg * 8);
#pragma unroll
      for (int ti = 0; ti < 4; ++ti)
        oacc[ti][vj] = __builtin_amdgcn_mfma_f32_16x16x32_bf16(aP[ti], bZ, oacc[ti][vj], 0, 0, 0);
    }
  }

  // ---- fused gated RMSNorm ----
  float sum2[4][4];
#pragma unroll
  for (int ti = 0; ti < 4; ++ti)
#pragma unroll
    for (int q = 0; q < 4; ++q) {
      float s = 0.f;
#pragma unroll
      for (int vj = 0; vj < 4; ++vj) s += oacc[ti][vj][q] * oacc[ti][vj][q];
      sum2[ti][q] = s;
    }
#pragma unroll
  for (int mk = 1; mk < 16; mk <<= 1)
#pragma unroll
    for (int ti = 0; ti < 4; ++ti)
#pragma unroll
      for (int q = 0; q < 4; ++q)
        sum2[ti][q] += __shfl_xor(sum2[ti][q], mk, 64);
  if (lr == 0) {
#pragma unroll
    for (int ti = 0; ti < 4; ++ti)
#pragma unroll
      for (int q = 0; q < 4; ++q)
        sred[wq][ti * 16 + lg * 4 + q] = sum2[ti][q];
  }
  __syncthreads();

  float onv[4];
#pragma unroll
  for (int vj = 0; vj < 4; ++vj) onv[vj] = onorm_w[wq * 64 + vj * 16 + lr];
#pragma unroll
  for (int ti = 0; ti < 4; ++ti)
#pragma unroll
    for (int q = 0; q < 4; ++q) {
      int t = ti * 16 + lg * 4 + q;
      float tot = sred[0][t] + sred[1][t] + sred[2][t] + sred[3][t];
      float rn = rsqrtf(tot * (1.f / VV) + 1e-5f);
#pragma unroll
      for (int vj = 0; vj < 4; ++vj) {
        int v = wq * 64 + vj * 16 + lr;
        float gate = fgate[(size_t)(r0 + t) * VD + h * VV + v];
        float y = oacc[ti][vj][q] * rn * onv[vj] * (gate / (1.f + expf(-gate)));
        ovd[(size_t)(r0 + t) * VD + h * VV + v] = (bf16_t)y;
      }
    }
}

extern "C" void kernel_launch(void* const* d_in, const int* in_sizes, int n_in,
                              void* d_out, int out_size, void* d_ws, size_t ws_size,
                              hipStream_t stream) {
  const float* hidden = (const float*)d_in[0];
  const float* Wq = (const float*)d_in[1];
  const float* Wk = (const float*)d_in[2];
  const float* Wv = (const float*)d_in[3];
  const float* Wa = (const float*)d_in[4];
  const float* Wb = (const float*)d_in[5];
  const float* A_log = (const float*)d_in[6];
  const float* dt_bias = (const float*)d_in[7];
  const float* qconv = (const float*)d_in[8];
  const float* kconv = (const float*)d_in[9];
  const float* vconv = (const float*)d_in[10];
  const float* Wg = (const float*)d_in[11];
  const float* onorm = (const float*)d_in[12];
  const float* Wo = (const float*)d_in[13];
  float* out = (float*)d_out;

  char* ws = (char*)d_ws;
  size_t off = 0;
  auto alloc = [&](size_t bytes) {
    void* p = ws + off;
    off += (bytes + 255) & ~(size_t)255;
    return p;
  };
  const int M = BB * TT;  // 2048
  bf16_t* hbf   = (bf16_t*)alloc((size_t)M * CC * 2);       // aliased by Wn16/khatT16 later
  bf16_t* WcatT = (bf16_t*)alloc((size_t)NCAT * CC * 2);
  bf16_t* WoT   = (bf16_t*)alloc((size_t)CC * VD * 2);
  float*  fqkv  = (float*) alloc((size_t)M * NQKV * 4);     // aliased by states later
  float*  fgate = (float*) alloc((size_t)M * VD * 4);
  float*  kn    = (float*) alloc((size_t)M * KD * 4);       // aliased by Zt later
  float*  vn    = (float*) alloc((size_t)M * VD * 4);       // becomes Dv in pass 1
  float*  gdec  = (float*) alloc((size_t)M * HH * 4);
  float*  beta  = (float*) alloc((size_t)M * HH * 4);
  bf16_t* ovd   = (bf16_t*)alloc((size_t)M * VD * 2);
  bf16_t* qb16  = (bf16_t*)alloc((size_t)M * KD * 2);
  bf16_t* kb16  = (bf16_t*)alloc((size_t)M * KD * 2);
  float*  bcum  = (float*) alloc((size_t)12 * NC * CL * 4);

  // aliases (stream-ordered lifetime separation):
  bf16_t* Wn16    = (bf16_t*)hbf;                     // 12*16*64*128 bf16 = 3.15MB
  bf16_t* khatT16 = Wn16 + (size_t)12 * NC * CL * KK; // +3.15MB (hbf is 8.4MB)
  bf16_t* states  = (bf16_t*)fqkv;                    // 12*16*256*128 bf16 = 12.6MB
  bf16_t* Zt      = (bf16_t*)kn;                      // 12*16*256*64 bf16 = 6.3MB

  // pre-pass
  k_cvt_bf16<<<(M * CC / 4 + 255) / 256, 256, 0, stream>>>(hidden, hbf, M * CC);
  k_transpose_cvt<<<dim3(KD / 32, CC / 32), dim3(32, 8), 0, stream>>>(Wq, WcatT, CC, KD);
  k_transpose_cvt<<<dim3(KD / 32, CC / 32), dim3(32, 8), 0, stream>>>(Wk, WcatT + (size_t)768 * CC, CC, KD);
  k_transpose_cvt<<<dim3(VD / 32, CC / 32), dim3(32, 8), 0, stream>>>(Wv, WcatT + (size_t)1536 * CC, CC, VD);
  k_transpose_cvt<<<dim3(VD / 32, CC / 32), dim3(32, 8), 0, stream>>>(Wg, WcatT + (size_t)3072 * CC, CC, VD);
  k_transpose_cvt<<<dim3(CC / 32, VD / 32), dim3(32, 8), 0, stream>>>(Wo, WoT, VD, CC);

  // projections
  k_gemm_bt<<<dim3(NQKV / 128, M / 128), 256, 0, stream>>>(hbf, WcatT, fqkv, M, NQKV, CC);
  k_gemm_bt<<<dim3(VD / 128, M / 128), 256, 0, stream>>>(hbf, WcatT + (size_t)3072 * CC, fgate, M, VD, CC);

  // beta / g
  k_ab<<<M, 64, 0, stream>>>(hidden, Wa, Wb, A_log, dt_bias, gdec, beta);

  // conv + silu (+norm for q,k)
  k_conv_silu<<<dim3(M, HH), 128, 0, stream>>>(fqkv, NQKV, 0, qconv, nullptr, qb16, KD, 1);
  k_conv_silu<<<dim3(M, HH), 128, 0, stream>>>(fqkv, NQKV, 768, kconv, nullptr, kb16, KD, 1);
  k_conv_silu<<<dim3(M, HH), 256, 0, stream>>>(fqkv, NQKV, 1536, vconv, vn, nullptr, VD, 0);

  // chunked gated delta rule (hbf dead -> Wn16/khatT16; fqkv dead -> states; kn dead -> Zt)
  k_chunk1<<<dim3(NC, 12), 256, 0, stream>>>(kb16, vn, gdec, beta, Wn16, khatT16, bcum);
  k_chunk2<<<dim3(8, 12), 256, 0, stream>>>(vn, Wn16, khatT16, bcum, states, Zt);
  k_chunk3<<<dim3(NC, 12), 256, 0, stream>>>(qb16, kb16, Zt, states, bcum, fgate, onorm, ovd);

  // output projection
  k_gemm_bt<<<dim3(CC / 128, M / 128), 256, 0, stream>>>(ovd, WoT, out, M, CC, VD);
}

// Round 12
// 266.843 us; speedup vs baseline: 1.4199x; 1.4199x over previous
//
#include <hip/hip_runtime.h>
#include <hip/hip_bf16.h>
#include <math.h>

typedef __bf16 bf16_t;
typedef __attribute__((ext_vector_type(8))) __bf16 bf16x8;
typedef __attribute__((ext_vector_type(4))) float f32x4;

#define GAS __attribute__((address_space(1)))
#define LAS __attribute__((address_space(3)))

#define BB 2
#define TT 1024
#define CC 2048
#define HH 6
#define KK 128
#define VV 256
#define KD 768
#define VD 1536
#define NQKV 3072
#define NCAT 4608
#define NC 16     // chunks per sequence
#define CL 64     // chunk length

__device__ __forceinline__ void gload_lds16(const void* g, void* l) {
  __builtin_amdgcn_global_load_lds((const GAS void*)g, (LAS void*)l, 16, 0, 0);
}

// scalar read of swizzled [64][128] bf16 tile element (t, kk)
__device__ __forceinline__ float ksh_get(const bf16_t* ksh, int t, int kk) {
  return (float)*(const bf16_t*)((const char*)ksh + t * 256 +
           ((((kk >> 3) ^ (t & 7)) * 16) + (kk & 7) * 2));
}

// ---------- f32 -> bf16 convert ----------
__global__ void k_cvt_bf16(const float* __restrict__ in, bf16_t* __restrict__ out, int n) {
  int i = (blockIdx.x * blockDim.x + threadIdx.x) * 4;
  if (i + 3 < n) {
    float4 v = *(const float4*)(in + i);
    out[i + 0] = (bf16_t)v.x;
    out[i + 1] = (bf16_t)v.y;
    out[i + 2] = (bf16_t)v.z;
    out[i + 3] = (bf16_t)v.w;
  }
}

// ---------- transpose [Kd,Nd] f32 -> [Nd,Kd] bf16 ----------
__global__ void k_transpose_cvt(const float* __restrict__ in, bf16_t* __restrict__ out,
                                int Kd, int Nd) {
  __shared__ float t[32][33];
  int n0 = blockIdx.x * 32, k0 = blockIdx.y * 32;
  int tx = threadIdx.x, ty = threadIdx.y;
#pragma unroll
  for (int i = 0; i < 32; i += 8)
    t[ty + i][tx] = in[(size_t)(k0 + ty + i) * Nd + n0 + tx];
  __syncthreads();
#pragma unroll
  for (int i = 0; i < 32; i += 8)
    out[(size_t)(n0 + ty + i) * Kd + k0 + tx] = (bf16_t)t[tx][ty + i];
}

// ---------- bf16 MFMA GEMM: C[M,N] = A[M,K] * B^T (B is [N,K]); XCD-swizzled grid ----------
__global__ __launch_bounds__(256, 2)
void k_gemm_bt(const bf16_t* __restrict__ A, const bf16_t* __restrict__ B,
               float* __restrict__ C, int M, int N, int K) {
  __shared__ __align__(16) bf16_t As[128 * 32];
  __shared__ __align__(16) bf16_t Bs[128 * 32];
  int tid = threadIdx.x;
  int wave = tid >> 6, lane = tid & 63;
  int wm = wave >> 1, wn = wave & 1;

  // bijective XCD-aware swizzle (m204): contiguous wgid chunk per XCD
  int gx = gridDim.x;
  int nwg = gx * gridDim.y;
  int lin = blockIdx.y * gx + blockIdx.x;
  int q8 = nwg >> 3, r8 = nwg & 7;
  int xcd = lin & 7, off8 = lin >> 3;
  int wgid = (xcd < r8 ? xcd * (q8 + 1) : r8 * (q8 + 1) + (xcd - r8) * q8) + off8;
  int bx = wgid % gx, by = wgid / gx;

  const bf16_t* Abase = A + (size_t)by * 128 * K;
  const bf16_t* Bbase = B + (size_t)bx * 128 * K;
  int kc = tid & 3;

  f32x4 acc[4][4];
#pragma unroll
  for (int i = 0; i < 4; ++i)
#pragma unroll
    for (int j = 0; j < 4; ++j) acc[i][j] = (f32x4){0.f, 0.f, 0.f, 0.f};

  for (int k0 = 0; k0 < K; k0 += 32) {
#pragma unroll
    for (int r = 0; r < 2; ++r) {
      int rowe = r * 64 + (tid >> 2);
      const bf16_t* ga = Abase + (size_t)rowe * K + k0 + kc * 8;
      const bf16_t* gb = Bbase + (size_t)rowe * K + k0 + kc * 8;
      gload_lds16(ga, As + (size_t)(r * 256 + wave * 64) * 8);
      gload_lds16(gb, Bs + (size_t)(r * 256 + wave * 64) * 8);
    }
    __syncthreads();
    int kg = lane >> 4, lr = lane & 15;
    bf16x8 af[4], bfv[4];
#pragma unroll
    for (int i = 0; i < 4; ++i) {
      af[i]  = *(const bf16x8*)(As + ((wm * 64 + i * 16 + lr) * 32 + kg * 8));
      bfv[i] = *(const bf16x8*)(Bs + ((wn * 64 + i * 16 + lr) * 32 + kg * 8));
    }
#pragma unroll
    for (int i = 0; i < 4; ++i)
#pragma unroll
      for (int j = 0; j < 4; ++j)
        acc[i][j] = __builtin_amdgcn_mfma_f32_16x16x32_bf16(af[i], bfv[j], acc[i][j], 0, 0, 0);
    __syncthreads();
  }

#pragma unroll
  for (int i = 0; i < 4; ++i) {
    int r0 = by * 128 + wm * 64 + i * 16 + ((lane >> 4) << 2);
#pragma unroll
    for (int j = 0; j < 4; ++j) {
      int c = bx * 128 + wn * 64 + j * 16 + (lane & 15);
      float* Cp = C + (size_t)r0 * N + c;
#pragma unroll
      for (int q = 0; q < 4; ++q) Cp[(size_t)q * N] = acc[i][j][q];
    }
  }
}

// ---------- beta / g ----------
__global__ __launch_bounds__(64)
void k_ab(const float* __restrict__ hidden, const float* __restrict__ Wa,
          const float* __restrict__ Wb, const float* __restrict__ A_log,
          const float* __restrict__ dt_bias, float* __restrict__ g_out,
          float* __restrict__ beta_out) {
  int row = blockIdx.x;
  int lane = threadIdx.x;
  float accA[6] = {0, 0, 0, 0, 0, 0};
  float accB[6] = {0, 0, 0, 0, 0, 0};
  const float* h = hidden + (size_t)row * CC;
  for (int c = lane; c < CC; c += 64) {
    float x = h[c];
    const float* wa = Wa + c * 6;
    const float* wb = Wb + c * 6;
#pragma unroll
    for (int j = 0; j < 6; ++j) {
      accA[j] += x * wa[j];
      accB[j] += x * wb[j];
    }
  }
#pragma unroll
  for (int j = 0; j < 6; ++j) {
    for (int off = 32; off; off >>= 1) {
      accA[j] += __shfl_down(accA[j], off);
      accB[j] += __shfl_down(accB[j], off);
    }
  }
  if (lane == 0) {
#pragma unroll
    for (int j = 0; j < 6; ++j) {
      float a = accA[j] + dt_bias[j];
      float sp = (a > 20.f) ? a : log1pf(expf(a));
      g_out[(size_t)row * 6 + j] = -expf(A_log[j]) * sp;
      beta_out[(size_t)row * 6 + j] = 1.f / (1.f + expf(-accB[j]));
    }
  }
}

// ---------- depthwise causal conv(4) + SiLU (+ optional L2 norm); optional f32/bf16 outs ----------
__global__ void k_conv_silu(const float* __restrict__ pre, int ldpre, int col0,
                            const float* __restrict__ w, float* __restrict__ out,
                            bf16_t* __restrict__ out16, int ld_out, int do_norm) {
  int row = blockIdx.x;     // b*T + t
  int t = row & (TT - 1);
  int h = blockIdx.y;
  int kk = threadIdx.x;
  int perH = blockDim.x;
  int ch = h * perH + kk;
  const float* wp = w + ch * 4;
  float y = 0.f;
#pragma unroll
  for (int i = 0; i < 4; ++i) {
    int tt = t - 3 + i;
    if (tt >= 0) y += wp[i] * pre[(size_t)(row - 3 + i) * ldpre + col0 + ch];
  }
  float s = y / (1.f + expf(-y));
  if (do_norm) {
    float ss = s * s;
#pragma unroll
    for (int off = 32; off; off >>= 1) ss += __shfl_down(ss, off);
    __shared__ float red[2];
    if ((threadIdx.x & 63) == 0) red[threadIdx.x >> 6] = ss;
    __syncthreads();
    float nrm = sqrtf(red[0] + red[1]);
    s = s / (nrm + 1e-6f);
  }
  if (out) out[(size_t)row * ld_out + ch] = s;
  if (out16) out16[(size_t)row * ld_out + ch] = (bf16_t)s;
}

// ============ chunked gated delta rule ============
// Pass 1 (R8's UT transform — best measured variant, 59.6us):
//   Mb  = -M (bf16, swizzled [t][s], 0 on/above diag)
//   Tdl = inverses of the 4 diagonal 16x16 blocks (bf16, A-frag layout, K padded to 32 w/ zeros)
//   X_i = T_ii (R_i + sum_{j<i} (-M_ij) X_j)  -- per-wave independent over 96 columns, 0 barriers
__global__ __launch_bounds__(256, 1)
void k_chunk1(const bf16_t* __restrict__ kb16, float* dv,
              const float* __restrict__ gdec, const float* __restrict__ beta,
              bf16_t* __restrict__ Wn16, bf16_t* __restrict__ khatT16,
              float* __restrict__ bcum) {
  __shared__ __align__(16) bf16_t ksh[64 * 128];    // 16KB [t][k] swizzled
  __shared__ __align__(16) bf16_t Mb[64 * 64];      // 8KB  [t][s] = -M, swizzled
  __shared__ __align__(16) bf16_t Tdl[4 * 16 * 32]; // 4KB  diag-block inverses, k:16..31 zero
  __shared__ __align__(16) bf16_t Yb[384 * 32];     // 24KB [n][k] Ytmp (B-frag layout), k:16..31 zero
  __shared__ __align__(16) bf16_t Xall[384 * 64];   // 48KB [n][s] solved X (B-frag layout)
  __shared__ float bc[64], bet[64];

  int tid = threadIdx.x;
  int bh = blockIdx.y, c = blockIdx.x;
  int b = bh / HH, h = bh % HH;
  int r0 = b * TT + c * CL;
  size_t cb = (size_t)bh * NC + c;
  int wq = tid >> 6, l = tid & 63;
  int lr = l & 15, lg = l >> 4;

  // ---- phase A: stage k chunk (pre-XOR'd source -> swizzled LDS), g-cumsum ----
#pragma unroll
  for (int it = 0; it < 4; ++it) {
    int idx = it * 256 + tid;
    int t = idx >> 4, p = idx & 15;
    int kslot = p ^ (t & 7);
    gload_lds16(kb16 + (size_t)(r0 + t) * KD + h * KK + kslot * 8,
                ksh + (size_t)(it * 256 + wq * 64) * 8);
  }
  if (tid < 64) {
    float val = gdec[(size_t)(r0 + tid) * HH + h];
    bet[tid] = beta[(size_t)(r0 + tid) * HH + h];
#pragma unroll
    for (int off = 1; off < 64; off <<= 1) {
      float o = __shfl_up(val, off, 64);
      if (tid >= off) val += o;
    }
    bc[tid] = val;
    bcum[cb * CL + tid] = val;
  }
  __syncthreads();
  float bL = bc[63];

  // ---- phase B: -M via MFMA -> Mb; zero-init Xall/Yb/Tdl ----
  {
    f32x4 z4 = (f32x4){0.f, 0.f, 0.f, 0.f};
#pragma unroll
    for (int i = 0; i < 12; ++i) ((f32x4*)Xall)[i * 256 + tid] = z4;
#pragma unroll
    for (int i = 0; i < 6; ++i) ((f32x4*)Yb)[i * 256 + tid] = z4;
    ((f32x4*)Tdl)[tid] = z4;
  }
  {
    f32x4 pacc[4];
#pragma unroll
    for (int sf = 0; sf < 4; ++sf) pacc[sf] = (f32x4){0.f, 0.f, 0.f, 0.f};
#pragma unroll
    for (int ks_ = 0; ks_ < 4; ++ks_) {
      int trow = wq * 16 + lr;
      bf16x8 aK = *(const bf16x8*)((const char*)ksh + trow * 256 + (((ks_ * 4 + lg) * 16) ^ ((trow & 7) << 4)));
#pragma unroll
      for (int sf = 0; sf < 4; ++sf) {
        int srow = sf * 16 + lr;
        bf16x8 bK = *(const bf16x8*)((const char*)ksh + srow * 256 + (((ks_ * 4 + lg) * 16) ^ ((srow & 7) << 4)));
        pacc[sf] = __builtin_amdgcn_mfma_f32_16x16x32_bf16(aK, bK, pacc[sf], 0, 0, 0);
      }
    }
#pragma unroll
    for (int sf = 0; sf < 4; ++sf)
#pragma unroll
      for (int q = 0; q < 4; ++q) {
        int t = wq * 16 + lg * 4 + q;
        int s = sf * 16 + lr;
        float val = (s < t) ? -bet[t] * __expf(bc[t] - bc[s]) * pacc[sf][q] : 0.f;
        *(bf16_t*)((char*)Mb + t * 128 + ((s * 2) ^ ((t & 7) << 4))) = (bf16_t)val;
      }
  }
  __syncthreads();

  // ---- phase C: diag-block inverses (threads 0..63) || khatT16 (threads 64..191) ----
  if (tid < 64) {
    int d = tid >> 4, cc = tid & 15;
    float x[16];
#pragma unroll
    for (int s = 0; s < 16; ++s) x[s] = (s == cc) ? 1.f : 0.f;
#pragma unroll
    for (int r = 1; r < 16; ++r) {
      float a = 0.f;
#pragma unroll
      for (int s = 0; s < r; ++s) {
        float m = (float)*(const bf16_t*)((const char*)Mb + (16 * d + r) * 128 +
                    (((16 * d + s) * 2) ^ ((r & 7) << 4)));
        a += m * x[s];
      }
      x[r] += a;
    }
#pragma unroll
    for (int r = 0; r < 16; ++r)
      *(bf16_t*)((char*)Tdl + d * 1024 + r * 64 +
          ((((cc >> 3) * 16) ^ ((r & 3) << 4)) + (cc & 7) * 2)) = (bf16_t)x[r];
  } else if (tid < 192) {
    int kk = tid - 64;
    bf16_t* kout = khatT16 + cb * (size_t)(KK * CL) + (size_t)kk * CL;
#pragma unroll
    for (int t8 = 0; t8 < 8; ++t8) {
      union { bf16x8 v; bf16_t e[8]; } u;
#pragma unroll
      for (int e = 0; e < 8; ++e) {
        int t = t8 * 8 + e;
        u.e[e] = (bf16_t)(__expf(bL - bc[t]) * ksh_get(ksh, t, kk));
      }
      *(bf16x8*)(kout + t8 * 8) = u.v;
    }
  }
  __syncthreads();

  // ---- phase D: 4-stage block solve, per-wave independent (no barriers) ----
  const int nbase = wq * 96;
#pragma unroll
  for (int st = 0; st < 4; ++st) {
#pragma unroll
    for (int nt = 0; nt < 6; ++nt) {
      const int n0 = nbase + nt * 16;
      const bool isv = (n0 < 256);
      const int n = n0 + lr;
      f32x4 acc = (f32x4){0.f, 0.f, 0.f, 0.f};
      if (isv) {
#pragma unroll
        for (int q = 0; q < 4; ++q) {
          int t = st * 16 + lg * 4 + q;
          acc[q] = bet[t] * dv[(size_t)(r0 + t) * VD + h * VV + n];
        }
      } else {
        int kk = n - 256;
#pragma unroll
        for (int q = 0; q < 4; ++q) {
          int t = st * 16 + lg * 4 + q;
          acc[q] = bet[t] * __expf(bc[t]) * ksh_get(ksh, t, kk);
        }
      }
      // acc += (-M) X  (K=32 pair-packed; unwritten X regions are zero)
#pragma unroll
      for (int p = 0; p < 2; ++p) {
        if ((p == 0 && st >= 1) || (p == 1 && st == 3)) {
          int arow = st * 16 + lr;
          bf16x8 aM = *(const bf16x8*)((const char*)Mb + arow * 128 +
                         (((p * 4 + lg) * 16) ^ ((arow & 7) << 4)));
          bf16x8 bX = *(const bf16x8*)((const char*)Xall + n * 128 +
                         (((p * 4 + lg) * 16) ^ ((n & 7) << 4)));
          acc = __builtin_amdgcn_mfma_f32_16x16x32_bf16(aM, bX, acc, 0, 0, 0);
        }
      }
      // Ytmp -> Yb (B-frag layout, own rows only)
#pragma unroll
      for (int q = 0; q < 4; ++q) {
        int tq = lg * 4 + q;
        *(bf16_t*)((char*)Yb + n * 64 +
            ((((tq >> 3) * 16) ^ ((n & 3) << 4)) + (tq & 7) * 2)) = (bf16_t)acc[q];
      }
      // X_st = T_st @ Ytmp
      f32x4 acc2 = (f32x4){0.f, 0.f, 0.f, 0.f};
      {
        bf16x8 aT = *(const bf16x8*)((const char*)Tdl + st * 1024 + lr * 64 +
                       ((lg * 16) ^ ((lr & 3) << 4)));
        bf16x8 bY = *(const bf16x8*)((const char*)Yb + n * 64 +
                       ((lg * 16) ^ ((n & 3) << 4)));
        acc2 = __builtin_amdgcn_mfma_f32_16x16x32_bf16(aT, bY, acc2, 0, 0, 0);
      }
      // store X for later stages + final outputs
      if (st < 3) {
#pragma unroll
        for (int q = 0; q < 4; ++q) {
          int s = st * 16 + lg * 4 + q;
          *(bf16_t*)((char*)Xall + n * 128 +
              ((((s >> 3) * 16) ^ ((n & 7) << 4)) + (s & 7) * 2)) = (bf16_t)acc2[q];
        }
      }
      if (isv) {
#pragma unroll
        for (int q = 0; q < 4; ++q) {
          int t = st * 16 + lg * 4 + q;
          dv[(size_t)(r0 + t) * VD + h * VV + n] = acc2[q];
        }
      } else {
        int kk = n - 256;
#pragma unroll
        for (int q = 0; q < 4; ++q) {
          int t = st * 16 + lg * 4 + q;
          Wn16[(cb * CL + t) * KK + kk] = (bf16_t)(-acc2[q]);
        }
      }
    }
  }
}

// Pass 2: MFMA state propagation. Grid (8 vtiles of 32, 12 bh), 256 thr (4 waves).
__global__ __launch_bounds__(256, 1)
void k_chunk2(const float* __restrict__ dv, const bf16_t* __restrict__ Wn16,
              const bf16_t* __restrict__ khatT16, const float* __restrict__ bcum,
              bf16_t* __restrict__ states, bf16_t* __restrict__ Zt) {
  __shared__ __align__(16) bf16_t St[32 * 128];   // [v][k], XOR-swizzled
  __shared__ __align__(16) bf16_t Zl[32 * 64];    // [v][t], XOR-swizzled
  int tid = threadIdx.x;
  int vt = blockIdx.x, bh = blockIdx.y;
  int b = bh / HH, h = bh % HH;
  int wq = tid >> 6, l = tid & 63;
  int lr = l & 15, lg = l >> 4;

  f32x4 acc[2][2];
#pragma unroll
  for (int kf = 0; kf < 2; ++kf)
#pragma unroll
    for (int vf = 0; vf < 2; ++vf) acc[kf][vf] = (f32x4){0.f, 0.f, 0.f, 0.f};

  for (int c = 0; c < NC; ++c) {
    size_t cb = (size_t)bh * NC + c;
    int r0 = b * TT + c * CL;
    float ebL = __expf(bcum[cb * CL + 63]);

#pragma unroll
    for (int kf = 0; kf < 2; ++kf)
#pragma unroll
      for (int vf = 0; vf < 2; ++vf)
#pragma unroll
        for (int q = 0; q < 4; ++q) {
          int k = wq * 32 + kf * 16 + lg * 4 + q;
          int v = vf * 16 + lr;
          *(bf16_t*)((char*)St + v * 256 + ((k * 2) ^ ((v & 7) << 4))) = (bf16_t)acc[kf][vf][q];
        }
    __syncthreads();

#pragma unroll
    for (int it = 0; it < 2; ++it) {
      int idx = tid + it * 256;
      int v = idx >> 4, slot = idx & 15;
      bf16x8 val = *(const bf16x8*)((const char*)St + v * 256 + ((slot * 16) ^ ((v & 7) << 4)));
      *(bf16x8*)(states + ((size_t)cb * 256 + vt * 32 + v) * 128 + slot * 8) = val;
    }

    f32x4 zacc[2];
#pragma unroll
    for (int vf = 0; vf < 2; ++vf)
#pragma unroll
      for (int q = 0; q < 4; ++q) {
        int t = wq * 16 + lg * 4 + q;
        zacc[vf][q] = dv[(size_t)(r0 + t) * VD + h * VV + vt * 32 + vf * 16 + lr];
      }
#pragma unroll
    for (int ks_ = 0; ks_ < 4; ++ks_) {
      bf16x8 aW = *(const bf16x8*)(Wn16 + (cb * CL + wq * 16 + lr) * KK + ks_ * 32 + lg * 8);
#pragma unroll
      for (int vf = 0; vf < 2; ++vf) {
        int v = vf * 16 + lr;
        bf16x8 bS = *(const bf16x8*)((const char*)St + v * 256 + (((ks_ * 32 + lg * 8) * 2) ^ ((v & 7) << 4)));
        zacc[vf] = __builtin_amdgcn_mfma_f32_16x16x32_bf16(aW, bS, zacc[vf], 0, 0, 0);
      }
    }
#pragma unroll
    for (int vf = 0; vf < 2; ++vf)
#pragma unroll
      for (int q = 0; q < 4; ++q) {
        int t = wq * 16 + lg * 4 + q;
        int v = vf * 16 + lr;
        *(bf16_t*)((char*)Zl + v * 128 + ((t * 2) ^ ((v & 7) << 4))) = (bf16_t)zacc[vf][q];
      }
    __syncthreads();

    {
      int v = tid >> 3, slot = tid & 7;
      bf16x8 val = *(const bf16x8*)((const char*)Zl + v * 128 + ((slot * 16) ^ ((v & 7) << 4)));
      *(bf16x8*)(Zt + ((size_t)cb * 256 + vt * 32 + v) * 64 + slot * 8) = val;
    }
#pragma unroll
    for (int kf = 0; kf < 2; ++kf)
#pragma unroll
      for (int vf = 0; vf < 2; ++vf)
#pragma unroll
        for (int q = 0; q < 4; ++q) acc[kf][vf][q] *= ebL;
#pragma unroll
    for (int ts = 0; ts < 2; ++ts) {
      bf16x8 aK[2], bZ[2];
#pragma unroll
      for (int kf = 0; kf < 2; ++kf)
        aK[kf] = *(const bf16x8*)(khatT16 + (cb * KK + wq * 32 + kf * 16 + lr) * CL + ts * 32 + lg * 8);
#pragma unroll
      for (int vf = 0; vf < 2; ++vf) {
        int v = vf * 16 + lr;
        bZ[vf] = *(const bf16x8*)((const char*)Zl + v * 128 + (((ts * 32 + lg * 8) * 2) ^ ((v & 7) << 4)));
      }
#pragma unroll
      for (int kf = 0; kf < 2; ++kf)
#pragma unroll
        for (int vf = 0; vf < 2; ++vf)
          acc[kf][vf] = __builtin_amdgcn_mfma_f32_16x16x32_bf16(aK[kf], bZ[vf], acc[kf][vf], 0, 0, 0);
    }
  }
}

// Pass 3: o = e^{b_t} q^T S0 + P Z (MFMA) + fused gated RMSNorm -> ovd bf16.
// fgate points at the gate column-slice of the fused projection (row stride NCAT).
__global__ __launch_bounds__(256, 1)
void k_chunk3(const bf16_t* __restrict__ qb16, const bf16_t* __restrict__ kb16,
              const bf16_t* __restrict__ Zt, const bf16_t* __restrict__ states,
              const float* __restrict__ bcum, const float* __restrict__ fgate,
              const float* __restrict__ onorm_w, bf16_t* __restrict__ ovd) {
  __shared__ __align__(16) bf16_t qs[64 * 128];   // [t][k] swizzled via pre-XOR source
  __shared__ __align__(16) bf16_t ksh[64 * 128];
  __shared__ __align__(16) bf16_t Pl[64 * 64];    // [t][s] swizzled
  __shared__ float bcs[64];
  __shared__ float sred[4][64];

  int tid = threadIdx.x;
  int c = blockIdx.x, bh = blockIdx.y;
  int b = bh / HH, h = bh % HH;
  int r0 = b * TT + c * CL;
  size_t cb = (size_t)bh * NC + c;
  int wq = tid >> 6, l = tid & 63;
  int lr = l & 15, lg = l >> 4;

  if (tid < 64) bcs[tid] = bcum[cb * CL + tid];
#pragma unroll
  for (int it = 0; it < 4; ++it) {
    int idx = it * 256 + tid;
    int t = idx >> 4, p = idx & 15;
    int kslot = p ^ (t & 7);
    gload_lds16(qb16 + (size_t)(r0 + t) * KD + h * KK + kslot * 8,
                qs + (size_t)(it * 256 + wq * 64) * 8);
    gload_lds16(kb16 + (size_t)(r0 + t) * KD + h * KK + kslot * 8,
                ksh + (size_t)(it * 256 + wq * 64) * 8);
  }
  __syncthreads();

  f32x4 pacc[4];
#pragma unroll
  for (int sf = 0; sf < 4; ++sf) pacc[sf] = (f32x4){0.f, 0.f, 0.f, 0.f};
#pragma unroll
  for (int ks_ = 0; ks_ < 4; ++ks_) {
    int trow = wq * 16 + lr;
    bf16x8 aQ = *(const bf16x8*)((const char*)qs + trow * 256 + (((ks_ * 4 + lg) * 16) ^ ((trow & 7) << 4)));
#pragma unroll
    for (int sf = 0; sf < 4; ++sf) {
      int srow = sf * 16 + lr;
      bf16x8 bK = *(const bf16x8*)((const char*)ksh + srow * 256 + (((ks_ * 4 + lg) * 16) ^ ((srow & 7) << 4)));
      pacc[sf] = __builtin_amdgcn_mfma_f32_16x16x32_bf16(aQ, bK, pacc[sf], 0, 0, 0);
    }
  }
#pragma unroll
  for (int sf = 0; sf < 4; ++sf)
#pragma unroll
    for (int q = 0; q < 4; ++q) {
      int t = wq * 16 + lg * 4 + q;
      int s = sf * 16 + lr;
      float val = (s <= t) ? pacc[sf][q] * __expf(bcs[t] - bcs[s]) : 0.f;
      *(bf16_t*)((char*)Pl + t * 128 + ((s * 2) ^ ((t & 7) << 4))) = (bf16_t)val;
    }
  __syncthreads();

  f32x4 oacc[4][4];
#pragma unroll
  for (int ti = 0; ti < 4; ++ti)
#pragma unroll
    for (int vj = 0; vj < 4; ++vj) oacc[ti][vj] = (f32x4){0.f, 0.f, 0.f, 0.f};

#pragma unroll
  for (int ks_ = 0; ks_ < 4; ++ks_) {
    bf16x8 aQ[4];
#pragma unroll
    for (int ti = 0; ti < 4; ++ti) {
      int t = ti * 16 + lr;
      union { bf16x8 v; bf16_t e[8]; } u;
      u.v = *(const bf16x8*)((const char*)qs + t * 256 + (((ks_ * 4 + lg) * 16) ^ ((t & 7) << 4)));
      float eb = __expf(bcs[t]);
#pragma unroll
      for (int e = 0; e < 8; ++e) u.e[e] = (bf16_t)((float)u.e[e] * eb);
      aQ[ti] = u.v;
    }
#pragma unroll
    for (int vj = 0; vj < 4; ++vj) {
      int vrow = wq * 64 + vj * 16 + lr;
      bf16x8 bS = *(const bf16x8*)(states + ((size_t)cb * 256 + vrow) * 128 + ks_ * 32 + lg * 8);
#pragma unroll
      for (int ti = 0; ti < 4; ++ti)
        oacc[ti][vj] = __builtin_amdgcn_mfma_f32_16x16x32_bf16(aQ[ti], bS, oacc[ti][vj], 0, 0, 0);
    }
  }
#pragma unroll
  for (int ts = 0; ts < 2; ++ts) {
    bf16x8 aP[4];
#pragma unroll
    for (int ti = 0; ti < 4; ++ti) {
      int t = ti * 16 + lr;
      aP[ti] = *(const bf16x8*)((const char*)Pl + t * 128 + (((ts * 4 + lg) * 16) ^ ((t & 7) << 4)));
    }
#pragma unroll
    for (int vj = 0; vj < 4; ++vj) {
      int vrow = wq * 64 + vj * 16 + lr;
      bf16x8 bZ = *(const bf16x8*)(Zt + ((size_t)cb * 256 + vrow) * 64 + ts * 32 + lg * 8);
#pragma unroll
      for (int ti = 0; ti < 4; ++ti)
        oacc[ti][vj] = __builtin_amdgcn_mfma_f32_16x16x32_bf16(aP[ti], bZ, oacc[ti][vj], 0, 0, 0);
    }
  }

  // ---- fused gated RMSNorm ----
  float sum2[4][4];
#pragma unroll
  for (int ti = 0; ti < 4; ++ti)
#pragma unroll
    for (int q = 0; q < 4; ++q) {
      float s = 0.f;
#pragma unroll
      for (int vj = 0; vj < 4; ++vj) s += oacc[ti][vj][q] * oacc[ti][vj][q];
      sum2[ti][q] = s;
    }
#pragma unroll
  for (int mk = 1; mk < 16; mk <<= 1)
#pragma unroll
    for (int ti = 0; ti < 4; ++ti)
#pragma unroll
      for (int q = 0; q < 4; ++q)
        sum2[ti][q] += __shfl_xor(sum2[ti][q], mk, 64);
  if (lr == 0) {
#pragma unroll
    for (int ti = 0; ti < 4; ++ti)
#pragma unroll
      for (int q = 0; q < 4; ++q)
        sred[wq][ti * 16 + lg * 4 + q] = sum2[ti][q];
  }
  __syncthreads();

  float onv[4];
#pragma unroll
  for (int vj = 0; vj < 4; ++vj) onv[vj] = onorm_w[wq * 64 + vj * 16 + lr];
#pragma unroll
  for (int ti = 0; ti < 4; ++ti)
#pragma unroll
    for (int q = 0; q < 4; ++q) {
      int t = ti * 16 + lg * 4 + q;
      float tot = sred[0][t] + sred[1][t] + sred[2][t] + sred[3][t];
      float rn = rsqrtf(tot * (1.f / VV) + 1e-5f);
#pragma unroll
      for (int vj = 0; vj < 4; ++vj) {
        int v = wq * 64 + vj * 16 + lr;
        float gate = fgate[(size_t)(r0 + t) * NCAT + h * VV + v];
        float y = oacc[ti][vj][q] * rn * onv[vj] * (gate / (1.f + expf(-gate)));
        ovd[(size_t)(r0 + t) * VD + h * VV + v] = (bf16_t)y;
      }
    }
}

extern "C" void kernel_launch(void* const* d_in, const int* in_sizes, int n_in,
                              void* d_out, int out_size, void* d_ws, size_t ws_size,
                              hipStream_t stream) {
  const float* hidden = (const float*)d_in[0];
  const float* Wq = (const float*)d_in[1];
  const float* Wk = (const float*)d_in[2];
  const float* Wv = (const float*)d_in[3];
  const float* Wa = (const float*)d_in[4];
  const float* Wb = (const float*)d_in[5];
  const float* A_log = (const float*)d_in[6];
  const float* dt_bias = (const float*)d_in[7];
  const float* qconv = (const float*)d_in[8];
  const float* kconv = (const float*)d_in[9];
  const float* vconv = (const float*)d_in[10];
  const float* Wg = (const float*)d_in[11];
  const float* onorm = (const float*)d_in[12];
  const float* Wo = (const float*)d_in[13];
  float* out = (float*)d_out;

  char* ws = (char*)d_ws;
  size_t off = 0;
  auto alloc = [&](size_t bytes) {
    void* p = ws + off;
    off += (bytes + 255) & ~(size_t)255;
    return p;
  };
  const int M = BB * TT;  // 2048
  bf16_t* hbf   = (bf16_t*)alloc((size_t)M * CC * 2);       // aliased by Wn16/khatT16 later
  bf16_t* WcatT = (bf16_t*)alloc((size_t)NCAT * CC * 2);
  bf16_t* WoT   = (bf16_t*)alloc((size_t)CC * VD * 2);
  float*  fall  = (float*) alloc((size_t)M * NCAT * 4);     // fused q|k|v|gate projection
  bf16_t* states = (bf16_t*)alloc((size_t)12 * NC * VV * KK * 2);  // 12.6MB
  float*  kn    = (float*) alloc((size_t)M * KD * 4);       // aliased by Zt later
  float*  vn    = (float*) alloc((size_t)M * VD * 4);       // becomes Dv in pass 1
  float*  gdec  = (float*) alloc((size_t)M * HH * 4);
  float*  beta  = (float*) alloc((size_t)M * HH * 4);
  bf16_t* ovd   = (bf16_t*)alloc((size_t)M * VD * 2);
  bf16_t* qb16  = (bf16_t*)alloc((size_t)M * KD * 2);
  bf16_t* kb16  = (bf16_t*)alloc((size_t)M * KD * 2);
  float*  bcum  = (float*) alloc((size_t)12 * NC * CL * 4);

  // aliases (stream-ordered lifetime separation):
  bf16_t* Wn16    = (bf16_t*)hbf;                     // 12*16*64*128 bf16 = 3.15MB
  bf16_t* khatT16 = Wn16 + (size_t)12 * NC * CL * KK; // +3.15MB (hbf is 8.4MB)
  bf16_t* Zt      = (bf16_t*)kn;                      // 12*16*256*64 bf16 = 6.3MB

  // pre-pass
  k_cvt_bf16<<<(M * CC / 4 + 255) / 256, 256, 0, stream>>>(hidden, hbf, M * CC);
  k_transpose_cvt<<<dim3(KD / 32, CC / 32), dim3(32, 8), 0, stream>>>(Wq, WcatT, CC, KD);
  k_transpose_cvt<<<dim3(KD / 32, CC / 32), dim3(32, 8), 0, stream>>>(Wk, WcatT + (size_t)768 * CC, CC, KD);
  k_transpose_cvt<<<dim3(VD / 32, CC / 32), dim3(32, 8), 0, stream>>>(Wv, WcatT + (size_t)1536 * CC, CC, VD);
  k_transpose_cvt<<<dim3(VD / 32, CC / 32), dim3(32, 8), 0, stream>>>(Wg, WcatT + (size_t)3072 * CC, CC, VD);
  k_transpose_cvt<<<dim3(CC / 32, VD / 32), dim3(32, 8), 0, stream>>>(Wo, WoT, VD, CC);

  // fused projection GEMM: [2048,2048] x [4608,2048]^T -> [2048,4608]
  k_gemm_bt<<<dim3(NCAT / 128, M / 128), 256, 0, stream>>>(hbf, WcatT, fall, M, NCAT, CC);

  // beta / g
  k_ab<<<M, 64, 0, stream>>>(hidden, Wa, Wb, A_log, dt_bias, gdec, beta);

  // conv + silu (+norm for q,k)
  k_conv_silu<<<dim3(M, HH), 128, 0, stream>>>(fall, NCAT, 0, qconv, nullptr, qb16, KD, 1);
  k_conv_silu<<<dim3(M, HH), 128, 0, stream>>>(fall, NCAT, 768, kconv, nullptr, kb16, KD, 1);
  k_conv_silu<<<dim3(M, HH), 256, 0, stream>>>(fall, NCAT, 1536, vconv, vn, nullptr, VD, 0);

  // chunked gated delta rule (hbf dead -> Wn16/khatT16; kn dead -> Zt)
  k_chunk1<<<dim3(NC, 12), 256, 0, stream>>>(kb16, vn, gdec, beta, Wn16, khatT16, bcum);
  k_chunk2<<<dim3(8, 12), 256, 0, stream>>>(vn, Wn16, khatT16, bcum, states, Zt);
  k_chunk3<<<dim3(NC, 12), 256, 0, stream>>>(qb16, kb16, Zt, states, bcum, fall + 3072, onorm, ovd);

  // output projection
  k_gemm_bt<<<dim3(CC / 128, M / 128), 256, 0, stream>>>(ovd, WoT, out, M, CC, VD);
}

// Round 13
// 254.284 us; speedup vs baseline: 1.4901x; 1.0494x over previous
//
#include <hip/hip_runtime.h>
#include <hip/hip_bf16.h>
#include <math.h>

typedef __bf16 bf16_t;
typedef __attribute__((ext_vector_type(8))) __bf16 bf16x8;
typedef __attribute__((ext_vector_type(4))) float f32x4;

#define GAS __attribute__((address_space(1)))
#define LAS __attribute__((address_space(3)))

#define BB 2
#define TT 1024
#define CC 2048
#define HH 6
#define KK 128
#define VV 256
#define KD 768
#define VD 1536
#define NQKV 3072
#define NCAT 4608
#define NC 16     // chunks per sequence
#define CL 64     // chunk length

__device__ __forceinline__ void gload_lds16(const void* g, void* l) {
  __builtin_amdgcn_global_load_lds((const GAS void*)g, (LAS void*)l, 16, 0, 0);
}

// scalar read of swizzled [64][128] bf16 tile element (t, kk)
__device__ __forceinline__ float ksh_get(const bf16_t* ksh, int t, int kk) {
  return (float)*(const bf16_t*)((const char*)ksh + t * 256 +
           ((((kk >> 3) ^ (t & 7)) * 16) + (kk & 7) * 2));
}

// ---------- f32 -> bf16 convert ----------
__global__ void k_cvt_bf16(const float* __restrict__ in, bf16_t* __restrict__ out, int n) {
  int i = (blockIdx.x * blockDim.x + threadIdx.x) * 4;
  if (i + 3 < n) {
    float4 v = *(const float4*)(in + i);
    out[i + 0] = (bf16_t)v.x;
    out[i + 1] = (bf16_t)v.y;
    out[i + 2] = (bf16_t)v.z;
    out[i + 3] = (bf16_t)v.w;
  }
}

// ---------- transpose [Kd,Nd] f32 -> [Nd,Kd] bf16 ----------
__global__ void k_transpose_cvt(const float* __restrict__ in, bf16_t* __restrict__ out,
                                int Kd, int Nd) {
  __shared__ float t[32][33];
  int n0 = blockIdx.x * 32, k0 = blockIdx.y * 32;
  int tx = threadIdx.x, ty = threadIdx.y;
#pragma unroll
  for (int i = 0; i < 32; i += 8)
    t[ty + i][tx] = in[(size_t)(k0 + ty + i) * Nd + n0 + tx];
  __syncthreads();
#pragma unroll
  for (int i = 0; i < 32; i += 8)
    out[(size_t)(n0 + ty + i) * Kd + k0 + tx] = (bf16_t)t[tx][ty + i];
}

// ---------- bf16 MFMA GEMM: C[M,N] = A[M,K] * B^T (B is [N,K]) ----------
// BK=64, XOR-swizzled LDS (slot ^= row&7) via pre-swizzled global source ->
// conflict-free ds_read_b128. XCD-swizzled grid.
__global__ __launch_bounds__(256, 2)
void k_gemm_bt(const bf16_t* __restrict__ A, const bf16_t* __restrict__ B,
               float* __restrict__ C, int M, int N, int K) {
  __shared__ __align__(16) bf16_t As[128 * 64];
  __shared__ __align__(16) bf16_t Bs[128 * 64];
  int tid = threadIdx.x;
  int wave = tid >> 6, lane = tid & 63;
  int wm = wave >> 1, wn = wave & 1;

  // bijective XCD-aware swizzle (m204): contiguous wgid chunk per XCD
  int gx = gridDim.x;
  int nwg = gx * gridDim.y;
  int lin = blockIdx.y * gx + blockIdx.x;
  int q8 = nwg >> 3, r8 = nwg & 7;
  int xcd = lin & 7, off8 = lin >> 3;
  int wgid = (xcd < r8 ? xcd * (q8 + 1) : r8 * (q8 + 1) + (xcd - r8) * q8) + off8;
  int bx = wgid % gx, by = wgid / gx;

  const bf16_t* Abase = A + (size_t)by * 128 * K;
  const bf16_t* Bbase = B + (size_t)bx * 128 * K;
  int srow = tid >> 3, sslot = tid & 7;          // staging: thread -> (row, slot)
  int scol = (sslot ^ (srow & 7)) * 8;           // pre-XOR'd source column

  f32x4 acc[4][4];
#pragma unroll
  for (int i = 0; i < 4; ++i)
#pragma unroll
    for (int j = 0; j < 4; ++j) acc[i][j] = (f32x4){0.f, 0.f, 0.f, 0.f};

  int kg = lane >> 4, lr = lane & 15;

  for (int k0 = 0; k0 < K; k0 += 64) {
#pragma unroll
    for (int it = 0; it < 4; ++it) {
      int row = it * 32 + srow;                  // 32 rows per iteration
      const bf16_t* ga = Abase + (size_t)row * K + k0 + ((sslot ^ (row & 7)) * 8);
      const bf16_t* gb = Bbase + (size_t)row * K + k0 + ((sslot ^ (row & 7)) * 8);
      gload_lds16(ga, As + (size_t)(it * 256 + wave * 64) * 8);
      gload_lds16(gb, Bs + (size_t)(it * 256 + wave * 64) * 8);
    }
    __syncthreads();
#pragma unroll
    for (int ks2 = 0; ks2 < 2; ++ks2) {
      int j = ks2 * 4 + kg;
      bf16x8 af[4], bfv[4];
#pragma unroll
      for (int i = 0; i < 4; ++i) {
        int ra = wm * 64 + i * 16 + lr;
        int rb = wn * 64 + i * 16 + lr;
        af[i]  = *(const bf16x8*)((const char*)As + ra * 128 + ((j ^ (ra & 7)) * 16));
        bfv[i] = *(const bf16x8*)((const char*)Bs + rb * 128 + ((j ^ (rb & 7)) * 16));
      }
#pragma unroll
      for (int i = 0; i < 4; ++i)
#pragma unroll
        for (int jj = 0; jj < 4; ++jj)
          acc[i][jj] = __builtin_amdgcn_mfma_f32_16x16x32_bf16(af[i], bfv[jj], acc[i][jj], 0, 0, 0);
    }
    __syncthreads();
  }

#pragma unroll
  for (int i = 0; i < 4; ++i) {
    int r0 = by * 128 + wm * 64 + i * 16 + ((lane >> 4) << 2);
#pragma unroll
    for (int j = 0; j < 4; ++j) {
      int c = bx * 128 + wn * 64 + j * 16 + (lane & 15);
      float* Cp = C + (size_t)r0 * N + c;
#pragma unroll
      for (int q = 0; q < 4; ++q) Cp[(size_t)q * N] = acc[i][j][q];
    }
  }
}

// ---------- beta / g ----------
__global__ __launch_bounds__(64)
void k_ab(const float* __restrict__ hidden, const float* __restrict__ Wa,
          const float* __restrict__ Wb, const float* __restrict__ A_log,
          const float* __restrict__ dt_bias, float* __restrict__ g_out,
          float* __restrict__ beta_out) {
  int row = blockIdx.x;
  int lane = threadIdx.x;
  float accA[6] = {0, 0, 0, 0, 0, 0};
  float accB[6] = {0, 0, 0, 0, 0, 0};
  const float* h = hidden + (size_t)row * CC;
  for (int c = lane; c < CC; c += 64) {
    float x = h[c];
    const float* wa = Wa + c * 6;
    const float* wb = Wb + c * 6;
#pragma unroll
    for (int j = 0; j < 6; ++j) {
      accA[j] += x * wa[j];
      accB[j] += x * wb[j];
    }
  }
#pragma unroll
  for (int j = 0; j < 6; ++j) {
    for (int off = 32; off; off >>= 1) {
      accA[j] += __shfl_down(accA[j], off);
      accB[j] += __shfl_down(accB[j], off);
    }
  }
  if (lane == 0) {
#pragma unroll
    for (int j = 0; j < 6; ++j) {
      float a = accA[j] + dt_bias[j];
      float sp = (a > 20.f) ? a : log1pf(expf(a));
      g_out[(size_t)row * 6 + j] = -expf(A_log[j]) * sp;
      beta_out[(size_t)row * 6 + j] = 1.f / (1.f + expf(-accB[j]));
    }
  }
}

// ---------- depthwise causal conv(4) + SiLU (+ optional L2 norm); optional f32/bf16 outs ----------
__global__ void k_conv_silu(const float* __restrict__ pre, int ldpre, int col0,
                            const float* __restrict__ w, float* __restrict__ out,
                            bf16_t* __restrict__ out16, int ld_out, int do_norm) {
  int row = blockIdx.x;     // b*T + t
  int t = row & (TT - 1);
  int h = blockIdx.y;
  int kk = threadIdx.x;
  int perH = blockDim.x;
  int ch = h * perH + kk;
  const float* wp = w + ch * 4;
  float y = 0.f;
#pragma unroll
  for (int i = 0; i < 4; ++i) {
    int tt = t - 3 + i;
    if (tt >= 0) y += wp[i] * pre[(size_t)(row - 3 + i) * ldpre + col0 + ch];
  }
  float s = y / (1.f + expf(-y));
  if (do_norm) {
    float ss = s * s;
#pragma unroll
    for (int off = 32; off; off >>= 1) ss += __shfl_down(ss, off);
    __shared__ float red[2];
    if ((threadIdx.x & 63) == 0) red[threadIdx.x >> 6] = ss;
    __syncthreads();
    float nrm = sqrtf(red[0] + red[1]);
    s = s / (nrm + 1e-6f);
  }
  if (out) out[(size_t)row * ld_out + ch] = s;
  if (out16) out16[(size_t)row * ld_out + ch] = (bf16_t)s;
}

// ============ chunked gated delta rule ============
// Pass 1 (R8's UT transform — best measured variant):
__global__ __launch_bounds__(256, 1)
void k_chunk1(const bf16_t* __restrict__ kb16, float* dv,
              const float* __restrict__ gdec, const float* __restrict__ beta,
              bf16_t* __restrict__ Wn16, bf16_t* __restrict__ khatT16,
              float* __restrict__ bcum) {
  __shared__ __align__(16) bf16_t ksh[64 * 128];    // 16KB [t][k] swizzled
  __shared__ __align__(16) bf16_t Mb[64 * 64];      // 8KB  [t][s] = -M, swizzled
  __shared__ __align__(16) bf16_t Tdl[4 * 16 * 32]; // 4KB  diag-block inverses, k:16..31 zero
  __shared__ __align__(16) bf16_t Yb[384 * 32];     // 24KB [n][k] Ytmp (B-frag layout), k:16..31 zero
  __shared__ __align__(16) bf16_t Xall[384 * 64];   // 48KB [n][s] solved X (B-frag layout)
  __shared__ float bc[64], bet[64];

  int tid = threadIdx.x;
  int bh = blockIdx.y, c = blockIdx.x;
  int b = bh / HH, h = bh % HH;
  int r0 = b * TT + c * CL;
  size_t cb = (size_t)bh * NC + c;
  int wq = tid >> 6, l = tid & 63;
  int lr = l & 15, lg = l >> 4;

  // ---- phase A: stage k chunk (pre-XOR'd source -> swizzled LDS), g-cumsum ----
#pragma unroll
  for (int it = 0; it < 4; ++it) {
    int idx = it * 256 + tid;
    int t = idx >> 4, p = idx & 15;
    int kslot = p ^ (t & 7);
    gload_lds16(kb16 + (size_t)(r0 + t) * KD + h * KK + kslot * 8,
                ksh + (size_t)(it * 256 + wq * 64) * 8);
  }
  if (tid < 64) {
    float val = gdec[(size_t)(r0 + tid) * HH + h];
    bet[tid] = beta[(size_t)(r0 + tid) * HH + h];
#pragma unroll
    for (int off = 1; off < 64; off <<= 1) {
      float o = __shfl_up(val, off, 64);
      if (tid >= off) val += o;
    }
    bc[tid] = val;
    bcum[cb * CL + tid] = val;
  }
  __syncthreads();
  float bL = bc[63];

  // ---- phase B: -M via MFMA -> Mb; zero-init Xall/Yb/Tdl ----
  {
    f32x4 z4 = (f32x4){0.f, 0.f, 0.f, 0.f};
#pragma unroll
    for (int i = 0; i < 12; ++i) ((f32x4*)Xall)[i * 256 + tid] = z4;
#pragma unroll
    for (int i = 0; i < 6; ++i) ((f32x4*)Yb)[i * 256 + tid] = z4;
    ((f32x4*)Tdl)[tid] = z4;
  }
  {
    f32x4 pacc[4];
#pragma unroll
    for (int sf = 0; sf < 4; ++sf) pacc[sf] = (f32x4){0.f, 0.f, 0.f, 0.f};
#pragma unroll
    for (int ks_ = 0; ks_ < 4; ++ks_) {
      int trow = wq * 16 + lr;
      bf16x8 aK = *(const bf16x8*)((const char*)ksh + trow * 256 + (((ks_ * 4 + lg) * 16) ^ ((trow & 7) << 4)));
#pragma unroll
      for (int sf = 0; sf < 4; ++sf) {
        int srow = sf * 16 + lr;
        bf16x8 bK = *(const bf16x8*)((const char*)ksh + srow * 256 + (((ks_ * 4 + lg) * 16) ^ ((srow & 7) << 4)));
        pacc[sf] = __builtin_amdgcn_mfma_f32_16x16x32_bf16(aK, bK, pacc[sf], 0, 0, 0);
      }
    }
#pragma unroll
    for (int sf = 0; sf < 4; ++sf)
#pragma unroll
      for (int q = 0; q < 4; ++q) {
        int t = wq * 16 + lg * 4 + q;
        int s = sf * 16 + lr;
        float val = (s < t) ? -bet[t] * __expf(bc[t] - bc[s]) * pacc[sf][q] : 0.f;
        *(bf16_t*)((char*)Mb + t * 128 + ((s * 2) ^ ((t & 7) << 4))) = (bf16_t)val;
      }
  }
  __syncthreads();

  // ---- phase C: diag-block inverses (threads 0..63) || khatT16 (threads 64..191) ----
  if (tid < 64) {
    int d = tid >> 4, cc = tid & 15;
    float x[16];
#pragma unroll
    for (int s = 0; s < 16; ++s) x[s] = (s == cc) ? 1.f : 0.f;
#pragma unroll
    for (int r = 1; r < 16; ++r) {
      float a = 0.f;
#pragma unroll
      for (int s = 0; s < r; ++s) {
        float m = (float)*(const bf16_t*)((const char*)Mb + (16 * d + r) * 128 +
                    (((16 * d + s) * 2) ^ ((r & 7) << 4)));
        a += m * x[s];
      }
      x[r] += a;
    }
#pragma unroll
    for (int r = 0; r < 16; ++r)
      *(bf16_t*)((char*)Tdl + d * 1024 + r * 64 +
          ((((cc >> 3) * 16) ^ ((r & 3) << 4)) + (cc & 7) * 2)) = (bf16_t)x[r];
  } else if (tid < 192) {
    int kk = tid - 64;
    bf16_t* kout = khatT16 + cb * (size_t)(KK * CL) + (size_t)kk * CL;
#pragma unroll
    for (int t8 = 0; t8 < 8; ++t8) {
      union { bf16x8 v; bf16_t e[8]; } u;
#pragma unroll
      for (int e = 0; e < 8; ++e) {
        int t = t8 * 8 + e;
        u.e[e] = (bf16_t)(__expf(bL - bc[t]) * ksh_get(ksh, t, kk));
      }
      *(bf16x8*)(kout + t8 * 8) = u.v;
    }
  }
  __syncthreads();

  // ---- phase D: 4-stage block solve, per-wave independent (no barriers) ----
  const int nbase = wq * 96;
#pragma unroll
  for (int st = 0; st < 4; ++st) {
#pragma unroll
    for (int nt = 0; nt < 6; ++nt) {
      const int n0 = nbase + nt * 16;
      const bool isv = (n0 < 256);
      const int n = n0 + lr;
      f32x4 acc = (f32x4){0.f, 0.f, 0.f, 0.f};
      if (isv) {
#pragma unroll
        for (int q = 0; q < 4; ++q) {
          int t = st * 16 + lg * 4 + q;
          acc[q] = bet[t] * dv[(size_t)(r0 + t) * VD + h * VV + n];
        }
      } else {
        int kk = n - 256;
#pragma unroll
        for (int q = 0; q < 4; ++q) {
          int t = st * 16 + lg * 4 + q;
          acc[q] = bet[t] * __expf(bc[t]) * ksh_get(ksh, t, kk);
        }
      }
      // acc += (-M) X  (K=32 pair-packed; unwritten X regions are zero)
#pragma unroll
      for (int p = 0; p < 2; ++p) {
        if ((p == 0 && st >= 1) || (p == 1 && st == 3)) {
          int arow = st * 16 + lr;
          bf16x8 aM = *(const bf16x8*)((const char*)Mb + arow * 128 +
                         (((p * 4 + lg) * 16) ^ ((arow & 7) << 4)));
          bf16x8 bX = *(const bf16x8*)((const char*)Xall + n * 128 +
                         (((p * 4 + lg) * 16) ^ ((n & 7) << 4)));
          acc = __builtin_amdgcn_mfma_f32_16x16x32_bf16(aM, bX, acc, 0, 0, 0);
        }
      }
      // Ytmp -> Yb (B-frag layout, own rows only)
#pragma unroll
      for (int q = 0; q < 4; ++q) {
        int tq = lg * 4 + q;
        *(bf16_t*)((char*)Yb + n * 64 +
            ((((tq >> 3) * 16) ^ ((n & 3) << 4)) + (tq & 7) * 2)) = (bf16_t)acc[q];
      }
      // X_st = T_st @ Ytmp
      f32x4 acc2 = (f32x4){0.f, 0.f, 0.f, 0.f};
      {
        bf16x8 aT = *(const bf16x8*)((const char*)Tdl + st * 1024 + lr * 64 +
                       ((lg * 16) ^ ((lr & 3) << 4)));
        bf16x8 bY = *(const bf16x8*)((const char*)Yb + n * 64 +
                       ((lg * 16) ^ ((n & 3) << 4)));
        acc2 = __builtin_amdgcn_mfma_f32_16x16x32_bf16(aT, bY, acc2, 0, 0, 0);
      }
      // store X for later stages + final outputs
      if (st < 3) {
#pragma unroll
        for (int q = 0; q < 4; ++q) {
          int s = st * 16 + lg * 4 + q;
          *(bf16_t*)((char*)Xall + n * 128 +
              ((((s >> 3) * 16) ^ ((n & 7) << 4)) + (s & 7) * 2)) = (bf16_t)acc2[q];
        }
      }
      if (isv) {
#pragma unroll
        for (int q = 0; q < 4; ++q) {
          int t = st * 16 + lg * 4 + q;
          dv[(size_t)(r0 + t) * VD + h * VV + n] = acc2[q];
        }
      } else {
        int kk = n - 256;
#pragma unroll
        for (int q = 0; q < 4; ++q) {
          int t = st * 16 + lg * 4 + q;
          Wn16[(cb * CL + t) * KK + kk] = (bf16_t)(-acc2[q]);
        }
      }
    }
  }
}

// Pass 2: MFMA state propagation. Grid (8 vtiles of 32, 12 bh), 256 thr (4 waves).
__global__ __launch_bounds__(256, 1)
void k_chunk2(const float* __restrict__ dv, const bf16_t* __restrict__ Wn16,
              const bf16_t* __restrict__ khatT16, const float* __restrict__ bcum,
              bf16_t* __restrict__ states, bf16_t* __restrict__ Zt) {
  __shared__ __align__(16) bf16_t St[32 * 128];   // [v][k], XOR-swizzled
  __shared__ __align__(16) bf16_t Zl[32 * 64];    // [v][t], XOR-swizzled
  int tid = threadIdx.x;
  int vt = blockIdx.x, bh = blockIdx.y;
  int b = bh / HH, h = bh % HH;
  int wq = tid >> 6, l = tid & 63;
  int lr = l & 15, lg = l >> 4;

  f32x4 acc[2][2];
#pragma unroll
  for (int kf = 0; kf < 2; ++kf)
#pragma unroll
    for (int vf = 0; vf < 2; ++vf) acc[kf][vf] = (f32x4){0.f, 0.f, 0.f, 0.f};

  for (int c = 0; c < NC; ++c) {
    size_t cb = (size_t)bh * NC + c;
    int r0 = b * TT + c * CL;
    float ebL = __expf(bcum[cb * CL + 63]);

#pragma unroll
    for (int kf = 0; kf < 2; ++kf)
#pragma unroll
      for (int vf = 0; vf < 2; ++vf)
#pragma unroll
        for (int q = 0; q < 4; ++q) {
          int k = wq * 32 + kf * 16 + lg * 4 + q;
          int v = vf * 16 + lr;
          *(bf16_t*)((char*)St + v * 256 + ((k * 2) ^ ((v & 7) << 4))) = (bf16_t)acc[kf][vf][q];
        }
    __syncthreads();

#pragma unroll
    for (int it = 0; it < 2; ++it) {
      int idx = tid + it * 256;
      int v = idx >> 4, slot = idx & 15;
      bf16x8 val = *(const bf16x8*)((const char*)St + v * 256 + ((slot * 16) ^ ((v & 7) << 4)));
      *(bf16x8*)(states + ((size_t)cb * 256 + vt * 32 + v) * 128 + slot * 8) = val;
    }

    f32x4 zacc[2];
#pragma unroll
    for (int vf = 0; vf < 2; ++vf)
#pragma unroll
      for (int q = 0; q < 4; ++q) {
        int t = wq * 16 + lg * 4 + q;
        zacc[vf][q] = dv[(size_t)(r0 + t) * VD + h * VV + vt * 32 + vf * 16 + lr];
      }
#pragma unroll
    for (int ks_ = 0; ks_ < 4; ++ks_) {
      bf16x8 aW = *(const bf16x8*)(Wn16 + (cb * CL + wq * 16 + lr) * KK + ks_ * 32 + lg * 8);
#pragma unroll
      for (int vf = 0; vf < 2; ++vf) {
        int v = vf * 16 + lr;
        bf16x8 bS = *(const bf16x8*)((const char*)St + v * 256 + (((ks_ * 32 + lg * 8) * 2) ^ ((v & 7) << 4)));
        zacc[vf] = __builtin_amdgcn_mfma_f32_16x16x32_bf16(aW, bS, zacc[vf], 0, 0, 0);
      }
    }
#pragma unroll
    for (int vf = 0; vf < 2; ++vf)
#pragma unroll
      for (int q = 0; q < 4; ++q) {
        int t = wq * 16 + lg * 4 + q;
        int v = vf * 16 + lr;
        *(bf16_t*)((char*)Zl + v * 128 + ((t * 2) ^ ((v & 7) << 4))) = (bf16_t)zacc[vf][q];
      }
    __syncthreads();

    {
      int v = tid >> 3, slot = tid & 7;
      bf16x8 val = *(const bf16x8*)((const char*)Zl + v * 128 + ((slot * 16) ^ ((v & 7) << 4)));
      *(bf16x8*)(Zt + ((size_t)cb * 256 + vt * 32 + v) * 64 + slot * 8) = val;
    }
#pragma unroll
    for (int kf = 0; kf < 2; ++kf)
#pragma unroll
      for (int vf = 0; vf < 2; ++vf)
#pragma unroll
        for (int q = 0; q < 4; ++q) acc[kf][vf][q] *= ebL;
#pragma unroll
    for (int ts = 0; ts < 2; ++ts) {
      bf16x8 aK[2], bZ[2];
#pragma unroll
      for (int kf = 0; kf < 2; ++kf)
        aK[kf] = *(const bf16x8*)(khatT16 + (cb * KK + wq * 32 + kf * 16 + lr) * CL + ts * 32 + lg * 8);
#pragma unroll
      for (int vf = 0; vf < 2; ++vf) {
        int v = vf * 16 + lr;
        bZ[vf] = *(const bf16x8*)((const char*)Zl + v * 128 + (((ts * 32 + lg * 8) * 2) ^ ((v & 7) << 4)));
      }
#pragma unroll
      for (int kf = 0; kf < 2; ++kf)
#pragma unroll
        for (int vf = 0; vf < 2; ++vf)
          acc[kf][vf] = __builtin_amdgcn_mfma_f32_16x16x32_bf16(aK[kf], bZ[vf], acc[kf][vf], 0, 0, 0);
    }
  }
}

// Pass 3: o = e^{b_t} q^T S0 + P Z (MFMA) + fused gated RMSNorm -> ovd bf16.
// fgate points at the gate column-slice of the fused projection (row stride NCAT).
__global__ __launch_bounds__(256, 1)
void k_chunk3(const bf16_t* __restrict__ qb16, const bf16_t* __restrict__ kb16,
              const bf16_t* __restrict__ Zt, const bf16_t* __restrict__ states,
              const float* __restrict__ bcum, const float* __restrict__ fgate,
              const float* __restrict__ onorm_w, bf16_t* __restrict__ ovd) {
  __shared__ __align__(16) bf16_t qs[64 * 128];   // [t][k] swizzled via pre-XOR source
  __shared__ __align__(16) bf16_t ksh[64 * 128];
  __shared__ __align__(16) bf16_t Pl[64 * 64];    // [t][s] swizzled
  __shared__ float bcs[64];
  __shared__ float sred[4][64];

  int tid = threadIdx.x;
  int c = blockIdx.x, bh = blockIdx.y;
  int b = bh / HH, h = bh % HH;
  int r0 = b * TT + c * CL;
  size_t cb = (size_t)bh * NC + c;
  int wq = tid >> 6, l = tid & 63;
  int lr = l & 15, lg = l >> 4;

  if (tid < 64) bcs[tid] = bcum[cb * CL + tid];
#pragma unroll
  for (int it = 0; it < 4; ++it) {
    int idx = it * 256 + tid;
    int t = idx >> 4, p = idx & 15;
    int kslot = p ^ (t & 7);
    gload_lds16(qb16 + (size_t)(r0 + t) * KD + h * KK + kslot * 8,
                qs + (size_t)(it * 256 + wq * 64) * 8);
    gload_lds16(kb16 + (size_t)(r0 + t) * KD + h * KK + kslot * 8,
                ksh + (size_t)(it * 256 + wq * 64) * 8);
  }
  __syncthreads();

  f32x4 pacc[4];
#pragma unroll
  for (int sf = 0; sf < 4; ++sf) pacc[sf] = (f32x4){0.f, 0.f, 0.f, 0.f};
#pragma unroll
  for (int ks_ = 0; ks_ < 4; ++ks_) {
    int trow = wq * 16 + lr;
    bf16x8 aQ = *(const bf16x8*)((const char*)qs + trow * 256 + (((ks_ * 4 + lg) * 16) ^ ((trow & 7) << 4)));
#pragma unroll
    for (int sf = 0; sf < 4; ++sf) {
      int srow = sf * 16 + lr;
      bf16x8 bK = *(const bf16x8*)((const char*)ksh + srow * 256 + (((ks_ * 4 + lg) * 16) ^ ((srow & 7) << 4)));
      pacc[sf] = __builtin_amdgcn_mfma_f32_16x16x32_bf16(aQ, bK, pacc[sf], 0, 0, 0);
    }
  }
#pragma unroll
  for (int sf = 0; sf < 4; ++sf)
#pragma unroll
    for (int q = 0; q < 4; ++q) {
      int t = wq * 16 + lg * 4 + q;
      int s = sf * 16 + lr;
      float val = (s <= t) ? pacc[sf][q] * __expf(bcs[t] - bcs[s]) : 0.f;
      *(bf16_t*)((char*)Pl + t * 128 + ((s * 2) ^ ((t & 7) << 4))) = (bf16_t)val;
    }
  __syncthreads();

  f32x4 oacc[4][4];
#pragma unroll
  for (int ti = 0; ti < 4; ++ti)
#pragma unroll
    for (int vj = 0; vj < 4; ++vj) oacc[ti][vj] = (f32x4){0.f, 0.f, 0.f, 0.f};

#pragma unroll
  for (int ks_ = 0; ks_ < 4; ++ks_) {
    bf16x8 aQ[4];
#pragma unroll
    for (int ti = 0; ti < 4; ++ti) {
      int t = ti * 16 + lr;
      union { bf16x8 v; bf16_t e[8]; } u;
      u.v = *(const bf16x8*)((const char*)qs + t * 256 + (((ks_ * 4 + lg) * 16) ^ ((t & 7) << 4)));
      float eb = __expf(bcs[t]);
#pragma unroll
      for (int e = 0; e < 8; ++e) u.e[e] = (bf16_t)((float)u.e[e] * eb);
      aQ[ti] = u.v;
    }
#pragma unroll
    for (int vj = 0; vj < 4; ++vj) {
      int vrow = wq * 64 + vj * 16 + lr;
      bf16x8 bS = *(const bf16x8*)(states + ((size_t)cb * 256 + vrow) * 128 + ks_ * 32 + lg * 8);
#pragma unroll
      for (int ti = 0; ti < 4; ++ti)
        oacc[ti][vj] = __builtin_amdgcn_mfma_f32_16x16x32_bf16(aQ[ti], bS, oacc[ti][vj], 0, 0, 0);
    }
  }
#pragma unroll
  for (int ts = 0; ts < 2; ++ts) {
    bf16x8 aP[4];
#pragma unroll
    for (int ti = 0; ti < 4; ++ti) {
      int t = ti * 16 + lr;
      aP[ti] = *(const bf16x8*)((const char*)Pl + t * 128 + (((ts * 4 + lg) * 16) ^ ((t & 7) << 4)));
    }
#pragma unroll
    for (int vj = 0; vj < 4; ++vj) {
      int vrow = wq * 64 + vj * 16 + lr;
      bf16x8 bZ = *(const bf16x8*)(Zt + ((size_t)cb * 256 + vrow) * 64 + ts * 32 + lg * 8);
#pragma unroll
      for (int ti = 0; ti < 4; ++ti)
        oacc[ti][vj] = __builtin_amdgcn_mfma_f32_16x16x32_bf16(aP[ti], bZ, oacc[ti][vj], 0, 0, 0);
    }
  }

  // ---- fused gated RMSNorm ----
  float sum2[4][4];
#pragma unroll
  for (int ti = 0; ti < 4; ++ti)
#pragma unroll
    for (int q = 0; q < 4; ++q) {
      float s = 0.f;
#pragma unroll
      for (int vj = 0; vj < 4; ++vj) s += oacc[ti][vj][q] * oacc[ti][vj][q];
      sum2[ti][q] = s;
    }
#pragma unroll
  for (int mk = 1; mk < 16; mk <<= 1)
#pragma unroll
    for (int ti = 0; ti < 4; ++ti)
#pragma unroll
      for (int q = 0; q < 4; ++q)
        sum2[ti][q] += __shfl_xor(sum2[ti][q], mk, 64);
  if (lr == 0) {
#pragma unroll
    for (int ti = 0; ti < 4; ++ti)
#pragma unroll
      for (int q = 0; q < 4; ++q)
        sred[wq][ti * 16 + lg * 4 + q] = sum2[ti][q];
  }
  __syncthreads();

  float onv[4];
#pragma unroll
  for (int vj = 0; vj < 4; ++vj) onv[vj] = onorm_w[wq * 64 + vj * 16 + lr];
#pragma unroll
  for (int ti = 0; ti < 4; ++ti)
#pragma unroll
    for (int q = 0; q < 4; ++q) {
      int t = ti * 16 + lg * 4 + q;
      float tot = sred[0][t] + sred[1][t] + sred[2][t] + sred[3][t];
      float rn = rsqrtf(tot * (1.f / VV) + 1e-5f);
#pragma unroll
      for (int vj = 0; vj < 4; ++vj) {
        int v = wq * 64 + vj * 16 + lr;
        float gate = fgate[(size_t)(r0 + t) * NCAT + h * VV + v];
        float y = oacc[ti][vj][q] * rn * onv[vj] * (gate / (1.f + expf(-gate)));
        ovd[(size_t)(r0 + t) * VD + h * VV + v] = (bf16_t)y;
      }
    }
}

extern "C" void kernel_launch(void* const* d_in, const int* in_sizes, int n_in,
                              void* d_out, int out_size, void* d_ws, size_t ws_size,
                              hipStream_t stream) {
  const float* hidden = (const float*)d_in[0];
  const float* Wq = (const float*)d_in[1];
  const float* Wk = (const float*)d_in[2];
  const float* Wv = (const float*)d_in[3];
  const float* Wa = (const float*)d_in[4];
  const float* Wb = (const float*)d_in[5];
  const float* A_log = (const float*)d_in[6];
  const float* dt_bias = (const float*)d_in[7];
  const float* qconv = (const float*)d_in[8];
  const float* kconv = (const float*)d_in[9];
  const float* vconv = (const float*)d_in[10];
  const float* Wg = (const float*)d_in[11];
  const float* onorm = (const float*)d_in[12];
  const float* Wo = (const float*)d_in[13];
  float* out = (float*)d_out;

  char* ws = (char*)d_ws;
  size_t off = 0;
  auto alloc = [&](size_t bytes) {
    void* p = ws + off;
    off += (bytes + 255) & ~(size_t)255;
    return p;
  };
  const int M = BB * TT;  // 2048
  bf16_t* hbf   = (bf16_t*)alloc((size_t)M * CC * 2);       // aliased by Wn16/khatT16 later
  bf16_t* WcatT = (bf16_t*)alloc((size_t)NCAT * CC * 2);
  bf16_t* WoT   = (bf16_t*)alloc((size_t)CC * VD * 2);
  float*  fall  = (float*) alloc((size_t)M * NCAT * 4);     // fused q|k|v|gate projection
  bf16_t* states = (bf16_t*)alloc((size_t)12 * NC * VV * KK * 2);  // 12.6MB
  float*  kn    = (float*) alloc((size_t)M * KD * 4);       // aliased by Zt later
  float*  vn    = (float*) alloc((size_t)M * VD * 4);       // becomes Dv in pass 1
  float*  gdec  = (float*) alloc((size_t)M * HH * 4);
  float*  beta  = (float*) alloc((size_t)M * HH * 4);
  bf16_t* ovd   = (bf16_t*)alloc((size_t)M * VD * 2);
  bf16_t* qb16  = (bf16_t*)alloc((size_t)M * KD * 2);
  bf16_t* kb16  = (bf16_t*)alloc((size_t)M * KD * 2);
  float*  bcum  = (float*) alloc((size_t)12 * NC * CL * 4);

  // aliases (stream-ordered lifetime separation):
  bf16_t* Wn16    = (bf16_t*)hbf;                     // 12*16*64*128 bf16 = 3.15MB
  bf16_t* khatT16 = Wn16 + (size_t)12 * NC * CL * KK; // +3.15MB (hbf is 8.4MB)
  bf16_t* Zt      = (bf16_t*)kn;                      // 12*16*256*64 bf16 = 6.3MB

  // pre-pass
  k_cvt_bf16<<<(M * CC / 4 + 255) / 256, 256, 0, stream>>>(hidden, hbf, M * CC);
  k_transpose_cvt<<<dim3(KD / 32, CC / 32), dim3(32, 8), 0, stream>>>(Wq, WcatT, CC, KD);
  k_transpose_cvt<<<dim3(KD / 32, CC / 32), dim3(32, 8), 0, stream>>>(Wk, WcatT + (size_t)768 * CC, CC, KD);
  k_transpose_cvt<<<dim3(VD / 32, CC / 32), dim3(32, 8), 0, stream>>>(Wv, WcatT + (size_t)1536 * CC, CC, VD);
  k_transpose_cvt<<<dim3(VD / 32, CC / 32), dim3(32, 8), 0, stream>>>(Wg, WcatT + (size_t)3072 * CC, CC, VD);
  k_transpose_cvt<<<dim3(CC / 32, VD / 32), dim3(32, 8), 0, stream>>>(Wo, WoT, VD, CC);

  // fused projection GEMM: [2048,2048] x [4608,2048]^T -> [2048,4608]
  k_gemm_bt<<<dim3(NCAT / 128, M / 128), 256, 0, stream>>>(hbf, WcatT, fall, M, NCAT, CC);

  // beta / g
  k_ab<<<M, 64, 0, stream>>>(hidden, Wa, Wb, A_log, dt_bias, gdec, beta);

  // conv + silu (+norm for q,k)
  k_conv_silu<<<dim3(M, HH), 128, 0, stream>>>(fall, NCAT, 0, qconv, nullptr, qb16, KD, 1);
  k_conv_silu<<<dim3(M, HH), 128, 0, stream>>>(fall, NCAT, 768, kconv, nullptr, kb16, KD, 1);
  k_conv_silu<<<dim3(M, HH), 256, 0, stream>>>(fall, NCAT, 1536, vconv, vn, nullptr, VD, 0);

  // chunked gated delta rule (hbf dead -> Wn16/khatT16; kn dead -> Zt)
  k_chunk1<<<dim3(NC, 12), 256, 0, stream>>>(kb16, vn, gdec, beta, Wn16, khatT16, bcum);
  k_chunk2<<<dim3(8, 12), 256, 0, stream>>>(vn, Wn16, khatT16, bcum, states, Zt);
  k_chunk3<<<dim3(NC, 12), 256, 0, stream>>>(qb16, kb16, Zt, states, bcum, fall + 3072, onorm, ovd);

  // output projection
  k_gemm_bt<<<dim3(CC / 128, M / 128), 256, 0, stream>>>(ovd, WoT, out, M, CC, VD);
}

// Round 14
// 227.786 us; speedup vs baseline: 1.6634x; 1.1163x over previous
//
#include <hip/hip_runtime.h>
#include <hip/hip_bf16.h>
#include <math.h>

typedef __bf16 bf16_t;
typedef __attribute__((ext_vector_type(8))) __bf16 bf16x8;
typedef __attribute__((ext_vector_type(4))) float f32x4;

#define GAS __attribute__((address_space(1)))
#define LAS __attribute__((address_space(3)))

#define BB 2
#define TT 1024
#define CC 2048
#define HH 6
#define KK 128
#define VV 256
#define KD 768
#define VD 1536
#define NQKV 3072
#define NCAT 4608
#define NC 16     // chunks per sequence
#define CL 64     // chunk length

__device__ __forceinline__ void gload_lds16(const void* g, void* l) {
  __builtin_amdgcn_global_load_lds((const GAS void*)g, (LAS void*)l, 16, 0, 0);
}

// scalar read of swizzled [64][128] bf16 tile element (t, kk)
__device__ __forceinline__ float ksh_get(const bf16_t* ksh, int t, int kk) {
  return (float)*(const bf16_t*)((const char*)ksh + t * 256 +
           ((((kk >> 3) ^ (t & 7)) * 16) + (kk & 7) * 2));
}

// ---------- f32 -> bf16 convert ----------
__global__ void k_cvt_bf16(const float* __restrict__ in, bf16_t* __restrict__ out, int n) {
  int i = (blockIdx.x * blockDim.x + threadIdx.x) * 4;
  if (i + 3 < n) {
    float4 v = *(const float4*)(in + i);
    out[i + 0] = (bf16_t)v.x;
    out[i + 1] = (bf16_t)v.y;
    out[i + 2] = (bf16_t)v.z;
    out[i + 3] = (bf16_t)v.w;
  }
}

// ---------- transpose [Kd,Nd] f32 -> [Nd,Kd] bf16 ----------
__global__ void k_transpose_cvt(const float* __restrict__ in, bf16_t* __restrict__ out,
                                int Kd, int Nd) {
  __shared__ float t[32][33];
  int n0 = blockIdx.x * 32, k0 = blockIdx.y * 32;
  int tx = threadIdx.x, ty = threadIdx.y;
#pragma unroll
  for (int i = 0; i < 32; i += 8)
    t[ty + i][tx] = in[(size_t)(k0 + ty + i) * Nd + n0 + tx];
  __syncthreads();
#pragma unroll
  for (int i = 0; i < 32; i += 8)
    out[(size_t)(n0 + ty + i) * Kd + k0 + tx] = (bf16_t)t[tx][ty + i];
}

// ---------- bf16 MFMA GEMM: C[M,N] = A[M,K] * B^T (B is [N,K]) ----------
// BK=64, XOR-swizzled LDS (slot ^= row&7) via pre-swizzled global source ->
// conflict-free ds_read_b128. XCD-swizzled grid.
__global__ __launch_bounds__(256, 2)
void k_gemm_bt(const bf16_t* __restrict__ A, const bf16_t* __restrict__ B,
               float* __restrict__ C, int M, int N, int K) {
  __shared__ __align__(16) bf16_t As[128 * 64];
  __shared__ __align__(16) bf16_t Bs[128 * 64];
  int tid = threadIdx.x;
  int wave = tid >> 6, lane = tid & 63;
  int wm = wave >> 1, wn = wave & 1;

  // bijective XCD-aware swizzle (m204): contiguous wgid chunk per XCD
  int gx = gridDim.x;
  int nwg = gx * gridDim.y;
  int lin = blockIdx.y * gx + blockIdx.x;
  int q8 = nwg >> 3, r8 = nwg & 7;
  int xcd = lin & 7, off8 = lin >> 3;
  int wgid = (xcd < r8 ? xcd * (q8 + 1) : r8 * (q8 + 1) + (xcd - r8) * q8) + off8;
  int bx = wgid % gx, by = wgid / gx;

  const bf16_t* Abase = A + (size_t)by * 128 * K;
  const bf16_t* Bbase = B + (size_t)bx * 128 * K;
  int srow = tid >> 3, sslot = tid & 7;          // staging: thread -> (row, slot)

  f32x4 acc[4][4];
#pragma unroll
  for (int i = 0; i < 4; ++i)
#pragma unroll
    for (int j = 0; j < 4; ++j) acc[i][j] = (f32x4){0.f, 0.f, 0.f, 0.f};

  int kg = lane >> 4, lr = lane & 15;

  for (int k0 = 0; k0 < K; k0 += 64) {
#pragma unroll
    for (int it = 0; it < 4; ++it) {
      int row = it * 32 + srow;                  // 32 rows per iteration
      const bf16_t* ga = Abase + (size_t)row * K + k0 + ((sslot ^ (row & 7)) * 8);
      const bf16_t* gb = Bbase + (size_t)row * K + k0 + ((sslot ^ (row & 7)) * 8);
      gload_lds16(ga, As + (size_t)(it * 256 + wave * 64) * 8);
      gload_lds16(gb, Bs + (size_t)(it * 256 + wave * 64) * 8);
    }
    __syncthreads();
#pragma unroll
    for (int ks2 = 0; ks2 < 2; ++ks2) {
      int j = ks2 * 4 + kg;
      bf16x8 af[4], bfv[4];
#pragma unroll
      for (int i = 0; i < 4; ++i) {
        int ra = wm * 64 + i * 16 + lr;
        int rb = wn * 64 + i * 16 + lr;
        af[i]  = *(const bf16x8*)((const char*)As + ra * 128 + ((j ^ (ra & 7)) * 16));
        bfv[i] = *(const bf16x8*)((const char*)Bs + rb * 128 + ((j ^ (rb & 7)) * 16));
      }
#pragma unroll
      for (int i = 0; i < 4; ++i)
#pragma unroll
        for (int jj = 0; jj < 4; ++jj)
          acc[i][jj] = __builtin_amdgcn_mfma_f32_16x16x32_bf16(af[i], bfv[jj], acc[i][jj], 0, 0, 0);
    }
    __syncthreads();
  }

#pragma unroll
  for (int i = 0; i < 4; ++i) {
    int r0 = by * 128 + wm * 64 + i * 16 + ((lane >> 4) << 2);
#pragma unroll
    for (int j = 0; j < 4; ++j) {
      int c = bx * 128 + wn * 64 + j * 16 + (lane & 15);
      float* Cp = C + (size_t)r0 * N + c;
#pragma unroll
      for (int q = 0; q < 4; ++q) Cp[(size_t)q * N] = acc[i][j][q];
    }
  }
}

// ---------- beta / g ----------
__global__ __launch_bounds__(64)
void k_ab(const float* __restrict__ hidden, const float* __restrict__ Wa,
          const float* __restrict__ Wb, const float* __restrict__ A_log,
          const float* __restrict__ dt_bias, float* __restrict__ g_out,
          float* __restrict__ beta_out) {
  int row = blockIdx.x;
  int lane = threadIdx.x;
  float accA[6] = {0, 0, 0, 0, 0, 0};
  float accB[6] = {0, 0, 0, 0, 0, 0};
  const float* h = hidden + (size_t)row * CC;
  for (int c = lane; c < CC; c += 64) {
    float x = h[c];
    const float* wa = Wa + c * 6;
    const float* wb = Wb + c * 6;
#pragma unroll
    for (int j = 0; j < 6; ++j) {
      accA[j] += x * wa[j];
      accB[j] += x * wb[j];
    }
  }
#pragma unroll
  for (int j = 0; j < 6; ++j) {
    for (int off = 32; off; off >>= 1) {
      accA[j] += __shfl_down(accA[j], off);
      accB[j] += __shfl_down(accB[j], off);
    }
  }
  if (lane == 0) {
#pragma unroll
    for (int j = 0; j < 6; ++j) {
      float a = accA[j] + dt_bias[j];
      float sp = (a > 20.f) ? a : log1pf(expf(a));
      g_out[(size_t)row * 6 + j] = -expf(A_log[j]) * sp;
      beta_out[(size_t)row * 6 + j] = 1.f / (1.f + expf(-accB[j]));
    }
  }
}

// ---------- depthwise causal conv(4) + SiLU (+ optional L2 norm); optional f32/bf16 outs ----------
__global__ void k_conv_silu(const float* __restrict__ pre, int ldpre, int col0,
                            const float* __restrict__ w, float* __restrict__ out,
                            bf16_t* __restrict__ out16, int ld_out, int do_norm) {
  int row = blockIdx.x;     // b*T + t
  int t = row & (TT - 1);
  int h = blockIdx.y;
  int kk = threadIdx.x;
  int perH = blockDim.x;
  int ch = h * perH + kk;
  const float* wp = w + ch * 4;
  float y = 0.f;
#pragma unroll
  for (int i = 0; i < 4; ++i) {
    int tt = t - 3 + i;
    if (tt >= 0) y += wp[i] * pre[(size_t)(row - 3 + i) * ldpre + col0 + ch];
  }
  float s = y / (1.f + expf(-y));
  if (do_norm) {
    float ss = s * s;
#pragma unroll
    for (int off = 32; off; off >>= 1) ss += __shfl_down(ss, off);
    __shared__ float red[2];
    if ((threadIdx.x & 63) == 0) red[threadIdx.x >> 6] = ss;
    __syncthreads();
    float nrm = sqrtf(red[0] + red[1]);
    s = s / (nrm + 1e-6f);
  }
  if (out) out[(size_t)row * ld_out + ch] = s;
  if (out16) out16[(size_t)row * ld_out + ch] = (bf16_t)s;
}

// ============ chunked gated delta rule ============
// Pass 1 (R8's UT transform, 8-wave version): 512 thr; phase D = 3 n-tiles/wave
// for 2 waves/SIMD latency hiding. Math identical to the verified R8 kernel.
__global__ __launch_bounds__(512, 2)
void k_chunk1(const bf16_t* __restrict__ kb16, float* dv,
              const float* __restrict__ gdec, const float* __restrict__ beta,
              bf16_t* __restrict__ Wn16, bf16_t* __restrict__ khatT16,
              float* __restrict__ bcum) {
  __shared__ __align__(16) bf16_t ksh[64 * 128];    // 16KB [t][k] swizzled
  __shared__ __align__(16) bf16_t Mb[64 * 64];      // 8KB  [t][s] = -M, swizzled
  __shared__ __align__(16) bf16_t Tdl[4 * 16 * 32]; // 4KB  diag-block inverses, k:16..31 zero
  __shared__ __align__(16) bf16_t Yb[384 * 32];     // 24KB [n][k] Ytmp (B-frag layout), k:16..31 zero
  __shared__ __align__(16) bf16_t Xall[384 * 64];   // 48KB [n][s] solved X (B-frag layout)
  __shared__ float bc[64], bet[64];

  int tid = threadIdx.x;
  int bh = blockIdx.y, c = blockIdx.x;
  int b = bh / HH, h = bh % HH;
  int r0 = b * TT + c * CL;
  size_t cb = (size_t)bh * NC + c;
  int wq = tid >> 6, l = tid & 63;
  int lr = l & 15, lg = l >> 4;

  // ---- phase A: stage k chunk (pre-XOR'd source -> swizzled LDS), g-cumsum ----
#pragma unroll
  for (int it = 0; it < 2; ++it) {
    int idx = it * 512 + tid;
    int t = idx >> 4, p = idx & 15;
    int kslot = p ^ (t & 7);
    gload_lds16(kb16 + (size_t)(r0 + t) * KD + h * KK + kslot * 8,
                ksh + (size_t)idx * 8);
  }
  if (tid < 64) {
    float val = gdec[(size_t)(r0 + tid) * HH + h];
    bet[tid] = beta[(size_t)(r0 + tid) * HH + h];
#pragma unroll
    for (int off = 1; off < 64; off <<= 1) {
      float o = __shfl_up(val, off, 64);
      if (tid >= off) val += o;
    }
    bc[tid] = val;
    bcum[cb * CL + tid] = val;
  }
  __syncthreads();
  float bL = bc[63];

  // ---- phase B: -M via MFMA (waves 0-3) -> Mb; zero-init Xall/Yb/Tdl ----
  {
    f32x4 z4 = (f32x4){0.f, 0.f, 0.f, 0.f};
#pragma unroll
    for (int i = 0; i < 6; ++i) ((f32x4*)Xall)[i * 512 + tid] = z4;
#pragma unroll
    for (int i = 0; i < 3; ++i) ((f32x4*)Yb)[i * 512 + tid] = z4;
    if (tid < 256) ((f32x4*)Tdl)[tid] = z4;
  }
  if (wq < 4) {
    f32x4 pacc[4];
#pragma unroll
    for (int sf = 0; sf < 4; ++sf) pacc[sf] = (f32x4){0.f, 0.f, 0.f, 0.f};
#pragma unroll
    for (int ks_ = 0; ks_ < 4; ++ks_) {
      int trow = wq * 16 + lr;
      bf16x8 aK = *(const bf16x8*)((const char*)ksh + trow * 256 + (((ks_ * 4 + lg) * 16) ^ ((trow & 7) << 4)));
#pragma unroll
      for (int sf = 0; sf < 4; ++sf) {
        int srow = sf * 16 + lr;
        bf16x8 bK = *(const bf16x8*)((const char*)ksh + srow * 256 + (((ks_ * 4 + lg) * 16) ^ ((srow & 7) << 4)));
        pacc[sf] = __builtin_amdgcn_mfma_f32_16x16x32_bf16(aK, bK, pacc[sf], 0, 0, 0);
      }
    }
#pragma unroll
    for (int sf = 0; sf < 4; ++sf)
#pragma unroll
      for (int q = 0; q < 4; ++q) {
        int t = wq * 16 + lg * 4 + q;
        int s = sf * 16 + lr;
        float val = (s < t) ? -bet[t] * __expf(bc[t] - bc[s]) * pacc[sf][q] : 0.f;
        *(bf16_t*)((char*)Mb + t * 128 + ((s * 2) ^ ((t & 7) << 4))) = (bf16_t)val;
      }
  }
  __syncthreads();

  // ---- phase C: diag-block inverses (threads 0..63) || khatT16 (threads 64..191) ----
  if (tid < 64) {
    int d = tid >> 4, cc = tid & 15;
    float x[16];
#pragma unroll
    for (int s = 0; s < 16; ++s) x[s] = (s == cc) ? 1.f : 0.f;
#pragma unroll
    for (int r = 1; r < 16; ++r) {
      float a = 0.f;
#pragma unroll
      for (int s = 0; s < r; ++s) {
        float m = (float)*(const bf16_t*)((const char*)Mb + (16 * d + r) * 128 +
                    (((16 * d + s) * 2) ^ ((r & 7) << 4)));
        a += m * x[s];
      }
      x[r] += a;
    }
#pragma unroll
    for (int r = 0; r < 16; ++r)
      *(bf16_t*)((char*)Tdl + d * 1024 + r * 64 +
          ((((cc >> 3) * 16) ^ ((r & 3) << 4)) + (cc & 7) * 2)) = (bf16_t)x[r];
  } else if (tid < 192) {
    int kk = tid - 64;
    bf16_t* kout = khatT16 + cb * (size_t)(KK * CL) + (size_t)kk * CL;
#pragma unroll
    for (int t8 = 0; t8 < 8; ++t8) {
      union { bf16x8 v; bf16_t e[8]; } u;
#pragma unroll
      for (int e = 0; e < 8; ++e) {
        int t = t8 * 8 + e;
        u.e[e] = (bf16_t)(__expf(bL - bc[t]) * ksh_get(ksh, t, kk));
      }
      *(bf16x8*)(kout + t8 * 8) = u.v;
    }
  }
  __syncthreads();

  // ---- phase D: 4-stage block solve, 3 n-tiles per wave (8 waves) ----
  const int nbase = wq * 48;
#pragma unroll
  for (int st = 0; st < 4; ++st) {
#pragma unroll
    for (int nt = 0; nt < 3; ++nt) {
      const int n0 = nbase + nt * 16;
      const bool isv = (n0 < 256);
      const int n = n0 + lr;
      f32x4 acc = (f32x4){0.f, 0.f, 0.f, 0.f};
      if (isv) {
#pragma unroll
        for (int q = 0; q < 4; ++q) {
          int t = st * 16 + lg * 4 + q;
          acc[q] = bet[t] * dv[(size_t)(r0 + t) * VD + h * VV + n];
        }
      } else {
        int kk = n - 256;
#pragma unroll
        for (int q = 0; q < 4; ++q) {
          int t = st * 16 + lg * 4 + q;
          acc[q] = bet[t] * __expf(bc[t]) * ksh_get(ksh, t, kk);
        }
      }
      // acc += (-M) X  (K=32 pair-packed; unwritten X regions are zero)
#pragma unroll
      for (int p = 0; p < 2; ++p) {
        if ((p == 0 && st >= 1) || (p == 1 && st == 3)) {
          int arow = st * 16 + lr;
          bf16x8 aM = *(const bf16x8*)((const char*)Mb + arow * 128 +
                         (((p * 4 + lg) * 16) ^ ((arow & 7) << 4)));
          bf16x8 bX = *(const bf16x8*)((const char*)Xall + n * 128 +
                         (((p * 4 + lg) * 16) ^ ((n & 7) << 4)));
          acc = __builtin_amdgcn_mfma_f32_16x16x32_bf16(aM, bX, acc, 0, 0, 0);
        }
      }
      // Ytmp -> Yb (B-frag layout, own rows only)
#pragma unroll
      for (int q = 0; q < 4; ++q) {
        int tq = lg * 4 + q;
        *(bf16_t*)((char*)Yb + n * 64 +
            ((((tq >> 3) * 16) ^ ((n & 3) << 4)) + (tq & 7) * 2)) = (bf16_t)acc[q];
      }
      // X_st = T_st @ Ytmp
      f32x4 acc2 = (f32x4){0.f, 0.f, 0.f, 0.f};
      {
        bf16x8 aT = *(const bf16x8*)((const char*)Tdl + st * 1024 + lr * 64 +
                       ((lg * 16) ^ ((lr & 3) << 4)));
        bf16x8 bY = *(const bf16x8*)((const char*)Yb + n * 64 +
                       ((lg * 16) ^ ((n & 3) << 4)));
        acc2 = __builtin_amdgcn_mfma_f32_16x16x32_bf16(aT, bY, acc2, 0, 0, 0);
      }
      // store X for later stages + final outputs
      if (st < 3) {
#pragma unroll
        for (int q = 0; q < 4; ++q) {
          int s = st * 16 + lg * 4 + q;
          *(bf16_t*)((char*)Xall + n * 128 +
              ((((s >> 3) * 16) ^ ((n & 7) << 4)) + (s & 7) * 2)) = (bf16_t)acc2[q];
        }
      }
      if (isv) {
#pragma unroll
        for (int q = 0; q < 4; ++q) {
          int t = st * 16 + lg * 4 + q;
          dv[(size_t)(r0 + t) * VD + h * VV + n] = acc2[q];
        }
      } else {
        int kk = n - 256;
#pragma unroll
        for (int q = 0; q < 4; ++q) {
          int t = st * 16 + lg * 4 + q;
          Wn16[(cb * CL + t) * KK + kk] = (bf16_t)(-acc2[q]);
        }
      }
    }
  }
}

// Pass 2: MFMA state propagation. Grid (8 vtiles of 32, 12 bh), 256 thr (4 waves).
__global__ __launch_bounds__(256, 1)
void k_chunk2(const float* __restrict__ dv, const bf16_t* __restrict__ Wn16,
              const bf16_t* __restrict__ khatT16, const float* __restrict__ bcum,
              bf16_t* __restrict__ states, bf16_t* __restrict__ Zt) {
  __shared__ __align__(16) bf16_t St[32 * 128];   // [v][k], XOR-swizzled
  __shared__ __align__(16) bf16_t Zl[32 * 64];    // [v][t], XOR-swizzled
  int tid = threadIdx.x;
  int vt = blockIdx.x, bh = blockIdx.y;
  int b = bh / HH, h = bh % HH;
  int wq = tid >> 6, l = tid & 63;
  int lr = l & 15, lg = l >> 4;

  f32x4 acc[2][2];
#pragma unroll
  for (int kf = 0; kf < 2; ++kf)
#pragma unroll
    for (int vf = 0; vf < 2; ++vf) acc[kf][vf] = (f32x4){0.f, 0.f, 0.f, 0.f};

  for (int c = 0; c < NC; ++c) {
    size_t cb = (size_t)bh * NC + c;
    int r0 = b * TT + c * CL;
    float ebL = __expf(bcum[cb * CL + 63]);

#pragma unroll
    for (int kf = 0; kf < 2; ++kf)
#pragma unroll
      for (int vf = 0; vf < 2; ++vf)
#pragma unroll
        for (int q = 0; q < 4; ++q) {
          int k = wq * 32 + kf * 16 + lg * 4 + q;
          int v = vf * 16 + lr;
          *(bf16_t*)((char*)St + v * 256 + ((k * 2) ^ ((v & 7) << 4))) = (bf16_t)acc[kf][vf][q];
        }
    __syncthreads();

#pragma unroll
    for (int it = 0; it < 2; ++it) {
      int idx = tid + it * 256;
      int v = idx >> 4, slot = idx & 15;
      bf16x8 val = *(const bf16x8*)((const char*)St + v * 256 + ((slot * 16) ^ ((v & 7) << 4)));
      *(bf16x8*)(states + ((size_t)cb * 256 + vt * 32 + v) * 128 + slot * 8) = val;
    }

    f32x4 zacc[2];
#pragma unroll
    for (int vf = 0; vf < 2; ++vf)
#pragma unroll
      for (int q = 0; q < 4; ++q) {
        int t = wq * 16 + lg * 4 + q;
        zacc[vf][q] = dv[(size_t)(r0 + t) * VD + h * VV + vt * 32 + vf * 16 + lr];
      }
#pragma unroll
    for (int ks_ = 0; ks_ < 4; ++ks_) {
      bf16x8 aW = *(const bf16x8*)(Wn16 + (cb * CL + wq * 16 + lr) * KK + ks_ * 32 + lg * 8);
#pragma unroll
      for (int vf = 0; vf < 2; ++vf) {
        int v = vf * 16 + lr;
        bf16x8 bS = *(const bf16x8*)((const char*)St + v * 256 + (((ks_ * 32 + lg * 8) * 2) ^ ((v & 7) << 4)));
        zacc[vf] = __builtin_amdgcn_mfma_f32_16x16x32_bf16(aW, bS, zacc[vf], 0, 0, 0);
      }
    }
#pragma unroll
    for (int vf = 0; vf < 2; ++vf)
#pragma unroll
      for (int q = 0; q < 4; ++q) {
        int t = wq * 16 + lg * 4 + q;
        int v = vf * 16 + lr;
        *(bf16_t*)((char*)Zl + v * 128 + ((t * 2) ^ ((v & 7) << 4))) = (bf16_t)zacc[vf][q];
      }
    __syncthreads();

    {
      int v = tid >> 3, slot = tid & 7;
      bf16x8 val = *(const bf16x8*)((const char*)Zl + v * 128 + ((slot * 16) ^ ((v & 7) << 4)));
      *(bf16x8*)(Zt + ((size_t)cb * 256 + vt * 32 + v) * 64 + slot * 8) = val;
    }
#pragma unroll
    for (int kf = 0; kf < 2; ++kf)
#pragma unroll
      for (int vf = 0; vf < 2; ++vf)
#pragma unroll
        for (int q = 0; q < 4; ++q) acc[kf][vf][q] *= ebL;
#pragma unroll
    for (int ts = 0; ts < 2; ++ts) {
      bf16x8 aK[2], bZ[2];
#pragma unroll
      for (int kf = 0; kf < 2; ++kf)
        aK[kf] = *(const bf16x8*)(khatT16 + (cb * KK + wq * 32 + kf * 16 + lr) * CL + ts * 32 + lg * 8);
#pragma unroll
      for (int vf = 0; vf < 2; ++vf) {
        int v = vf * 16 + lr;
        bZ[vf] = *(const bf16x8*)((const char*)Zl + v * 128 + (((ts * 32 + lg * 8) * 2) ^ ((v & 7) << 4)));
      }
#pragma unroll
      for (int kf = 0; kf < 2; ++kf)
#pragma unroll
        for (int vf = 0; vf < 2; ++vf)
          acc[kf][vf] = __builtin_amdgcn_mfma_f32_16x16x32_bf16(aK[kf], bZ[vf], acc[kf][vf], 0, 0, 0);
    }
  }
}

// Pass 3 (8-wave): o = e^{b_t} q^T S0 + P Z (MFMA) + fused gated RMSNorm.
// states/Zt B-frags hoisted to registers at entry (T14); P on waves 0-3;
// O-phase: 8 waves x 32 v-cols. fgate row stride NCAT.
__global__ __launch_bounds__(512, 2)
void k_chunk3(const bf16_t* __restrict__ qb16, const bf16_t* __restrict__ kb16,
              const bf16_t* __restrict__ Zt, const bf16_t* __restrict__ states,
              const float* __restrict__ bcum, const float* __restrict__ fgate,
              const float* __restrict__ onorm_w, bf16_t* __restrict__ ovd) {
  __shared__ __align__(16) bf16_t qs[64 * 128];   // [t][k] swizzled via pre-XOR source
  __shared__ __align__(16) bf16_t ksh[64 * 128];
  __shared__ __align__(16) bf16_t Pl[64 * 64];    // [t][s] swizzled
  __shared__ float bcs[64];
  __shared__ float sred[8][64];

  int tid = threadIdx.x;
  int c = blockIdx.x, bh = blockIdx.y;
  int b = bh / HH, h = bh % HH;
  int r0 = b * TT + c * CL;
  size_t cb = (size_t)bh * NC + c;
  int wq = tid >> 6, l = tid & 63;
  int lr = l & 15, lg = l >> 4;

  // hoisted global B-frag loads: latency hides under staging + P phase
  bf16x8 bSv[4][2], bZv[2][2];
#pragma unroll
  for (int vj = 0; vj < 2; ++vj) {
    int vrow = wq * 32 + vj * 16 + lr;
#pragma unroll
    for (int ks_ = 0; ks_ < 4; ++ks_)
      bSv[ks_][vj] = *(const bf16x8*)(states + ((size_t)cb * 256 + vrow) * 128 + ks_ * 32 + lg * 8);
#pragma unroll
    for (int ts = 0; ts < 2; ++ts)
      bZv[ts][vj] = *(const bf16x8*)(Zt + ((size_t)cb * 256 + vrow) * 64 + ts * 32 + lg * 8);
  }

  if (tid < 64) bcs[tid] = bcum[cb * CL + tid];
#pragma unroll
  for (int it = 0; it < 2; ++it) {
    int idx = it * 512 + tid;
    int t = idx >> 4, p = idx & 15;
    int kslot = p ^ (t & 7);
    gload_lds16(qb16 + (size_t)(r0 + t) * KD + h * KK + kslot * 8,
                qs + (size_t)idx * 8);
    gload_lds16(kb16 + (size_t)(r0 + t) * KD + h * KK + kslot * 8,
                ksh + (size_t)idx * 8);
  }
  __syncthreads();

  if (wq < 4) {
    f32x4 pacc[4];
#pragma unroll
    for (int sf = 0; sf < 4; ++sf) pacc[sf] = (f32x4){0.f, 0.f, 0.f, 0.f};
#pragma unroll
    for (int ks_ = 0; ks_ < 4; ++ks_) {
      int trow = wq * 16 + lr;
      bf16x8 aQ = *(const bf16x8*)((const char*)qs + trow * 256 + (((ks_ * 4 + lg) * 16) ^ ((trow & 7) << 4)));
#pragma unroll
      for (int sf = 0; sf < 4; ++sf) {
        int srow = sf * 16 + lr;
        bf16x8 bK = *(const bf16x8*)((const char*)ksh + srow * 256 + (((ks_ * 4 + lg) * 16) ^ ((srow & 7) << 4)));
        pacc[sf] = __builtin_amdgcn_mfma_f32_16x16x32_bf16(aQ, bK, pacc[sf], 0, 0, 0);
      }
    }
#pragma unroll
    for (int sf = 0; sf < 4; ++sf)
#pragma unroll
      for (int q = 0; q < 4; ++q) {
        int t = wq * 16 + lg * 4 + q;
        int s = sf * 16 + lr;
        float val = (s <= t) ? pacc[sf][q] * __expf(bcs[t] - bcs[s]) : 0.f;
        *(bf16_t*)((char*)Pl + t * 128 + ((s * 2) ^ ((t & 7) << 4))) = (bf16_t)val;
      }
  }
  __syncthreads();

  // O: wave wq covers v cols wq*32..+31
  f32x4 oacc[4][2];
#pragma unroll
  for (int ti = 0; ti < 4; ++ti)
#pragma unroll
    for (int vj = 0; vj < 2; ++vj) oacc[ti][vj] = (f32x4){0.f, 0.f, 0.f, 0.f};

#pragma unroll
  for (int ks_ = 0; ks_ < 4; ++ks_) {
    bf16x8 aQ[4];
#pragma unroll
    for (int ti = 0; ti < 4; ++ti) {
      int t = ti * 16 + lr;
      union { bf16x8 v; bf16_t e[8]; } u;
      u.v = *(const bf16x8*)((const char*)qs + t * 256 + (((ks_ * 4 + lg) * 16) ^ ((t & 7) << 4)));
      float eb = __expf(bcs[t]);
#pragma unroll
      for (int e = 0; e < 8; ++e) u.e[e] = (bf16_t)((float)u.e[e] * eb);
      aQ[ti] = u.v;
    }
#pragma unroll
    for (int vj = 0; vj < 2; ++vj)
#pragma unroll
      for (int ti = 0; ti < 4; ++ti)
        oacc[ti][vj] = __builtin_amdgcn_mfma_f32_16x16x32_bf16(aQ[ti], bSv[ks_][vj], oacc[ti][vj], 0, 0, 0);
  }
#pragma unroll
  for (int ts = 0; ts < 2; ++ts) {
    bf16x8 aP[4];
#pragma unroll
    for (int ti = 0; ti < 4; ++ti) {
      int t = ti * 16 + lr;
      aP[ti] = *(const bf16x8*)((const char*)Pl + t * 128 + (((ts * 4 + lg) * 16) ^ ((t & 7) << 4)));
    }
#pragma unroll
    for (int vj = 0; vj < 2; ++vj)
#pragma unroll
      for (int ti = 0; ti < 4; ++ti)
        oacc[ti][vj] = __builtin_amdgcn_mfma_f32_16x16x32_bf16(aP[ti], bZv[ts][vj], oacc[ti][vj], 0, 0, 0);
  }

  // ---- fused gated RMSNorm (8-wave reduce) ----
  float sum2[4][4];
#pragma unroll
  for (int ti = 0; ti < 4; ++ti)
#pragma unroll
    for (int q = 0; q < 4; ++q) {
      float s = 0.f;
#pragma unroll
      for (int vj = 0; vj < 2; ++vj) s += oacc[ti][vj][q] * oacc[ti][vj][q];
      sum2[ti][q] = s;
    }
#pragma unroll
  for (int mk = 1; mk < 16; mk <<= 1)
#pragma unroll
    for (int ti = 0; ti < 4; ++ti)
#pragma unroll
      for (int q = 0; q < 4; ++q)
        sum2[ti][q] += __shfl_xor(sum2[ti][q], mk, 64);
  if (lr == 0) {
#pragma unroll
    for (int ti = 0; ti < 4; ++ti)
#pragma unroll
      for (int q = 0; q < 4; ++q)
        sred[wq][ti * 16 + lg * 4 + q] = sum2[ti][q];
  }
  __syncthreads();

  float onv[2];
#pragma unroll
  for (int vj = 0; vj < 2; ++vj) onv[vj] = onorm_w[wq * 32 + vj * 16 + lr];
#pragma unroll
  for (int ti = 0; ti < 4; ++ti)
#pragma unroll
    for (int q = 0; q < 4; ++q) {
      int t = ti * 16 + lg * 4 + q;
      float tot = 0.f;
#pragma unroll
      for (int w = 0; w < 8; ++w) tot += sred[w][t];
      float rn = rsqrtf(tot * (1.f / VV) + 1e-5f);
#pragma unroll
      for (int vj = 0; vj < 2; ++vj) {
        int v = wq * 32 + vj * 16 + lr;
        float gate = fgate[(size_t)(r0 + t) * NCAT + h * VV + v];
        float y = oacc[ti][vj][q] * rn * onv[vj] * (gate / (1.f + expf(-gate)));
        ovd[(size_t)(r0 + t) * VD + h * VV + v] = (bf16_t)y;
      }
    }
}

extern "C" void kernel_launch(void* const* d_in, const int* in_sizes, int n_in,
                              void* d_out, int out_size, void* d_ws, size_t ws_size,
                              hipStream_t stream) {
  const float* hidden = (const float*)d_in[0];
  const float* Wq = (const float*)d_in[1];
  const float* Wk = (const float*)d_in[2];
  const float* Wv = (const float*)d_in[3];
  const float* Wa = (const float*)d_in[4];
  const float* Wb = (const float*)d_in[5];
  const float* A_log = (const float*)d_in[6];
  const float* dt_bias = (const float*)d_in[7];
  const float* qconv = (const float*)d_in[8];
  const float* kconv = (const float*)d_in[9];
  const float* vconv = (const float*)d_in[10];
  const float* Wg = (const float*)d_in[11];
  const float* onorm = (const float*)d_in[12];
  const float* Wo = (const float*)d_in[13];
  float* out = (float*)d_out;

  char* ws = (char*)d_ws;
  size_t off = 0;
  auto alloc = [&](size_t bytes) {
    void* p = ws + off;
    off += (bytes + 255) & ~(size_t)255;
    return p;
  };
  const int M = BB * TT;  // 2048
  bf16_t* hbf   = (bf16_t*)alloc((size_t)M * CC * 2);       // aliased by Wn16/khatT16 later
  bf16_t* WcatT = (bf16_t*)alloc((size_t)NCAT * CC * 2);
  bf16_t* WoT   = (bf16_t*)alloc((size_t)CC * VD * 2);
  float*  fall  = (float*) alloc((size_t)M * NCAT * 4);     // fused q|k|v|gate projection
  bf16_t* states = (bf16_t*)alloc((size_t)12 * NC * VV * KK * 2);  // 12.6MB
  float*  kn    = (float*) alloc((size_t)M * KD * 4);       // aliased by Zt later
  float*  vn    = (float*) alloc((size_t)M * VD * 4);       // becomes Dv in pass 1
  float*  gdec  = (float*) alloc((size_t)M * HH * 4);
  float*  beta  = (float*) alloc((size_t)M * HH * 4);
  bf16_t* ovd   = (bf16_t*)alloc((size_t)M * VD * 2);
  bf16_t* qb16  = (bf16_t*)alloc((size_t)M * KD * 2);
  bf16_t* kb16  = (bf16_t*)alloc((size_t)M * KD * 2);
  float*  bcum  = (float*) alloc((size_t)12 * NC * CL * 4);

  // aliases (stream-ordered lifetime separation):
  bf16_t* Wn16    = (bf16_t*)hbf;                     // 12*16*64*128 bf16 = 3.15MB
  bf16_t* khatT16 = Wn16 + (size_t)12 * NC * CL * KK; // +3.15MB (hbf is 8.4MB)
  bf16_t* Zt      = (bf16_t*)kn;                      // 12*16*256*64 bf16 = 6.3MB

  // pre-pass
  k_cvt_bf16<<<(M * CC / 4 + 255) / 256, 256, 0, stream>>>(hidden, hbf, M * CC);
  k_transpose_cvt<<<dim3(KD / 32, CC / 32), dim3(32, 8), 0, stream>>>(Wq, WcatT, CC, KD);
  k_transpose_cvt<<<dim3(KD / 32, CC / 32), dim3(32, 8), 0, stream>>>(Wk, WcatT + (size_t)768 * CC, CC, KD);
  k_transpose_cvt<<<dim3(VD / 32, CC / 32), dim3(32, 8), 0, stream>>>(Wv, WcatT + (size_t)1536 * CC, CC, VD);
  k_transpose_cvt<<<dim3(VD / 32, CC / 32), dim3(32, 8), 0, stream>>>(Wg, WcatT + (size_t)3072 * CC, CC, VD);
  k_transpose_cvt<<<dim3(CC / 32, VD / 32), dim3(32, 8), 0, stream>>>(Wo, WoT, VD, CC);

  // fused projection GEMM: [2048,2048] x [4608,2048]^T -> [2048,4608]
  k_gemm_bt<<<dim3(NCAT / 128, M / 128), 256, 0, stream>>>(hbf, WcatT, fall, M, NCAT, CC);

  // beta / g
  k_ab<<<M, 64, 0, stream>>>(hidden, Wa, Wb, A_log, dt_bias, gdec, beta);

  // conv + silu (+norm for q,k)
  k_conv_silu<<<dim3(M, HH), 128, 0, stream>>>(fall, NCAT, 0, qconv, nullptr, qb16, KD, 1);
  k_conv_silu<<<dim3(M, HH), 128, 0, stream>>>(fall, NCAT, 768, kconv, nullptr, kb16, KD, 1);
  k_conv_silu<<<dim3(M, HH), 256, 0, stream>>>(fall, NCAT, 1536, vconv, vn, nullptr, VD, 0);

  // chunked gated delta rule (hbf dead -> Wn16/khatT16; kn dead -> Zt)
  k_chunk1<<<dim3(NC, 12), 512, 0, stream>>>(kb16, vn, gdec, beta, Wn16, khatT16, bcum);
  k_chunk2<<<dim3(8, 12), 256, 0, stream>>>(vn, Wn16, khatT16, bcum, states, Zt);
  k_chunk3<<<dim3(NC, 12), 512, 0, stream>>>(qb16, kb16, Zt, states, bcum, fall + 3072, onorm, ovd);

  // output projection
  k_gemm_bt<<<dim3(CC / 128, M / 128), 256, 0, stream>>>(ovd, WoT, out, M, CC, VD);
}

// Round 15
// 226.636 us; speedup vs baseline: 1.6718x; 1.0051x over previous
//
#include <hip/hip_runtime.h>
#include <hip/hip_bf16.h>
#include <math.h>

typedef __bf16 bf16_t;
typedef __attribute__((ext_vector_type(8))) __bf16 bf16x8;
typedef __attribute__((ext_vector_type(4))) float f32x4;

#define GAS __attribute__((address_space(1)))
#define LAS __attribute__((address_space(3)))

#define BB 2
#define TT 1024
#define CC 2048
#define HH 6
#define KK 128
#define VV 256
#define KD 768
#define VD 1536
#define NQKV 3072
#define NCAT 4608
#define NC 16     // chunks per sequence
#define CL 64     // chunk length

__device__ __forceinline__ void gload_lds16(const void* g, void* l) {
  __builtin_amdgcn_global_load_lds((const GAS void*)g, (LAS void*)l, 16, 0, 0);
}

// scalar read of swizzled [64][128] bf16 tile element (t, kk)
__device__ __forceinline__ float ksh_get(const bf16_t* ksh, int t, int kk) {
  return (float)*(const bf16_t*)((const char*)ksh + t * 256 +
           ((((kk >> 3) ^ (t & 7)) * 16) + (kk & 7) * 2));
}

// ---------- f32 -> bf16 convert ----------
__global__ void k_cvt_bf16(const float* __restrict__ in, bf16_t* __restrict__ out, int n) {
  int i = (blockIdx.x * blockDim.x + threadIdx.x) * 4;
  if (i + 3 < n) {
    float4 v = *(const float4*)(in + i);
    out[i + 0] = (bf16_t)v.x;
    out[i + 1] = (bf16_t)v.y;
    out[i + 2] = (bf16_t)v.z;
    out[i + 3] = (bf16_t)v.w;
  }
}

// ---------- transpose [Kd,Nd] f32 -> [Nd,Kd] bf16 ----------
__global__ void k_transpose_cvt(const float* __restrict__ in, bf16_t* __restrict__ out,
                                int Kd, int Nd) {
  __shared__ float t[32][33];
  int n0 = blockIdx.x * 32, k0 = blockIdx.y * 32;
  int tx = threadIdx.x, ty = threadIdx.y;
#pragma unroll
  for (int i = 0; i < 32; i += 8)
    t[ty + i][tx] = in[(size_t)(k0 + ty + i) * Nd + n0 + tx];
  __syncthreads();
#pragma unroll
  for (int i = 0; i < 32; i += 8)
    out[(size_t)(n0 + ty + i) * Kd + k0 + tx] = (bf16_t)t[tx][ty + i];
}

// ---------- bf16 MFMA GEMM: C[M,N] = A[M,K] * B^T (B is [N,K]) ----------
// BK=64, XOR-swizzled LDS (slot ^= row&7) via pre-swizzled global source ->
// conflict-free ds_read_b128. XCD-swizzled grid. Templated output type.
template <typename OT>
__global__ __launch_bounds__(256, 2)
void k_gemm_bt(const bf16_t* __restrict__ A, const bf16_t* __restrict__ B,
               OT* __restrict__ C, int M, int N, int K) {
  __shared__ __align__(16) bf16_t As[128 * 64];
  __shared__ __align__(16) bf16_t Bs[128 * 64];
  int tid = threadIdx.x;
  int wave = tid >> 6, lane = tid & 63;
  int wm = wave >> 1, wn = wave & 1;

  // bijective XCD-aware swizzle (m204): contiguous wgid chunk per XCD
  int gx = gridDim.x;
  int nwg = gx * gridDim.y;
  int lin = blockIdx.y * gx + blockIdx.x;
  int q8 = nwg >> 3, r8 = nwg & 7;
  int xcd = lin & 7, off8 = lin >> 3;
  int wgid = (xcd < r8 ? xcd * (q8 + 1) : r8 * (q8 + 1) + (xcd - r8) * q8) + off8;
  int bx = wgid % gx, by = wgid / gx;

  const bf16_t* Abase = A + (size_t)by * 128 * K;
  const bf16_t* Bbase = B + (size_t)bx * 128 * K;
  int srow = tid >> 3, sslot = tid & 7;          // staging: thread -> (row, slot)

  f32x4 acc[4][4];
#pragma unroll
  for (int i = 0; i < 4; ++i)
#pragma unroll
    for (int j = 0; j < 4; ++j) acc[i][j] = (f32x4){0.f, 0.f, 0.f, 0.f};

  int kg = lane >> 4, lr = lane & 15;

  for (int k0 = 0; k0 < K; k0 += 64) {
#pragma unroll
    for (int it = 0; it < 4; ++it) {
      int row = it * 32 + srow;                  // 32 rows per iteration
      const bf16_t* ga = Abase + (size_t)row * K + k0 + ((sslot ^ (row & 7)) * 8);
      const bf16_t* gb = Bbase + (size_t)row * K + k0 + ((sslot ^ (row & 7)) * 8);
      gload_lds16(ga, As + (size_t)(it * 256 + wave * 64) * 8);
      gload_lds16(gb, Bs + (size_t)(it * 256 + wave * 64) * 8);
    }
    __syncthreads();
#pragma unroll
    for (int ks2 = 0; ks2 < 2; ++ks2) {
      int j = ks2 * 4 + kg;
      bf16x8 af[4], bfv[4];
#pragma unroll
      for (int i = 0; i < 4; ++i) {
        int ra = wm * 64 + i * 16 + lr;
        int rb = wn * 64 + i * 16 + lr;
        af[i]  = *(const bf16x8*)((const char*)As + ra * 128 + ((j ^ (ra & 7)) * 16));
        bfv[i] = *(const bf16x8*)((const char*)Bs + rb * 128 + ((j ^ (rb & 7)) * 16));
      }
#pragma unroll
      for (int i = 0; i < 4; ++i)
#pragma unroll
        for (int jj = 0; jj < 4; ++jj)
          acc[i][jj] = __builtin_amdgcn_mfma_f32_16x16x32_bf16(af[i], bfv[jj], acc[i][jj], 0, 0, 0);
    }
    __syncthreads();
  }

#pragma unroll
  for (int i = 0; i < 4; ++i) {
    int r0 = by * 128 + wm * 64 + i * 16 + ((lane >> 4) << 2);
#pragma unroll
    for (int j = 0; j < 4; ++j) {
      int c = bx * 128 + wn * 64 + j * 16 + (lane & 15);
      OT* Cp = C + (size_t)r0 * N + c;
#pragma unroll
      for (int q = 0; q < 4; ++q) Cp[(size_t)q * N] = (OT)acc[i][j][q];
    }
  }
}

// ---------- beta / g ----------
__global__ __launch_bounds__(64)
void k_ab(const float* __restrict__ hidden, const float* __restrict__ Wa,
          const float* __restrict__ Wb, const float* __restrict__ A_log,
          const float* __restrict__ dt_bias, float* __restrict__ g_out,
          float* __restrict__ beta_out) {
  int row = blockIdx.x;
  int lane = threadIdx.x;
  float accA[6] = {0, 0, 0, 0, 0, 0};
  float accB[6] = {0, 0, 0, 0, 0, 0};
  const float* h = hidden + (size_t)row * CC;
  for (int c = lane; c < CC; c += 64) {
    float x = h[c];
    const float* wa = Wa + c * 6;
    const float* wb = Wb + c * 6;
#pragma unroll
    for (int j = 0; j < 6; ++j) {
      accA[j] += x * wa[j];
      accB[j] += x * wb[j];
    }
  }
#pragma unroll
  for (int j = 0; j < 6; ++j) {
    for (int off = 32; off; off >>= 1) {
      accA[j] += __shfl_down(accA[j], off);
      accB[j] += __shfl_down(accB[j], off);
    }
  }
  if (lane == 0) {
#pragma unroll
    for (int j = 0; j < 6; ++j) {
      float a = accA[j] + dt_bias[j];
      float sp = (a > 20.f) ? a : log1pf(expf(a));
      g_out[(size_t)row * 6 + j] = -expf(A_log[j]) * sp;
      beta_out[(size_t)row * 6 + j] = 1.f / (1.f + expf(-accB[j]));
    }
  }
}

// ---------- depthwise causal conv(4) + SiLU (+ optional L2 norm); bf16 input ----------
__global__ void k_conv_silu(const bf16_t* __restrict__ pre, int ldpre, int col0,
                            const float* __restrict__ w, float* __restrict__ out,
                            bf16_t* __restrict__ out16, int ld_out, int do_norm) {
  int row = blockIdx.x;     // b*T + t
  int t = row & (TT - 1);
  int h = blockIdx.y;
  int kk = threadIdx.x;
  int perH = blockDim.x;
  int ch = h * perH + kk;
  const float* wp = w + ch * 4;
  float y = 0.f;
#pragma unroll
  for (int i = 0; i < 4; ++i) {
    int tt = t - 3 + i;
    if (tt >= 0) y += wp[i] * (float)pre[(size_t)(row - 3 + i) * ldpre + col0 + ch];
  }
  float s = y / (1.f + expf(-y));
  if (do_norm) {
    float ss = s * s;
#pragma unroll
    for (int off = 32; off; off >>= 1) ss += __shfl_down(ss, off);
    __shared__ float red[2];
    if ((threadIdx.x & 63) == 0) red[threadIdx.x >> 6] = ss;
    __syncthreads();
    float nrm = sqrtf(red[0] + red[1]);
    s = s / (nrm + 1e-6f);
  }
  if (out) out[(size_t)row * ld_out + ch] = s;
  if (out16) out16[(size_t)row * ld_out + ch] = (bf16_t)s;
}

// ============ chunked gated delta rule ============
// Pass 1 (R8's UT transform, 8-wave version): 512 thr; phase D = 3 n-tiles/wave
// for 2 waves/SIMD latency hiding. Math identical to the verified R8 kernel.
__global__ __launch_bounds__(512, 2)
void k_chunk1(const bf16_t* __restrict__ kb16, float* dv,
              const float* __restrict__ gdec, const float* __restrict__ beta,
              bf16_t* __restrict__ Wn16, bf16_t* __restrict__ khatT16,
              float* __restrict__ bcum) {
  __shared__ __align__(16) bf16_t ksh[64 * 128];    // 16KB [t][k] swizzled
  __shared__ __align__(16) bf16_t Mb[64 * 64];      // 8KB  [t][s] = -M, swizzled
  __shared__ __align__(16) bf16_t Tdl[4 * 16 * 32]; // 4KB  diag-block inverses, k:16..31 zero
  __shared__ __align__(16) bf16_t Yb[384 * 32];     // 24KB [n][k] Ytmp (B-frag layout), k:16..31 zero
  __shared__ __align__(16) bf16_t Xall[384 * 64];   // 48KB [n][s] solved X (B-frag layout)
  __shared__ float bc[64], bet[64];

  int tid = threadIdx.x;
  int bh = blockIdx.y, c = blockIdx.x;
  int b = bh / HH, h = bh % HH;
  int r0 = b * TT + c * CL;
  size_t cb = (size_t)bh * NC + c;
  int wq = tid >> 6, l = tid & 63;
  int lr = l & 15, lg = l >> 4;

  // ---- phase A: stage k chunk (pre-XOR'd source -> swizzled LDS), g-cumsum ----
#pragma unroll
  for (int it = 0; it < 2; ++it) {
    int idx = it * 512 + tid;
    int t = idx >> 4, p = idx & 15;
    int kslot = p ^ (t & 7);
    gload_lds16(kb16 + (size_t)(r0 + t) * KD + h * KK + kslot * 8,
                ksh + (size_t)idx * 8);
  }
  if (tid < 64) {
    float val = gdec[(size_t)(r0 + tid) * HH + h];
    bet[tid] = beta[(size_t)(r0 + tid) * HH + h];
#pragma unroll
    for (int off = 1; off < 64; off <<= 1) {
      float o = __shfl_up(val, off, 64);
      if (tid >= off) val += o;
    }
    bc[tid] = val;
    bcum[cb * CL + tid] = val;
  }
  __syncthreads();
  float bL = bc[63];

  // ---- phase B: -M via MFMA (waves 0-3) -> Mb; zero-init Xall/Yb/Tdl ----
  {
    f32x4 z4 = (f32x4){0.f, 0.f, 0.f, 0.f};
#pragma unroll
    for (int i = 0; i < 6; ++i) ((f32x4*)Xall)[i * 512 + tid] = z4;
#pragma unroll
    for (int i = 0; i < 3; ++i) ((f32x4*)Yb)[i * 512 + tid] = z4;
    if (tid < 256) ((f32x4*)Tdl)[tid] = z4;
  }
  if (wq < 4) {
    f32x4 pacc[4];
#pragma unroll
    for (int sf = 0; sf < 4; ++sf) pacc[sf] = (f32x4){0.f, 0.f, 0.f, 0.f};
#pragma unroll
    for (int ks_ = 0; ks_ < 4; ++ks_) {
      int trow = wq * 16 + lr;
      bf16x8 aK = *(const bf16x8*)((const char*)ksh + trow * 256 + (((ks_ * 4 + lg) * 16) ^ ((trow & 7) << 4)));
#pragma unroll
      for (int sf = 0; sf < 4; ++sf) {
        int srow = sf * 16 + lr;
        bf16x8 bK = *(const bf16x8*)((const char*)ksh + srow * 256 + (((ks_ * 4 + lg) * 16) ^ ((srow & 7) << 4)));
        pacc[sf] = __builtin_amdgcn_mfma_f32_16x16x32_bf16(aK, bK, pacc[sf], 0, 0, 0);
      }
    }
#pragma unroll
    for (int sf = 0; sf < 4; ++sf)
#pragma unroll
      for (int q = 0; q < 4; ++q) {
        int t = wq * 16 + lg * 4 + q;
        int s = sf * 16 + lr;
        float val = (s < t) ? -bet[t] * __expf(bc[t] - bc[s]) * pacc[sf][q] : 0.f;
        *(bf16_t*)((char*)Mb + t * 128 + ((s * 2) ^ ((t & 7) << 4))) = (bf16_t)val;
      }
  }
  __syncthreads();

  // ---- phase C: diag-block inverses (threads 0..63) || khatT16 (threads 64..191) ----
  if (tid < 64) {
    int d = tid >> 4, cc = tid & 15;
    float x[16];
#pragma unroll
    for (int s = 0; s < 16; ++s) x[s] = (s == cc) ? 1.f : 0.f;
#pragma unroll
    for (int r = 1; r < 16; ++r) {
      float a = 0.f;
#pragma unroll
      for (int s = 0; s < r; ++s) {
        float m = (float)*(const bf16_t*)((const char*)Mb + (16 * d + r) * 128 +
                    (((16 * d + s) * 2) ^ ((r & 7) << 4)));
        a += m * x[s];
      }
      x[r] += a;
    }
#pragma unroll
    for (int r = 0; r < 16; ++r)
      *(bf16_t*)((char*)Tdl + d * 1024 + r * 64 +
          ((((cc >> 3) * 16) ^ ((r & 3) << 4)) + (cc & 7) * 2)) = (bf16_t)x[r];
  } else if (tid < 192) {
    int kk = tid - 64;
    bf16_t* kout = khatT16 + cb * (size_t)(KK * CL) + (size_t)kk * CL;
#pragma unroll
    for (int t8 = 0; t8 < 8; ++t8) {
      union { bf16x8 v; bf16_t e[8]; } u;
#pragma unroll
      for (int e = 0; e < 8; ++e) {
        int t = t8 * 8 + e;
        u.e[e] = (bf16_t)(__expf(bL - bc[t]) * ksh_get(ksh, t, kk));
      }
      *(bf16x8*)(kout + t8 * 8) = u.v;
    }
  }
  __syncthreads();

  // ---- phase D: 4-stage block solve, 3 n-tiles per wave (8 waves) ----
  const int nbase = wq * 48;
#pragma unroll
  for (int st = 0; st < 4; ++st) {
#pragma unroll
    for (int nt = 0; nt < 3; ++nt) {
      const int n0 = nbase + nt * 16;
      const bool isv = (n0 < 256);
      const int n = n0 + lr;
      f32x4 acc = (f32x4){0.f, 0.f, 0.f, 0.f};
      if (isv) {
#pragma unroll
        for (int q = 0; q < 4; ++q) {
          int t = st * 16 + lg * 4 + q;
          acc[q] = bet[t] * dv[(size_t)(r0 + t) * VD + h * VV + n];
        }
      } else {
        int kk = n - 256;
#pragma unroll
        for (int q = 0; q < 4; ++q) {
          int t = st * 16 + lg * 4 + q;
          acc[q] = bet[t] * __expf(bc[t]) * ksh_get(ksh, t, kk);
        }
      }
      // acc += (-M) X  (K=32 pair-packed; unwritten X regions are zero)
#pragma unroll
      for (int p = 0; p < 2; ++p) {
        if ((p == 0 && st >= 1) || (p == 1 && st == 3)) {
          int arow = st * 16 + lr;
          bf16x8 aM = *(const bf16x8*)((const char*)Mb + arow * 128 +
                         (((p * 4 + lg) * 16) ^ ((arow & 7) << 4)));
          bf16x8 bX = *(const bf16x8*)((const char*)Xall + n * 128 +
                         (((p * 4 + lg) * 16) ^ ((n & 7) << 4)));
          acc = __builtin_amdgcn_mfma_f32_16x16x32_bf16(aM, bX, acc, 0, 0, 0);
        }
      }
      // Ytmp -> Yb (B-frag layout, own rows only)
#pragma unroll
      for (int q = 0; q < 4; ++q) {
        int tq = lg * 4 + q;
        *(bf16_t*)((char*)Yb + n * 64 +
            ((((tq >> 3) * 16) ^ ((n & 3) << 4)) + (tq & 7) * 2)) = (bf16_t)acc[q];
      }
      // X_st = T_st @ Ytmp
      f32x4 acc2 = (f32x4){0.f, 0.f, 0.f, 0.f};
      {
        bf16x8 aT = *(const bf16x8*)((const char*)Tdl + st * 1024 + lr * 64 +
                       ((lg * 16) ^ ((lr & 3) << 4)));
        bf16x8 bY = *(const bf16x8*)((const char*)Yb + n * 64 +
                       ((lg * 16) ^ ((n & 3) << 4)));
        acc2 = __builtin_amdgcn_mfma_f32_16x16x32_bf16(aT, bY, acc2, 0, 0, 0);
      }
      // store X for later stages + final outputs
      if (st < 3) {
#pragma unroll
        for (int q = 0; q < 4; ++q) {
          int s = st * 16 + lg * 4 + q;
          *(bf16_t*)((char*)Xall + n * 128 +
              ((((s >> 3) * 16) ^ ((n & 7) << 4)) + (s & 7) * 2)) = (bf16_t)acc2[q];
        }
      }
      if (isv) {
#pragma unroll
        for (int q = 0; q < 4; ++q) {
          int t = st * 16 + lg * 4 + q;
          dv[(size_t)(r0 + t) * VD + h * VV + n] = acc2[q];
        }
      } else {
        int kk = n - 256;
#pragma unroll
        for (int q = 0; q < 4; ++q) {
          int t = st * 16 + lg * 4 + q;
          Wn16[(cb * CL + t) * KK + kk] = (bf16_t)(-acc2[q]);
        }
      }
    }
  }
}

// Pass 2: MFMA state propagation. Grid (8 vtiles of 32, 12 bh), 256 thr (4 waves).
__global__ __launch_bounds__(256, 1)
void k_chunk2(const float* __restrict__ dv, const bf16_t* __restrict__ Wn16,
              const bf16_t* __restrict__ khatT16, const float* __restrict__ bcum,
              bf16_t* __restrict__ states, bf16_t* __restrict__ Zt) {
  __shared__ __align__(16) bf16_t St[32 * 128];   // [v][k], XOR-swizzled
  __shared__ __align__(16) bf16_t Zl[32 * 64];    // [v][t], XOR-swizzled
  int tid = threadIdx.x;
  int vt = blockIdx.x, bh = blockIdx.y;
  int b = bh / HH, h = bh % HH;
  int wq = tid >> 6, l = tid & 63;
  int lr = l & 15, lg = l >> 4;

  f32x4 acc[2][2];
#pragma unroll
  for (int kf = 0; kf < 2; ++kf)
#pragma unroll
    for (int vf = 0; vf < 2; ++vf) acc[kf][vf] = (f32x4){0.f, 0.f, 0.f, 0.f};

  for (int c = 0; c < NC; ++c) {
    size_t cb = (size_t)bh * NC + c;
    int r0 = b * TT + c * CL;
    float ebL = __expf(bcum[cb * CL + 63]);

#pragma unroll
    for (int kf = 0; kf < 2; ++kf)
#pragma unroll
      for (int vf = 0; vf < 2; ++vf)
#pragma unroll
        for (int q = 0; q < 4; ++q) {
          int k = wq * 32 + kf * 16 + lg * 4 + q;
          int v = vf * 16 + lr;
          *(bf16_t*)((char*)St + v * 256 + ((k * 2) ^ ((v & 7) << 4))) = (bf16_t)acc[kf][vf][q];
        }
    __syncthreads();

#pragma unroll
    for (int it = 0; it < 2; ++it) {
      int idx = tid + it * 256;
      int v = idx >> 4, slot = idx & 15;
      bf16x8 val = *(const bf16x8*)((const char*)St + v * 256 + ((slot * 16) ^ ((v & 7) << 4)));
      *(bf16x8*)(states + ((size_t)cb * 256 + vt * 32 + v) * 128 + slot * 8) = val;
    }

    f32x4 zacc[2];
#pragma unroll
    for (int vf = 0; vf < 2; ++vf)
#pragma unroll
      for (int q = 0; q < 4; ++q) {
        int t = wq * 16 + lg * 4 + q;
        zacc[vf][q] = dv[(size_t)(r0 + t) * VD + h * VV + vt * 32 + vf * 16 + lr];
      }
#pragma unroll
    for (int ks_ = 0; ks_ < 4; ++ks_) {
      bf16x8 aW = *(const bf16x8*)(Wn16 + (cb * CL + wq * 16 + lr) * KK + ks_ * 32 + lg * 8);
#pragma unroll
      for (int vf = 0; vf < 2; ++vf) {
        int v = vf * 16 + lr;
        bf16x8 bS = *(const bf16x8*)((const char*)St + v * 256 + (((ks_ * 32 + lg * 8) * 2) ^ ((v & 7) << 4)));
        zacc[vf] = __builtin_amdgcn_mfma_f32_16x16x32_bf16(aW, bS, zacc[vf], 0, 0, 0);
      }
    }
#pragma unroll
    for (int vf = 0; vf < 2; ++vf)
#pragma unroll
      for (int q = 0; q < 4; ++q) {
        int t = wq * 16 + lg * 4 + q;
        int v = vf * 16 + lr;
        *(bf16_t*)((char*)Zl + v * 128 + ((t * 2) ^ ((v & 7) << 4))) = (bf16_t)zacc[vf][q];
      }
    __syncthreads();

    {
      int v = tid >> 3, slot = tid & 7;
      bf16x8 val = *(const bf16x8*)((const char*)Zl + v * 128 + ((slot * 16) ^ ((v & 7) << 4)));
      *(bf16x8*)(Zt + ((size_t)cb * 256 + vt * 32 + v) * 64 + slot * 8) = val;
    }
#pragma unroll
    for (int kf = 0; kf < 2; ++kf)
#pragma unroll
      for (int vf = 0; vf < 2; ++vf)
#pragma unroll
        for (int q = 0; q < 4; ++q) acc[kf][vf][q] *= ebL;
#pragma unroll
    for (int ts = 0; ts < 2; ++ts) {
      bf16x8 aK[2], bZ[2];
#pragma unroll
      for (int kf = 0; kf < 2; ++kf)
        aK[kf] = *(const bf16x8*)(khatT16 + (cb * KK + wq * 32 + kf * 16 + lr) * CL + ts * 32 + lg * 8);
#pragma unroll
      for (int vf = 0; vf < 2; ++vf) {
        int v = vf * 16 + lr;
        bZ[vf] = *(const bf16x8*)((const char*)Zl + v * 128 + (((ts * 32 + lg * 8) * 2) ^ ((v & 7) << 4)));
      }
#pragma unroll
      for (int kf = 0; kf < 2; ++kf)
#pragma unroll
        for (int vf = 0; vf < 2; ++vf)
          acc[kf][vf] = __builtin_amdgcn_mfma_f32_16x16x32_bf16(aK[kf], bZ[vf], acc[kf][vf], 0, 0, 0);
    }
  }
}

// Pass 3 (8-wave): o = e^{b_t} q^T S0 + P Z (MFMA) + fused gated RMSNorm.
// states/Zt B-frags hoisted to registers at entry (T14); P on waves 0-3;
// O-phase: 8 waves x 32 v-cols. fgate bf16 with row stride NCAT.
__global__ __launch_bounds__(512, 2)
void k_chunk3(const bf16_t* __restrict__ qb16, const bf16_t* __restrict__ kb16,
              const bf16_t* __restrict__ Zt, const bf16_t* __restrict__ states,
              const float* __restrict__ bcum, const bf16_t* __restrict__ fgate,
              const float* __restrict__ onorm_w, bf16_t* __restrict__ ovd) {
  __shared__ __align__(16) bf16_t qs[64 * 128];   // [t][k] swizzled via pre-XOR source
  __shared__ __align__(16) bf16_t ksh[64 * 128];
  __shared__ __align__(16) bf16_t Pl[64 * 64];    // [t][s] swizzled
  __shared__ float bcs[64];
  __shared__ float sred[8][64];

  int tid = threadIdx.x;
  int c = blockIdx.x, bh = blockIdx.y;
  int b = bh / HH, h = bh % HH;
  int r0 = b * TT + c * CL;
  size_t cb = (size_t)bh * NC + c;
  int wq = tid >> 6, l = tid & 63;
  int lr = l & 15, lg = l >> 4;

  // hoisted global B-frag loads: latency hides under staging + P phase
  bf16x8 bSv[4][2], bZv[2][2];
#pragma unroll
  for (int vj = 0; vj < 2; ++vj) {
    int vrow = wq * 32 + vj * 16 + lr;
#pragma unroll
    for (int ks_ = 0; ks_ < 4; ++ks_)
      bSv[ks_][vj] = *(const bf16x8*)(states + ((size_t)cb * 256 + vrow) * 128 + ks_ * 32 + lg * 8);
#pragma unroll
    for (int ts = 0; ts < 2; ++ts)
      bZv[ts][vj] = *(const bf16x8*)(Zt + ((size_t)cb * 256 + vrow) * 64 + ts * 32 + lg * 8);
  }

  if (tid < 64) bcs[tid] = bcum[cb * CL + tid];
#pragma unroll
  for (int it = 0; it < 2; ++it) {
    int idx = it * 512 + tid;
    int t = idx >> 4, p = idx & 15;
    int kslot = p ^ (t & 7);
    gload_lds16(qb16 + (size_t)(r0 + t) * KD + h * KK + kslot * 8,
                qs + (size_t)idx * 8);
    gload_lds16(kb16 + (size_t)(r0 + t) * KD + h * KK + kslot * 8,
                ksh + (size_t)idx * 8);
  }
  __syncthreads();

  if (wq < 4) {
    f32x4 pacc[4];
#pragma unroll
    for (int sf = 0; sf < 4; ++sf) pacc[sf] = (f32x4){0.f, 0.f, 0.f, 0.f};
#pragma unroll
    for (int ks_ = 0; ks_ < 4; ++ks_) {
      int trow = wq * 16 + lr;
      bf16x8 aQ = *(const bf16x8*)((const char*)qs + trow * 256 + (((ks_ * 4 + lg) * 16) ^ ((trow & 7) << 4)));
#pragma unroll
      for (int sf = 0; sf < 4; ++sf) {
        int srow = sf * 16 + lr;
        bf16x8 bK = *(const bf16x8*)((const char*)ksh + srow * 256 + (((ks_ * 4 + lg) * 16) ^ ((srow & 7) << 4)));
        pacc[sf] = __builtin_amdgcn_mfma_f32_16x16x32_bf16(aQ, bK, pacc[sf], 0, 0, 0);
      }
    }
#pragma unroll
    for (int sf = 0; sf < 4; ++sf)
#pragma unroll
      for (int q = 0; q < 4; ++q) {
        int t = wq * 16 + lg * 4 + q;
        int s = sf * 16 + lr;
        float val = (s <= t) ? pacc[sf][q] * __expf(bcs[t] - bcs[s]) : 0.f;
        *(bf16_t*)((char*)Pl + t * 128 + ((s * 2) ^ ((t & 7) << 4))) = (bf16_t)val;
      }
  }
  __syncthreads();

  // O: wave wq covers v cols wq*32..+31
  f32x4 oacc[4][2];
#pragma unroll
  for (int ti = 0; ti < 4; ++ti)
#pragma unroll
    for (int vj = 0; vj < 2; ++vj) oacc[ti][vj] = (f32x4){0.f, 0.f, 0.f, 0.f};

#pragma unroll
  for (int ks_ = 0; ks_ < 4; ++ks_) {
    bf16x8 aQ[4];
#pragma unroll
    for (int ti = 0; ti < 4; ++ti) {
      int t = ti * 16 + lr;
      union { bf16x8 v; bf16_t e[8]; } u;
      u.v = *(const bf16x8*)((const char*)qs + t * 256 + (((ks_ * 4 + lg) * 16) ^ ((t & 7) << 4)));
      float eb = __expf(bcs[t]);
#pragma unroll
      for (int e = 0; e < 8; ++e) u.e[e] = (bf16_t)((float)u.e[e] * eb);
      aQ[ti] = u.v;
    }
#pragma unroll
    for (int vj = 0; vj < 2; ++vj)
#pragma unroll
      for (int ti = 0; ti < 4; ++ti)
        oacc[ti][vj] = __builtin_amdgcn_mfma_f32_16x16x32_bf16(aQ[ti], bSv[ks_][vj], oacc[ti][vj], 0, 0, 0);
  }
#pragma unroll
  for (int ts = 0; ts < 2; ++ts) {
    bf16x8 aP[4];
#pragma unroll
    for (int ti = 0; ti < 4; ++ti) {
      int t = ti * 16 + lr;
      aP[ti] = *(const bf16x8*)((const char*)Pl + t * 128 + (((ts * 4 + lg) * 16) ^ ((t & 7) << 4)));
    }
#pragma unroll
    for (int vj = 0; vj < 2; ++vj)
#pragma unroll
      for (int ti = 0; ti < 4; ++ti)
        oacc[ti][vj] = __builtin_amdgcn_mfma_f32_16x16x32_bf16(aP[ti], bZv[ts][vj], oacc[ti][vj], 0, 0, 0);
  }

  // ---- fused gated RMSNorm (8-wave reduce) ----
  float sum2[4][4];
#pragma unroll
  for (int ti = 0; ti < 4; ++ti)
#pragma unroll
    for (int q = 0; q < 4; ++q) {
      float s = 0.f;
#pragma unroll
      for (int vj = 0; vj < 2; ++vj) s += oacc[ti][vj][q] * oacc[ti][vj][q];
      sum2[ti][q] = s;
    }
#pragma unroll
  for (int mk = 1; mk < 16; mk <<= 1)
#pragma unroll
    for (int ti = 0; ti < 4; ++ti)
#pragma unroll
      for (int q = 0; q < 4; ++q)
        sum2[ti][q] += __shfl_xor(sum2[ti][q], mk, 64);
  if (lr == 0) {
#pragma unroll
    for (int ti = 0; ti < 4; ++ti)
#pragma unroll
      for (int q = 0; q < 4; ++q)
        sred[wq][ti * 16 + lg * 4 + q] = sum2[ti][q];
  }
  __syncthreads();

  float onv[2];
#pragma unroll
  for (int vj = 0; vj < 2; ++vj) onv[vj] = onorm_w[wq * 32 + vj * 16 + lr];
#pragma unroll
  for (int ti = 0; ti < 4; ++ti)
#pragma unroll
    for (int q = 0; q < 4; ++q) {
      int t = ti * 16 + lg * 4 + q;
      float tot = 0.f;
#pragma unroll
      for (int w = 0; w < 8; ++w) tot += sred[w][t];
      float rn = rsqrtf(tot * (1.f / VV) + 1e-5f);
#pragma unroll
      for (int vj = 0; vj < 2; ++vj) {
        int v = wq * 32 + vj * 16 + lr;
        float gate = (float)fgate[(size_t)(r0 + t) * NCAT + h * VV + v];
        float y = oacc[ti][vj][q] * rn * onv[vj] * (gate / (1.f + expf(-gate)));
        ovd[(size_t)(r0 + t) * VD + h * VV + v] = (bf16_t)y;
      }
    }
}

extern "C" void kernel_launch(void* const* d_in, const int* in_sizes, int n_in,
                              void* d_out, int out_size, void* d_ws, size_t ws_size,
                              hipStream_t stream) {
  const float* hidden = (const float*)d_in[0];
  const float* Wq = (const float*)d_in[1];
  const float* Wk = (const float*)d_in[2];
  const float* Wv = (const float*)d_in[3];
  const float* Wa = (const float*)d_in[4];
  const float* Wb = (const float*)d_in[5];
  const float* A_log = (const float*)d_in[6];
  const float* dt_bias = (const float*)d_in[7];
  const float* qconv = (const float*)d_in[8];
  const float* kconv = (const float*)d_in[9];
  const float* vconv = (const float*)d_in[10];
  const float* Wg = (const float*)d_in[11];
  const float* onorm = (const float*)d_in[12];
  const float* Wo = (const float*)d_in[13];
  float* out = (float*)d_out;

  char* ws = (char*)d_ws;
  size_t off = 0;
  auto alloc = [&](size_t bytes) {
    void* p = ws + off;
    off += (bytes + 255) & ~(size_t)255;
    return p;
  };
  const int M = BB * TT;  // 2048
  bf16_t* hbf   = (bf16_t*)alloc((size_t)M * CC * 2);       // aliased by Wn16/khatT16 later
  bf16_t* WcatT = (bf16_t*)alloc((size_t)NCAT * CC * 2);
  bf16_t* WoT   = (bf16_t*)alloc((size_t)CC * VD * 2);
  bf16_t* fall  = (bf16_t*)alloc((size_t)M * NCAT * 2);     // fused q|k|v|gate projection (bf16)
  bf16_t* states = (bf16_t*)alloc((size_t)12 * NC * VV * KK * 2);  // 12.6MB
  float*  kn    = (float*) alloc((size_t)M * KD * 4);       // aliased by Zt later
  float*  vn    = (float*) alloc((size_t)M * VD * 4);       // becomes Dv in pass 1
  float*  gdec  = (float*) alloc((size_t)M * HH * 4);
  float*  beta  = (float*) alloc((size_t)M * HH * 4);
  bf16_t* ovd   = (bf16_t*)alloc((size_t)M * VD * 2);
  bf16_t* qb16  = (bf16_t*)alloc((size_t)M * KD * 2);
  bf16_t* kb16  = (bf16_t*)alloc((size_t)M * KD * 2);
  float*  bcum  = (float*) alloc((size_t)12 * NC * CL * 4);

  // aliases (stream-ordered lifetime separation):
  bf16_t* Wn16    = (bf16_t*)hbf;                     // 12*16*64*128 bf16 = 3.15MB
  bf16_t* khatT16 = Wn16 + (size_t)12 * NC * CL * KK; // +3.15MB (hbf is 8.4MB)
  bf16_t* Zt      = (bf16_t*)kn;                      // 12*16*256*64 bf16 = 6.3MB

  // pre-pass
  k_cvt_bf16<<<(M * CC / 4 + 255) / 256, 256, 0, stream>>>(hidden, hbf, M * CC);
  k_transpose_cvt<<<dim3(KD / 32, CC / 32), dim3(32, 8), 0, stream>>>(Wq, WcatT, CC, KD);
  k_transpose_cvt<<<dim3(KD / 32, CC / 32), dim3(32, 8), 0, stream>>>(Wk, WcatT + (size_t)768 * CC, CC, KD);
  k_transpose_cvt<<<dim3(VD / 32, CC / 32), dim3(32, 8), 0, stream>>>(Wv, WcatT + (size_t)1536 * CC, CC, VD);
  k_transpose_cvt<<<dim3(VD / 32, CC / 32), dim3(32, 8), 0, stream>>>(Wg, WcatT + (size_t)3072 * CC, CC, VD);
  k_transpose_cvt<<<dim3(CC / 32, VD / 32), dim3(32, 8), 0, stream>>>(Wo, WoT, VD, CC);

  // fused projection GEMM: [2048,2048] x [4608,2048]^T -> [2048,4608] bf16
  k_gemm_bt<bf16_t><<<dim3(NCAT / 128, M / 128), 256, 0, stream>>>(hbf, WcatT, fall, M, NCAT, CC);

  // beta / g
  k_ab<<<M, 64, 0, stream>>>(hidden, Wa, Wb, A_log, dt_bias, gdec, beta);

  // conv + silu (+norm for q,k)
  k_conv_silu<<<dim3(M, HH), 128, 0, stream>>>(fall, NCAT, 0, qconv, nullptr, qb16, KD, 1);
  k_conv_silu<<<dim3(M, HH), 128, 0, stream>>>(fall, NCAT, 768, kconv, nullptr, kb16, KD, 1);
  k_conv_silu<<<dim3(M, HH), 256, 0, stream>>>(fall, NCAT, 1536, vconv, vn, nullptr, VD, 0);

  // chunked gated delta rule (hbf dead -> Wn16/khatT16; kn dead -> Zt)
  k_chunk1<<<dim3(NC, 12), 512, 0, stream>>>(kb16, vn, gdec, beta, Wn16, khatT16, bcum);
  k_chunk2<<<dim3(8, 12), 256, 0, stream>>>(vn, Wn16, khatT16, bcum, states, Zt);
  k_chunk3<<<dim3(NC, 12), 512, 0, stream>>>(qb16, kb16, Zt, states, bcum, fall + 3072, onorm, ovd);

  // output projection (f32 out)
  k_gemm_bt<float><<<dim3(CC / 128, M / 128), 256, 0, stream>>>(ovd, WoT, out, M, CC, VD);
}

// Round 16
// 213.600 us; speedup vs baseline: 1.7739x; 1.0610x over previous
//
#include <hip/hip_runtime.h>
#include <hip/hip_bf16.h>
#include <math.h>

typedef __bf16 bf16_t;
typedef __attribute__((ext_vector_type(8))) __bf16 bf16x8;
typedef __attribute__((ext_vector_type(4))) float f32x4;

#define GAS __attribute__((address_space(1)))
#define LAS __attribute__((address_space(3)))

#define BB 2
#define TT 1024
#define CC 2048
#define HH 6
#define KK 128
#define VV 256
#define KD 768
#define VD 1536
#define NQKV 3072
#define NCAT 4608
#define NC 16     // chunks per sequence
#define CL 64     // chunk length

__device__ __forceinline__ void gload_lds16(const void* g, void* l) {
  __builtin_amdgcn_global_load_lds((const GAS void*)g, (LAS void*)l, 16, 0, 0);
}

// scalar read of swizzled [64][128] bf16 tile element (t, kk)
__device__ __forceinline__ float ksh_get(const bf16_t* ksh, int t, int kk) {
  return (float)*(const bf16_t*)((const char*)ksh + t * 256 +
           ((((kk >> 3) ^ (t & 7)) * 16) + (kk & 7) * 2));
}

// ---------- f32 -> bf16 convert ----------
__global__ void k_cvt_bf16(const float* __restrict__ in, bf16_t* __restrict__ out, int n) {
  int i = (blockIdx.x * blockDim.x + threadIdx.x) * 4;
  if (i + 3 < n) {
    float4 v = *(const float4*)(in + i);
    out[i + 0] = (bf16_t)v.x;
    out[i + 1] = (bf16_t)v.y;
    out[i + 2] = (bf16_t)v.z;
    out[i + 3] = (bf16_t)v.w;
  }
}

// ---------- transpose [Kd,Nd] f32 -> [Nd,Kd] bf16 ----------
__global__ void k_transpose_cvt(const float* __restrict__ in, bf16_t* __restrict__ out,
                                int Kd, int Nd) {
  __shared__ float t[32][33];
  int n0 = blockIdx.x * 32, k0 = blockIdx.y * 32;
  int tx = threadIdx.x, ty = threadIdx.y;
#pragma unroll
  for (int i = 0; i < 32; i += 8)
    t[ty + i][tx] = in[(size_t)(k0 + ty + i) * Nd + n0 + tx];
  __syncthreads();
#pragma unroll
  for (int i = 0; i < 32; i += 8)
    out[(size_t)(n0 + ty + i) * Kd + k0 + tx] = (bf16_t)t[tx][ty + i];
}

// ---------- bf16 MFMA GEMM: C[M,N] = A[M,K] * B^T (B is [N,K]) ----------
// BM=128, BN template (128 or 96), BK=64, XOR-swizzled LDS via pre-swizzled
// global source -> conflict-free ds_read_b128. XCD-swizzled grid.
template <int BN, typename OT>
__global__ __launch_bounds__(256, 2)
void k_gemm_bt(const bf16_t* __restrict__ A, const bf16_t* __restrict__ B,
               OT* __restrict__ C, int M, int N, int K) {
  constexpr int NFRG = BN / 32;        // per-wave n fragments
  constexpr int NB_IT = BN / 32;       // B staging iterations (BN*8/256)
  __shared__ __align__(16) bf16_t As[128 * 64];
  __shared__ __align__(16) bf16_t Bs[BN * 64];
  int tid = threadIdx.x;
  int wave = tid >> 6, lane = tid & 63;
  int wm = wave >> 1, wn = wave & 1;

  // bijective XCD-aware swizzle (m204): contiguous wgid chunk per XCD
  int gx = gridDim.x;
  int nwg = gx * gridDim.y;
  int lin = blockIdx.y * gx + blockIdx.x;
  int q8 = nwg >> 3, r8 = nwg & 7;
  int xcd = lin & 7, off8 = lin >> 3;
  int wgid = (xcd < r8 ? xcd * (q8 + 1) : r8 * (q8 + 1) + (xcd - r8) * q8) + off8;
  int bx = wgid % gx, by = wgid / gx;

  const bf16_t* Abase = A + (size_t)by * 128 * K;
  const bf16_t* Bbase = B + (size_t)bx * BN * K;

  f32x4 acc[4][NFRG];
#pragma unroll
  for (int i = 0; i < 4; ++i)
#pragma unroll
    for (int j = 0; j < NFRG; ++j) acc[i][j] = (f32x4){0.f, 0.f, 0.f, 0.f};

  int kg = lane >> 4, lr = lane & 15;

  for (int k0 = 0; k0 < K; k0 += 64) {
#pragma unroll
    for (int it = 0; it < 4; ++it) {
      int idx = it * 256 + tid;
      int row = idx >> 3, slot = idx & 7;
      const bf16_t* ga = Abase + (size_t)row * K + k0 + ((slot ^ (row & 7)) * 8);
      gload_lds16(ga, As + (size_t)(it * 256 + wave * 64) * 8);
    }
#pragma unroll
    for (int it = 0; it < NB_IT; ++it) {
      int idx = it * 256 + tid;
      int row = idx >> 3, slot = idx & 7;
      const bf16_t* gb = Bbase + (size_t)row * K + k0 + ((slot ^ (row & 7)) * 8);
      gload_lds16(gb, Bs + (size_t)(it * 256 + wave * 64) * 8);
    }
    __syncthreads();
#pragma unroll
    for (int ks2 = 0; ks2 < 2; ++ks2) {
      int j = ks2 * 4 + kg;
      bf16x8 af[4], bfv[NFRG];
#pragma unroll
      for (int i = 0; i < 4; ++i) {
        int ra = wm * 64 + i * 16 + lr;
        af[i] = *(const bf16x8*)((const char*)As + ra * 128 + ((j ^ (ra & 7)) * 16));
      }
#pragma unroll
      for (int i = 0; i < NFRG; ++i) {
        int rb = wn * (BN / 2) + i * 16 + lr;
        bfv[i] = *(const bf16x8*)((const char*)Bs + rb * 128 + ((j ^ (rb & 7)) * 16));
      }
#pragma unroll
      for (int i = 0; i < 4; ++i)
#pragma unroll
        for (int jj = 0; jj < NFRG; ++jj)
          acc[i][jj] = __builtin_amdgcn_mfma_f32_16x16x32_bf16(af[i], bfv[jj], acc[i][jj], 0, 0, 0);
    }
    __syncthreads();
  }

#pragma unroll
  for (int i = 0; i < 4; ++i) {
    int r0 = by * 128 + wm * 64 + i * 16 + ((lane >> 4) << 2);
#pragma unroll
    for (int j = 0; j < NFRG; ++j) {
      int c = bx * BN + wn * (BN / 2) + j * 16 + (lane & 15);
      OT* Cp = C + (size_t)r0 * N + c;
#pragma unroll
      for (int q = 0; q < 4; ++q) Cp[(size_t)q * N] = (OT)acc[i][j][q];
    }
  }
}

// ---------- beta / g ----------
__global__ __launch_bounds__(64)
void k_ab(const float* __restrict__ hidden, const float* __restrict__ Wa,
          const float* __restrict__ Wb, const float* __restrict__ A_log,
          const float* __restrict__ dt_bias, float* __restrict__ g_out,
          float* __restrict__ beta_out) {
  int row = blockIdx.x;
  int lane = threadIdx.x;
  float accA[6] = {0, 0, 0, 0, 0, 0};
  float accB[6] = {0, 0, 0, 0, 0, 0};
  const float* h = hidden + (size_t)row * CC;
  for (int c = lane; c < CC; c += 64) {
    float x = h[c];
    const float* wa = Wa + c * 6;
    const float* wb = Wb + c * 6;
#pragma unroll
    for (int j = 0; j < 6; ++j) {
      accA[j] += x * wa[j];
      accB[j] += x * wb[j];
    }
  }
#pragma unroll
  for (int j = 0; j < 6; ++j) {
    for (int off = 32; off; off >>= 1) {
      accA[j] += __shfl_down(accA[j], off);
      accB[j] += __shfl_down(accB[j], off);
    }
  }
  if (lane == 0) {
#pragma unroll
    for (int j = 0; j < 6; ++j) {
      float a = accA[j] + dt_bias[j];
      float sp = (a > 20.f) ? a : log1pf(expf(a));
      g_out[(size_t)row * 6 + j] = -expf(A_log[j]) * sp;
      beta_out[(size_t)row * 6 + j] = 1.f / (1.f + expf(-accB[j]));
    }
  }
}

// ---------- depthwise causal conv(4) + SiLU (+ optional L2 norm); bf16 input ----------
__global__ void k_conv_silu(const bf16_t* __restrict__ pre, int ldpre, int col0,
                            const float* __restrict__ w, float* __restrict__ out,
                            bf16_t* __restrict__ out16, int ld_out, int do_norm) {
  int row = blockIdx.x;     // b*T + t
  int t = row & (TT - 1);
  int h = blockIdx.y;
  int kk = threadIdx.x;
  int perH = blockDim.x;
  int ch = h * perH + kk;
  const float* wp = w + ch * 4;
  float y = 0.f;
#pragma unroll
  for (int i = 0; i < 4; ++i) {
    int tt = t - 3 + i;
    if (tt >= 0) y += wp[i] * (float)pre[(size_t)(row - 3 + i) * ldpre + col0 + ch];
  }
  float s = y / (1.f + expf(-y));
  if (do_norm) {
    float ss = s * s;
#pragma unroll
    for (int off = 32; off; off >>= 1) ss += __shfl_down(ss, off);
    __shared__ float red[2];
    if ((threadIdx.x & 63) == 0) red[threadIdx.x >> 6] = ss;
    __syncthreads();
    float nrm = sqrtf(red[0] + red[1]);
    s = s / (nrm + 1e-6f);
  }
  if (out) out[(size_t)row * ld_out + ch] = s;
  if (out16) out16[(size_t)row * ld_out + ch] = (bf16_t)s;
}

// ============ chunked gated delta rule ============
// Pass 1 (R8's UT transform, 8-wave version): 512 thr; phase D = 3 n-tiles/wave.
__global__ __launch_bounds__(512, 2)
void k_chunk1(const bf16_t* __restrict__ kb16, float* dv,
              const float* __restrict__ gdec, const float* __restrict__ beta,
              bf16_t* __restrict__ Wn16, bf16_t* __restrict__ khatT16,
              float* __restrict__ bcum) {
  __shared__ __align__(16) bf16_t ksh[64 * 128];    // 16KB [t][k] swizzled
  __shared__ __align__(16) bf16_t Mb[64 * 64];      // 8KB  [t][s] = -M, swizzled
  __shared__ __align__(16) bf16_t Tdl[4 * 16 * 32]; // 4KB  diag-block inverses, k:16..31 zero
  __shared__ __align__(16) bf16_t Yb[384 * 32];     // 24KB [n][k] Ytmp (B-frag layout), k:16..31 zero
  __shared__ __align__(16) bf16_t Xall[384 * 64];   // 48KB [n][s] solved X (B-frag layout)
  __shared__ float bc[64], bet[64];

  int tid = threadIdx.x;
  int bh = blockIdx.y, c = blockIdx.x;
  int b = bh / HH, h = bh % HH;
  int r0 = b * TT + c * CL;
  size_t cb = (size_t)bh * NC + c;
  int wq = tid >> 6, l = tid & 63;
  int lr = l & 15, lg = l >> 4;

  // ---- phase A ----
#pragma unroll
  for (int it = 0; it < 2; ++it) {
    int idx = it * 512 + tid;
    int t = idx >> 4, p = idx & 15;
    int kslot = p ^ (t & 7);
    gload_lds16(kb16 + (size_t)(r0 + t) * KD + h * KK + kslot * 8,
                ksh + (size_t)idx * 8);
  }
  if (tid < 64) {
    float val = gdec[(size_t)(r0 + tid) * HH + h];
    bet[tid] = beta[(size_t)(r0 + tid) * HH + h];
#pragma unroll
    for (int off = 1; off < 64; off <<= 1) {
      float o = __shfl_up(val, off, 64);
      if (tid >= off) val += o;
    }
    bc[tid] = val;
    bcum[cb * CL + tid] = val;
  }
  __syncthreads();
  float bL = bc[63];

  // ---- phase B ----
  {
    f32x4 z4 = (f32x4){0.f, 0.f, 0.f, 0.f};
#pragma unroll
    for (int i = 0; i < 6; ++i) ((f32x4*)Xall)[i * 512 + tid] = z4;
#pragma unroll
    for (int i = 0; i < 3; ++i) ((f32x4*)Yb)[i * 512 + tid] = z4;
    if (tid < 256) ((f32x4*)Tdl)[tid] = z4;
  }
  if (wq < 4) {
    f32x4 pacc[4];
#pragma unroll
    for (int sf = 0; sf < 4; ++sf) pacc[sf] = (f32x4){0.f, 0.f, 0.f, 0.f};
#pragma unroll
    for (int ks_ = 0; ks_ < 4; ++ks_) {
      int trow = wq * 16 + lr;
      bf16x8 aK = *(const bf16x8*)((const char*)ksh + trow * 256 + (((ks_ * 4 + lg) * 16) ^ ((trow & 7) << 4)));
#pragma unroll
      for (int sf = 0; sf < 4; ++sf) {
        int srow = sf * 16 + lr;
        bf16x8 bK = *(const bf16x8*)((const char*)ksh + srow * 256 + (((ks_ * 4 + lg) * 16) ^ ((srow & 7) << 4)));
        pacc[sf] = __builtin_amdgcn_mfma_f32_16x16x32_bf16(aK, bK, pacc[sf], 0, 0, 0);
      }
    }
#pragma unroll
    for (int sf = 0; sf < 4; ++sf)
#pragma unroll
      for (int q = 0; q < 4; ++q) {
        int t = wq * 16 + lg * 4 + q;
        int s = sf * 16 + lr;
        float val = (s < t) ? -bet[t] * __expf(bc[t] - bc[s]) * pacc[sf][q] : 0.f;
        *(bf16_t*)((char*)Mb + t * 128 + ((s * 2) ^ ((t & 7) << 4))) = (bf16_t)val;
      }
  }
  __syncthreads();

  // ---- phase C ----
  if (tid < 64) {
    int d = tid >> 4, cc = tid & 15;
    float x[16];
#pragma unroll
    for (int s = 0; s < 16; ++s) x[s] = (s == cc) ? 1.f : 0.f;
#pragma unroll
    for (int r = 1; r < 16; ++r) {
      float a = 0.f;
#pragma unroll
      for (int s = 0; s < r; ++s) {
        float m = (float)*(const bf16_t*)((const char*)Mb + (16 * d + r) * 128 +
                    (((16 * d + s) * 2) ^ ((r & 7) << 4)));
        a += m * x[s];
      }
      x[r] += a;
    }
#pragma unroll
    for (int r = 0; r < 16; ++r)
      *(bf16_t*)((char*)Tdl + d * 1024 + r * 64 +
          ((((cc >> 3) * 16) ^ ((r & 3) << 4)) + (cc & 7) * 2)) = (bf16_t)x[r];
  } else if (tid < 192) {
    int kk = tid - 64;
    bf16_t* kout = khatT16 + cb * (size_t)(KK * CL) + (size_t)kk * CL;
#pragma unroll
    for (int t8 = 0; t8 < 8; ++t8) {
      union { bf16x8 v; bf16_t e[8]; } u;
#pragma unroll
      for (int e = 0; e < 8; ++e) {
        int t = t8 * 8 + e;
        u.e[e] = (bf16_t)(__expf(bL - bc[t]) * ksh_get(ksh, t, kk));
      }
      *(bf16x8*)(kout + t8 * 8) = u.v;
    }
  }
  __syncthreads();

  // ---- phase D ----
  const int nbase = wq * 48;
#pragma unroll
  for (int st = 0; st < 4; ++st) {
#pragma unroll
    for (int nt = 0; nt < 3; ++nt) {
      const int n0 = nbase + nt * 16;
      const bool isv = (n0 < 256);
      const int n = n0 + lr;
      f32x4 acc = (f32x4){0.f, 0.f, 0.f, 0.f};
      if (isv) {
#pragma unroll
        for (int q = 0; q < 4; ++q) {
          int t = st * 16 + lg * 4 + q;
          acc[q] = bet[t] * dv[(size_t)(r0 + t) * VD + h * VV + n];
        }
      } else {
        int kk = n - 256;
#pragma unroll
        for (int q = 0; q < 4; ++q) {
          int t = st * 16 + lg * 4 + q;
          acc[q] = bet[t] * __expf(bc[t]) * ksh_get(ksh, t, kk);
        }
      }
#pragma unroll
      for (int p = 0; p < 2; ++p) {
        if ((p == 0 && st >= 1) || (p == 1 && st == 3)) {
          int arow = st * 16 + lr;
          bf16x8 aM = *(const bf16x8*)((const char*)Mb + arow * 128 +
                         (((p * 4 + lg) * 16) ^ ((arow & 7) << 4)));
          bf16x8 bX = *(const bf16x8*)((const char*)Xall + n * 128 +
                         (((p * 4 + lg) * 16) ^ ((n & 7) << 4)));
          acc = __builtin_amdgcn_mfma_f32_16x16x32_bf16(aM, bX, acc, 0, 0, 0);
        }
      }
#pragma unroll
      for (int q = 0; q < 4; ++q) {
        int tq = lg * 4 + q;
        *(bf16_t*)((char*)Yb + n * 64 +
            ((((tq >> 3) * 16) ^ ((n & 3) << 4)) + (tq & 7) * 2)) = (bf16_t)acc[q];
      }
      f32x4 acc2 = (f32x4){0.f, 0.f, 0.f, 0.f};
      {
        bf16x8 aT = *(const bf16x8*)((const char*)Tdl + st * 1024 + lr * 64 +
                       ((lg * 16) ^ ((lr & 3) << 4)));
        bf16x8 bY = *(const bf16x8*)((const char*)Yb + n * 64 +
                       ((lg * 16) ^ ((n & 3) << 4)));
        acc2 = __builtin_amdgcn_mfma_f32_16x16x32_bf16(aT, bY, acc2, 0, 0, 0);
      }
      if (st < 3) {
#pragma unroll
        for (int q = 0; q < 4; ++q) {
          int s = st * 16 + lg * 4 + q;
          *(bf16_t*)((char*)Xall + n * 128 +
              ((((s >> 3) * 16) ^ ((n & 7) << 4)) + (s & 7) * 2)) = (bf16_t)acc2[q];
        }
      }
      if (isv) {
#pragma unroll
        for (int q = 0; q < 4; ++q) {
          int t = st * 16 + lg * 4 + q;
          dv[(size_t)(r0 + t) * VD + h * VV + n] = acc2[q];
        }
      } else {
        int kk = n - 256;
#pragma unroll
        for (int q = 0; q < 4; ++q) {
          int t = st * 16 + lg * 4 + q;
          Wn16[(cb * CL + t) * KK + kk] = (bf16_t)(-acc2[q]);
        }
      }
    }
  }
}

// Pass 2: MFMA state propagation. Grid (16 vtiles of 16, 12 bh), 256 thr.
__global__ __launch_bounds__(256, 1)
void k_chunk2(const float* __restrict__ dv, const bf16_t* __restrict__ Wn16,
              const bf16_t* __restrict__ khatT16, const float* __restrict__ bcum,
              bf16_t* __restrict__ states, bf16_t* __restrict__ Zt) {
  __shared__ __align__(16) bf16_t St[16 * 128];   // [v][k], XOR-swizzled
  __shared__ __align__(16) bf16_t Zl[16 * 64];    // [v][t], XOR-swizzled
  int tid = threadIdx.x;
  int vt = blockIdx.x, bh = blockIdx.y;
  int b = bh / HH, h = bh % HH;
  int wq = tid >> 6, l = tid & 63;
  int lr = l & 15, lg = l >> 4;

  f32x4 acc[2];
#pragma unroll
  for (int kf = 0; kf < 2; ++kf) acc[kf] = (f32x4){0.f, 0.f, 0.f, 0.f};

  for (int c = 0; c < NC; ++c) {
    size_t cb = (size_t)bh * NC + c;
    int r0 = b * TT + c * CL;
    float ebL = __expf(bcum[cb * CL + 63]);

    // S acc -> St bf16 (swizzled); each (k, v=lr) exactly once
#pragma unroll
    for (int kf = 0; kf < 2; ++kf)
#pragma unroll
      for (int q = 0; q < 4; ++q) {
        int k = wq * 32 + kf * 16 + lg * 4 + q;
        int v = lr;
        *(bf16_t*)((char*)St + v * 256 + ((k * 2) ^ ((v & 7) << 4))) = (bf16_t)acc[kf][q];
      }
    __syncthreads();

    // states copy (S0^T for pass 3)
    {
      int v = tid >> 4, slot = tid & 15;
      bf16x8 val = *(const bf16x8*)((const char*)St + v * 256 + ((slot * 16) ^ ((v & 7) << 4)));
      *(bf16x8*)(states + ((size_t)cb * 256 + vt * 16 + v) * 128 + slot * 8) = val;
    }

    // Z = Dv + (-W) * S : per wave 16t x 16v
    f32x4 zacc = (f32x4){0.f, 0.f, 0.f, 0.f};
#pragma unroll
    for (int q = 0; q < 4; ++q) {
      int t = wq * 16 + lg * 4 + q;
      zacc[q] = dv[(size_t)(r0 + t) * VD + h * VV + vt * 16 + lr];
    }
#pragma unroll
    for (int ks_ = 0; ks_ < 4; ++ks_) {
      bf16x8 aW = *(const bf16x8*)(Wn16 + (cb * CL + wq * 16 + lr) * KK + ks_ * 32 + lg * 8);
      int v = lr;
      bf16x8 bS = *(const bf16x8*)((const char*)St + v * 256 + (((ks_ * 32 + lg * 8) * 2) ^ ((v & 7) << 4)));
      zacc = __builtin_amdgcn_mfma_f32_16x16x32_bf16(aW, bS, zacc, 0, 0, 0);
    }
#pragma unroll
    for (int q = 0; q < 4; ++q) {
      int t = wq * 16 + lg * 4 + q;
      int v = lr;
      *(bf16_t*)((char*)Zl + v * 128 + ((t * 2) ^ ((v & 7) << 4))) = (bf16_t)zacc[q];
    }
    __syncthreads();

    // Zt copy to global
    if (tid < 128) {
      int v = tid >> 3, slot = tid & 7;
      bf16x8 val = *(const bf16x8*)((const char*)Zl + v * 128 + ((slot * 16) ^ ((v & 7) << 4)));
      *(bf16x8*)(Zt + ((size_t)cb * 256 + vt * 16 + v) * 64 + slot * 8) = val;
    }
    // S decay + S += khatT * Z
#pragma unroll
    for (int kf = 0; kf < 2; ++kf)
#pragma unroll
      for (int q = 0; q < 4; ++q) acc[kf][q] *= ebL;
#pragma unroll
    for (int ts = 0; ts < 2; ++ts) {
      bf16x8 aK[2];
#pragma unroll
      for (int kf = 0; kf < 2; ++kf)
        aK[kf] = *(const bf16x8*)(khatT16 + (cb * KK + wq * 32 + kf * 16 + lr) * CL + ts * 32 + lg * 8);
      int v = lr;
      bf16x8 bZ = *(const bf16x8*)((const char*)Zl + v * 128 + (((ts * 32 + lg * 8) * 2) ^ ((v & 7) << 4)));
#pragma unroll
      for (int kf = 0; kf < 2; ++kf)
        acc[kf] = __builtin_amdgcn_mfma_f32_16x16x32_bf16(aK[kf], bZ, acc[kf], 0, 0, 0);
    }
  }
}

// Pass 3 (8-wave): o = e^{b_t} q^T S0 + P Z (MFMA) + fused gated RMSNorm.
__global__ __launch_bounds__(512, 2)
void k_chunk3(const bf16_t* __restrict__ qb16, const bf16_t* __restrict__ kb16,
              const bf16_t* __restrict__ Zt, const bf16_t* __restrict__ states,
              const float* __restrict__ bcum, const bf16_t* __restrict__ fgate,
              const float* __restrict__ onorm_w, bf16_t* __restrict__ ovd) {
  __shared__ __align__(16) bf16_t qs[64 * 128];   // [t][k] swizzled via pre-XOR source
  __shared__ __align__(16) bf16_t ksh[64 * 128];
  __shared__ __align__(16) bf16_t Pl[64 * 64];    // [t][s] swizzled
  __shared__ float bcs[64];
  __shared__ float sred[8][64];

  int tid = threadIdx.x;
  int c = blockIdx.x, bh = blockIdx.y;
  int b = bh / HH, h = bh % HH;
  int r0 = b * TT + c * CL;
  size_t cb = (size_t)bh * NC + c;
  int wq = tid >> 6, l = tid & 63;
  int lr = l & 15, lg = l >> 4;

  // hoisted global B-frag loads: latency hides under staging + P phase
  bf16x8 bSv[4][2], bZv[2][2];
#pragma unroll
  for (int vj = 0; vj < 2; ++vj) {
    int vrow = wq * 32 + vj * 16 + lr;
#pragma unroll
    for (int ks_ = 0; ks_ < 4; ++ks_)
      bSv[ks_][vj] = *(const bf16x8*)(states + ((size_t)cb * 256 + vrow) * 128 + ks_ * 32 + lg * 8);
#pragma unroll
    for (int ts = 0; ts < 2; ++ts)
      bZv[ts][vj] = *(const bf16x8*)(Zt + ((size_t)cb * 256 + vrow) * 64 + ts * 32 + lg * 8);
  }

  if (tid < 64) bcs[tid] = bcum[cb * CL + tid];
#pragma unroll
  for (int it = 0; it < 2; ++it) {
    int idx = it * 512 + tid;
    int t = idx >> 4, p = idx & 15;
    int kslot = p ^ (t & 7);
    gload_lds16(qb16 + (size_t)(r0 + t) * KD + h * KK + kslot * 8,
                qs + (size_t)idx * 8);
    gload_lds16(kb16 + (size_t)(r0 + t) * KD + h * KK + kslot * 8,
                ksh + (size_t)idx * 8);
  }
  __syncthreads();

  if (wq < 4) {
    f32x4 pacc[4];
#pragma unroll
    for (int sf = 0; sf < 4; ++sf) pacc[sf] = (f32x4){0.f, 0.f, 0.f, 0.f};
#pragma unroll
    for (int ks_ = 0; ks_ < 4; ++ks_) {
      int trow = wq * 16 + lr;
      bf16x8 aQ = *(const bf16x8*)((const char*)qs + trow * 256 + (((ks_ * 4 + lg) * 16) ^ ((trow & 7) << 4)));
#pragma unroll
      for (int sf = 0; sf < 4; ++sf) {
        int srow = sf * 16 + lr;
        bf16x8 bK = *(const bf16x8*)((const char*)ksh + srow * 256 + (((ks_ * 4 + lg) * 16) ^ ((srow & 7) << 4)));
        pacc[sf] = __builtin_amdgcn_mfma_f32_16x16x32_bf16(aQ, bK, pacc[sf], 0, 0, 0);
      }
    }
#pragma unroll
    for (int sf = 0; sf < 4; ++sf)
#pragma unroll
      for (int q = 0; q < 4; ++q) {
        int t = wq * 16 + lg * 4 + q;
        int s = sf * 16 + lr;
        float val = (s <= t) ? pacc[sf][q] * __expf(bcs[t] - bcs[s]) : 0.f;
        *(bf16_t*)((char*)Pl + t * 128 + ((s * 2) ^ ((t & 7) << 4))) = (bf16_t)val;
      }
  }
  __syncthreads();

  // O: wave wq covers v cols wq*32..+31
  f32x4 oacc[4][2];
#pragma unroll
  for (int ti = 0; ti < 4; ++ti)
#pragma unroll
    for (int vj = 0; vj < 2; ++vj) oacc[ti][vj] = (f32x4){0.f, 0.f, 0.f, 0.f};

#pragma unroll
  for (int ks_ = 0; ks_ < 4; ++ks_) {
    bf16x8 aQ[4];
#pragma unroll
    for (int ti = 0; ti < 4; ++ti) {
      int t = ti * 16 + lr;
      union { bf16x8 v; bf16_t e[8]; } u;
      u.v = *(const bf16x8*)((const char*)qs + t * 256 + (((ks_ * 4 + lg) * 16) ^ ((t & 7) << 4)));
      float eb = __expf(bcs[t]);
#pragma unroll
      for (int e = 0; e < 8; ++e) u.e[e] = (bf16_t)((float)u.e[e] * eb);
      aQ[ti] = u.v;
    }
#pragma unroll
    for (int vj = 0; vj < 2; ++vj)
#pragma unroll
      for (int ti = 0; ti < 4; ++ti)
        oacc[ti][vj] = __builtin_amdgcn_mfma_f32_16x16x32_bf16(aQ[ti], bSv[ks_][vj], oacc[ti][vj], 0, 0, 0);
  }
#pragma unroll
  for (int ts = 0; ts < 2; ++ts) {
    bf16x8 aP[4];
#pragma unroll
    for (int ti = 0; ti < 4; ++ti) {
      int t = ti * 16 + lr;
      aP[ti] = *(const bf16x8*)((const char*)Pl + t * 128 + (((ts * 4 + lg) * 16) ^ ((t & 7) << 4)));
    }
#pragma unroll
    for (int vj = 0; vj < 2; ++vj)
#pragma unroll
      for (int ti = 0; ti < 4; ++ti)
        oacc[ti][vj] = __builtin_amdgcn_mfma_f32_16x16x32_bf16(aP[ti], bZv[ts][vj], oacc[ti][vj], 0, 0, 0);
  }

  // ---- fused gated RMSNorm (8-wave reduce) ----
  float sum2[4][4];
#pragma unroll
  for (int ti = 0; ti < 4; ++ti)
#pragma unroll
    for (int q = 0; q < 4; ++q) {
      float s = 0.f;
#pragma unroll
      for (int vj = 0; vj < 2; ++vj) s += oacc[ti][vj][q] * oacc[ti][vj][q];
      sum2[ti][q] = s;
    }
#pragma unroll
  for (int mk = 1; mk < 16; mk <<= 1)
#pragma unroll
    for (int ti = 0; ti < 4; ++ti)
#pragma unroll
      for (int q = 0; q < 4; ++q)
        sum2[ti][q] += __shfl_xor(sum2[ti][q], mk, 64);
  if (lr == 0) {
#pragma unroll
    for (int ti = 0; ti < 4; ++ti)
#pragma unroll
      for (int q = 0; q < 4; ++q)
        sred[wq][ti * 16 + lg * 4 + q] = sum2[ti][q];
  }
  __syncthreads();

  float onv[2];
#pragma unroll
  for (int vj = 0; vj < 2; ++vj) onv[vj] = onorm_w[wq * 32 + vj * 16 + lr];
#pragma unroll
  for (int ti = 0; ti < 4; ++ti)
#pragma unroll
    for (int q = 0; q < 4; ++q) {
      int t = ti * 16 + lg * 4 + q;
      float tot = 0.f;
#pragma unroll
      for (int w = 0; w < 8; ++w) tot += sred[w][t];
      float rn = rsqrtf(tot * (1.f / VV) + 1e-5f);
#pragma unroll
      for (int vj = 0; vj < 2; ++vj) {
        int v = wq * 32 + vj * 16 + lr;
        float gate = (float)fgate[(size_t)(r0 + t) * NCAT + h * VV + v];
        float y = oacc[ti][vj][q] * rn * onv[vj] * (gate / (1.f + expf(-gate)));
        ovd[(size_t)(r0 + t) * VD + h * VV + v] = (bf16_t)y;
      }
    }
}

extern "C" void kernel_launch(void* const* d_in, const int* in_sizes, int n_in,
                              void* d_out, int out_size, void* d_ws, size_t ws_size,
                              hipStream_t stream) {
  const float* hidden = (const float*)d_in[0];
  const float* Wq = (const float*)d_in[1];
  const float* Wk = (const float*)d_in[2];
  const float* Wv = (const float*)d_in[3];
  const float* Wa = (const float*)d_in[4];
  const float* Wb = (const float*)d_in[5];
  const float* A_log = (const float*)d_in[6];
  const float* dt_bias = (const float*)d_in[7];
  const float* qconv = (const float*)d_in[8];
  const float* kconv = (const float*)d_in[9];
  const float* vconv = (const float*)d_in[10];
  const float* Wg = (const float*)d_in[11];
  const float* onorm = (const float*)d_in[12];
  const float* Wo = (const float*)d_in[13];
  float* out = (float*)d_out;

  char* ws = (char*)d_ws;
  size_t off = 0;
  auto alloc = [&](size_t bytes) {
    void* p = ws + off;
    off += (bytes + 255) & ~(size_t)255;
    return p;
  };
  const int M = BB * TT;  // 2048
  bf16_t* hbf   = (bf16_t*)alloc((size_t)M * CC * 2);       // aliased by Wn16/khatT16 later
  bf16_t* WcatT = (bf16_t*)alloc((size_t)NCAT * CC * 2);
  bf16_t* WoT   = (bf16_t*)alloc((size_t)CC * VD * 2);
  bf16_t* fall  = (bf16_t*)alloc((size_t)M * NCAT * 2);     // fused q|k|v|gate projection (bf16)
  bf16_t* states = (bf16_t*)alloc((size_t)12 * NC * VV * KK * 2);  // 12.6MB
  float*  kn    = (float*) alloc((size_t)M * KD * 4);       // aliased by Zt later
  float*  vn    = (float*) alloc((size_t)M * VD * 4);       // becomes Dv in pass 1
  float*  gdec  = (float*) alloc((size_t)M * HH * 4);
  float*  beta  = (float*) alloc((size_t)M * HH * 4);
  bf16_t* ovd   = (bf16_t*)alloc((size_t)M * VD * 2);
  bf16_t* qb16  = (bf16_t*)alloc((size_t)M * KD * 2);
  bf16_t* kb16  = (bf16_t*)alloc((size_t)M * KD * 2);
  float*  bcum  = (float*) alloc((size_t)12 * NC * CL * 4);

  // aliases (stream-ordered lifetime separation):
  bf16_t* Wn16    = (bf16_t*)hbf;                     // 12*16*64*128 bf16 = 3.15MB
  bf16_t* khatT16 = Wn16 + (size_t)12 * NC * CL * KK; // +3.15MB (hbf is 8.4MB)
  bf16_t* Zt      = (bf16_t*)kn;                      // 12*16*256*64 bf16 = 6.3MB

  // pre-pass
  k_cvt_bf16<<<(M * CC / 4 + 255) / 256, 256, 0, stream>>>(hidden, hbf, M * CC);
  k_transpose_cvt<<<dim3(KD / 32, CC / 32), dim3(32, 8), 0, stream>>>(Wq, WcatT, CC, KD);
  k_transpose_cvt<<<dim3(KD / 32, CC / 32), dim3(32, 8), 0, stream>>>(Wk, WcatT + (size_t)768 * CC, CC, KD);
  k_transpose_cvt<<<dim3(VD / 32, CC / 32), dim3(32, 8), 0, stream>>>(Wv, WcatT + (size_t)1536 * CC, CC, VD);
  k_transpose_cvt<<<dim3(VD / 32, CC / 32), dim3(32, 8), 0, stream>>>(Wg, WcatT + (size_t)3072 * CC, CC, VD);
  k_transpose_cvt<<<dim3(CC / 32, VD / 32), dim3(32, 8), 0, stream>>>(Wo, WoT, VD, CC);

  // fused projection GEMM: [2048,2048] x [4608,2048]^T -> [2048,4608] bf16
  // BN=96 -> grid 48x16 = 768 blocks = exactly 3.0 blocks/CU (no tail imbalance)
  k_gemm_bt<96, bf16_t><<<dim3(NCAT / 96, M / 128), 256, 0, stream>>>(hbf, WcatT, fall, M, NCAT, CC);

  // beta / g
  k_ab<<<M, 64, 0, stream>>>(hidden, Wa, Wb, A_log, dt_bias, gdec, beta);

  // conv + silu (+norm for q,k)
  k_conv_silu<<<dim3(M, HH), 128, 0, stream>>>(fall, NCAT, 0, qconv, nullptr, qb16, KD, 1);
  k_conv_silu<<<dim3(M, HH), 128, 0, stream>>>(fall, NCAT, 768, kconv, nullptr, kb16, KD, 1);
  k_conv_silu<<<dim3(M, HH), 256, 0, stream>>>(fall, NCAT, 1536, vconv, vn, nullptr, VD, 0);

  // chunked gated delta rule (hbf dead -> Wn16/khatT16; kn dead -> Zt)
  k_chunk1<<<dim3(NC, 12), 512, 0, stream>>>(kb16, vn, gdec, beta, Wn16, khatT16, bcum);
  k_chunk2<<<dim3(16, 12), 256, 0, stream>>>(vn, Wn16, khatT16, bcum, states, Zt);
  k_chunk3<<<dim3(NC, 12), 512, 0, stream>>>(qb16, kb16, Zt, states, bcum, fall + 3072, onorm, ovd);

  // output projection (f32 out), grid 16x16 = 256 = 1.0 blocks/CU
  k_gemm_bt<128, float><<<dim3(CC / 128, M / 128), 256, 0, stream>>>(ovd, WoT, out, M, CC, VD);
}

// Round 17
// 204.928 us; speedup vs baseline: 1.8489x; 1.0423x over previous
//
#include <hip/hip_runtime.h>
#include <hip/hip_bf16.h>
#include <math.h>

typedef __bf16 bf16_t;
typedef __attribute__((ext_vector_type(8))) __bf16 bf16x8;
typedef __attribute__((ext_vector_type(4))) float f32x4;

#define GAS __attribute__((address_space(1)))
#define LAS __attribute__((address_space(3)))

#define BB 2
#define TT 1024
#define CC 2048
#define HH 6
#define KK 128
#define VV 256
#define KD 768
#define VD 1536
#define NQKV 3072
#define NCAT 4608
#define NC 16     // chunks per sequence
#define CL 64     // chunk length

__device__ __forceinline__ void gload_lds16(const void* g, void* l) {
  __builtin_amdgcn_global_load_lds((const GAS void*)g, (LAS void*)l, 16, 0, 0);
}

// scalar read of swizzled [64][128] bf16 tile element (t, kk)
__device__ __forceinline__ float ksh_get(const bf16_t* ksh, int t, int kk) {
  return (float)*(const bf16_t*)((const char*)ksh + t * 256 +
           ((((kk >> 3) ^ (t & 7)) * 16) + (kk & 7) * 2));
}

// ---------- transpose [Kd,Nd] f32 -> [Nd,Kd] bf16 ----------
__global__ void k_transpose_cvt(const float* __restrict__ in, bf16_t* __restrict__ out,
                                int Kd, int Nd) {
  __shared__ float t[32][33];
  int n0 = blockIdx.x * 32, k0 = blockIdx.y * 32;
  int tx = threadIdx.x, ty = threadIdx.y;
#pragma unroll
  for (int i = 0; i < 32; i += 8)
    t[ty + i][tx] = in[(size_t)(k0 + ty + i) * Nd + n0 + tx];
  __syncthreads();
#pragma unroll
  for (int i = 0; i < 32; i += 8)
    out[(size_t)(n0 + ty + i) * Kd + k0 + tx] = (bf16_t)t[tx][ty + i];
}

// ---------- bf16 MFMA GEMM: C[M,N] = A[M,K] * B^T (B is [N,K]) ----------
// BM=128, BN template (128/96/64), BK=64, XOR-swizzled LDS via pre-swizzled
// global source -> conflict-free ds_read_b128. XCD-swizzled grid.
template <int BN, typename OT>
__global__ __launch_bounds__(256, 2)
void k_gemm_bt(const bf16_t* __restrict__ A, const bf16_t* __restrict__ B,
               OT* __restrict__ C, int M, int N, int K) {
  constexpr int NFRG = BN / 32;        // per-wave n fragments
  constexpr int NB_IT = BN / 32;       // B staging iterations (BN*8/256)
  __shared__ __align__(16) bf16_t As[128 * 64];
  __shared__ __align__(16) bf16_t Bs[BN * 64];
  int tid = threadIdx.x;
  int wave = tid >> 6, lane = tid & 63;
  int wm = wave >> 1, wn = wave & 1;

  // bijective XCD-aware swizzle (m204): contiguous wgid chunk per XCD
  int gx = gridDim.x;
  int nwg = gx * gridDim.y;
  int lin = blockIdx.y * gx + blockIdx.x;
  int q8 = nwg >> 3, r8 = nwg & 7;
  int xcd = lin & 7, off8 = lin >> 3;
  int wgid = (xcd < r8 ? xcd * (q8 + 1) : r8 * (q8 + 1) + (xcd - r8) * q8) + off8;
  int bx = wgid % gx, by = wgid / gx;

  const bf16_t* Abase = A + (size_t)by * 128 * K;
  const bf16_t* Bbase = B + (size_t)bx * BN * K;

  f32x4 acc[4][NFRG];
#pragma unroll
  for (int i = 0; i < 4; ++i)
#pragma unroll
    for (int j = 0; j < NFRG; ++j) acc[i][j] = (f32x4){0.f, 0.f, 0.f, 0.f};

  int kg = lane >> 4, lr = lane & 15;

  for (int k0 = 0; k0 < K; k0 += 64) {
#pragma unroll
    for (int it = 0; it < 4; ++it) {
      int idx = it * 256 + tid;
      int row = idx >> 3, slot = idx & 7;
      const bf16_t* ga = Abase + (size_t)row * K + k0 + ((slot ^ (row & 7)) * 8);
      gload_lds16(ga, As + (size_t)(it * 256 + wave * 64) * 8);
    }
#pragma unroll
    for (int it = 0; it < NB_IT; ++it) {
      int idx = it * 256 + tid;
      int row = idx >> 3, slot = idx & 7;
      const bf16_t* gb = Bbase + (size_t)row * K + k0 + ((slot ^ (row & 7)) * 8);
      gload_lds16(gb, Bs + (size_t)(it * 256 + wave * 64) * 8);
    }
    __syncthreads();
#pragma unroll
    for (int ks2 = 0; ks2 < 2; ++ks2) {
      int j = ks2 * 4 + kg;
      bf16x8 af[4], bfv[NFRG];
#pragma unroll
      for (int i = 0; i < 4; ++i) {
        int ra = wm * 64 + i * 16 + lr;
        af[i] = *(const bf16x8*)((const char*)As + ra * 128 + ((j ^ (ra & 7)) * 16));
      }
#pragma unroll
      for (int i = 0; i < NFRG; ++i) {
        int rb = wn * (BN / 2) + i * 16 + lr;
        bfv[i] = *(const bf16x8*)((const char*)Bs + rb * 128 + ((j ^ (rb & 7)) * 16));
      }
#pragma unroll
      for (int i = 0; i < 4; ++i)
#pragma unroll
        for (int jj = 0; jj < NFRG; ++jj)
          acc[i][jj] = __builtin_amdgcn_mfma_f32_16x16x32_bf16(af[i], bfv[jj], acc[i][jj], 0, 0, 0);
    }
    __syncthreads();
  }

#pragma unroll
  for (int i = 0; i < 4; ++i) {
    int r0 = by * 128 + wm * 64 + i * 16 + ((lane >> 4) << 2);
#pragma unroll
    for (int j = 0; j < NFRG; ++j) {
      int c = bx * BN + wn * (BN / 2) + j * 16 + (lane & 15);
      OT* Cp = C + (size_t)r0 * N + c;
#pragma unroll
      for (int q = 0; q < 4; ++q) Cp[(size_t)q * N] = (OT)acc[i][j][q];
    }
  }
}

// ---------- beta / g + fused hidden->bf16 cast ----------
__global__ __launch_bounds__(64)
void k_ab(const float* __restrict__ hidden, const float* __restrict__ Wa,
          const float* __restrict__ Wb, const float* __restrict__ A_log,
          const float* __restrict__ dt_bias, float* __restrict__ g_out,
          float* __restrict__ beta_out, bf16_t* __restrict__ hbf) {
  int row = blockIdx.x;
  int lane = threadIdx.x;
  float accA[6] = {0, 0, 0, 0, 0, 0};
  float accB[6] = {0, 0, 0, 0, 0, 0};
  const float* h = hidden + (size_t)row * CC;
  bf16_t* hb = hbf + (size_t)row * CC;
  for (int c = lane; c < CC; c += 64) {
    float x = h[c];
    hb[c] = (bf16_t)x;
    const float* wa = Wa + c * 6;
    const float* wb = Wb + c * 6;
#pragma unroll
    for (int j = 0; j < 6; ++j) {
      accA[j] += x * wa[j];
      accB[j] += x * wb[j];
    }
  }
#pragma unroll
  for (int j = 0; j < 6; ++j) {
    for (int off = 32; off; off >>= 1) {
      accA[j] += __shfl_down(accA[j], off);
      accB[j] += __shfl_down(accB[j], off);
    }
  }
  if (lane == 0) {
#pragma unroll
    for (int j = 0; j < 6; ++j) {
      float a = accA[j] + dt_bias[j];
      float sp = (a > 20.f) ? a : log1pf(expf(a));
      g_out[(size_t)row * 6 + j] = -expf(A_log[j]) * sp;
      beta_out[(size_t)row * 6 + j] = 1.f / (1.f + expf(-accB[j]));
    }
  }
}

// ---------- depthwise causal conv(4) + SiLU (+ optional L2 norm); bf16 input ----------
__global__ void k_conv_silu(const bf16_t* __restrict__ pre, int ldpre, int col0,
                            const float* __restrict__ w, float* __restrict__ out,
                            bf16_t* __restrict__ out16, int ld_out, int do_norm) {
  int row = blockIdx.x;     // b*T + t
  int t = row & (TT - 1);
  int h = blockIdx.y;
  int kk = threadIdx.x;
  int perH = blockDim.x;
  int ch = h * perH + kk;
  const float* wp = w + ch * 4;
  float y = 0.f;
#pragma unroll
  for (int i = 0; i < 4; ++i) {
    int tt = t - 3 + i;
    if (tt >= 0) y += wp[i] * (float)pre[(size_t)(row - 3 + i) * ldpre + col0 + ch];
  }
  float s = y / (1.f + expf(-y));
  if (do_norm) {
    float ss = s * s;
#pragma unroll
    for (int off = 32; off; off >>= 1) ss += __shfl_down(ss, off);
    __shared__ float red[2];
    if ((threadIdx.x & 63) == 0) red[threadIdx.x >> 6] = ss;
    __syncthreads();
    float nrm = sqrtf(red[0] + red[1]);
    s = s / (nrm + 1e-6f);
  }
  if (out) out[(size_t)row * ld_out + ch] = s;
  if (out16) out16[(size_t)row * ld_out + ch] = (bf16_t)s;
}

// ============ chunked gated delta rule ============
// Pass 1 (R8's UT transform, 8-wave version): 512 thr; phase D = 3 n-tiles/wave.
__global__ __launch_bounds__(512, 2)
void k_chunk1(const bf16_t* __restrict__ kb16, float* dv,
              const float* __restrict__ gdec, const float* __restrict__ beta,
              bf16_t* __restrict__ Wn16, bf16_t* __restrict__ khatT16,
              float* __restrict__ bcum) {
  __shared__ __align__(16) bf16_t ksh[64 * 128];    // 16KB [t][k] swizzled
  __shared__ __align__(16) bf16_t Mb[64 * 64];      // 8KB  [t][s] = -M, swizzled
  __shared__ __align__(16) bf16_t Tdl[4 * 16 * 32]; // 4KB  diag-block inverses, k:16..31 zero
  __shared__ __align__(16) bf16_t Yb[384 * 32];     // 24KB [n][k] Ytmp (B-frag layout), k:16..31 zero
  __shared__ __align__(16) bf16_t Xall[384 * 64];   // 48KB [n][s] solved X (B-frag layout)
  __shared__ float bc[64], bet[64];

  int tid = threadIdx.x;
  int bh = blockIdx.y, c = blockIdx.x;
  int b = bh / HH, h = bh % HH;
  int r0 = b * TT + c * CL;
  size_t cb = (size_t)bh * NC + c;
  int wq = tid >> 6, l = tid & 63;
  int lr = l & 15, lg = l >> 4;

  // ---- phase A ----
#pragma unroll
  for (int it = 0; it < 2; ++it) {
    int idx = it * 512 + tid;
    int t = idx >> 4, p = idx & 15;
    int kslot = p ^ (t & 7);
    gload_lds16(kb16 + (size_t)(r0 + t) * KD + h * KK + kslot * 8,
                ksh + (size_t)idx * 8);
  }
  if (tid < 64) {
    float val = gdec[(size_t)(r0 + tid) * HH + h];
    bet[tid] = beta[(size_t)(r0 + tid) * HH + h];
#pragma unroll
    for (int off = 1; off < 64; off <<= 1) {
      float o = __shfl_up(val, off, 64);
      if (tid >= off) val += o;
    }
    bc[tid] = val;
    bcum[cb * CL + tid] = val;
  }
  __syncthreads();
  float bL = bc[63];

  // ---- phase B ----
  {
    f32x4 z4 = (f32x4){0.f, 0.f, 0.f, 0.f};
#pragma unroll
    for (int i = 0; i < 6; ++i) ((f32x4*)Xall)[i * 512 + tid] = z4;
#pragma unroll
    for (int i = 0; i < 3; ++i) ((f32x4*)Yb)[i * 512 + tid] = z4;
    if (tid < 256) ((f32x4*)Tdl)[tid] = z4;
  }
  if (wq < 4) {
    f32x4 pacc[4];
#pragma unroll
    for (int sf = 0; sf < 4; ++sf) pacc[sf] = (f32x4){0.f, 0.f, 0.f, 0.f};
#pragma unroll
    for (int ks_ = 0; ks_ < 4; ++ks_) {
      int trow = wq * 16 + lr;
      bf16x8 aK = *(const bf16x8*)((const char*)ksh + trow * 256 + (((ks_ * 4 + lg) * 16) ^ ((trow & 7) << 4)));
#pragma unroll
      for (int sf = 0; sf < 4; ++sf) {
        int srow = sf * 16 + lr;
        bf16x8 bK = *(const bf16x8*)((const char*)ksh + srow * 256 + (((ks_ * 4 + lg) * 16) ^ ((srow & 7) << 4)));
        pacc[sf] = __builtin_amdgcn_mfma_f32_16x16x32_bf16(aK, bK, pacc[sf], 0, 0, 0);
      }
    }
#pragma unroll
    for (int sf = 0; sf < 4; ++sf)
#pragma unroll
      for (int q = 0; q < 4; ++q) {
        int t = wq * 16 + lg * 4 + q;
        int s = sf * 16 + lr;
        float val = (s < t) ? -bet[t] * __expf(bc[t] - bc[s]) * pacc[sf][q] : 0.f;
        *(bf16_t*)((char*)Mb + t * 128 + ((s * 2) ^ ((t & 7) << 4))) = (bf16_t)val;
      }
  }
  __syncthreads();

  // ---- phase C ----
  if (tid < 64) {
    int d = tid >> 4, cc = tid & 15;
    float x[16];
#pragma unroll
    for (int s = 0; s < 16; ++s) x[s] = (s == cc) ? 1.f : 0.f;
#pragma unroll
    for (int r = 1; r < 16; ++r) {
      float a = 0.f;
#pragma unroll
      for (int s = 0; s < r; ++s) {
        float m = (float)*(const bf16_t*)((const char*)Mb + (16 * d + r) * 128 +
                    (((16 * d + s) * 2) ^ ((r & 7) << 4)));
        a += m * x[s];
      }
      x[r] += a;
    }
#pragma unroll
    for (int r = 0; r < 16; ++r)
      *(bf16_t*)((char*)Tdl + d * 1024 + r * 64 +
          ((((cc >> 3) * 16) ^ ((r & 3) << 4)) + (cc & 7) * 2)) = (bf16_t)x[r];
  } else if (tid < 192) {
    int kk = tid - 64;
    bf16_t* kout = khatT16 + cb * (size_t)(KK * CL) + (size_t)kk * CL;
#pragma unroll
    for (int t8 = 0; t8 < 8; ++t8) {
      union { bf16x8 v; bf16_t e[8]; } u;
#pragma unroll
      for (int e = 0; e < 8; ++e) {
        int t = t8 * 8 + e;
        u.e[e] = (bf16_t)(__expf(bL - bc[t]) * ksh_get(ksh, t, kk));
      }
      *(bf16x8*)(kout + t8 * 8) = u.v;
    }
  }
  __syncthreads();

  // ---- phase D ----
  const int nbase = wq * 48;
#pragma unroll
  for (int st = 0; st < 4; ++st) {
#pragma unroll
    for (int nt = 0; nt < 3; ++nt) {
      const int n0 = nbase + nt * 16;
      const bool isv = (n0 < 256);
      const int n = n0 + lr;
      f32x4 acc = (f32x4){0.f, 0.f, 0.f, 0.f};
      if (isv) {
#pragma unroll
        for (int q = 0; q < 4; ++q) {
          int t = st * 16 + lg * 4 + q;
          acc[q] = bet[t] * dv[(size_t)(r0 + t) * VD + h * VV + n];
        }
      } else {
        int kk = n - 256;
#pragma unroll
        for (int q = 0; q < 4; ++q) {
          int t = st * 16 + lg * 4 + q;
          acc[q] = bet[t] * __expf(bc[t]) * ksh_get(ksh, t, kk);
        }
      }
#pragma unroll
      for (int p = 0; p < 2; ++p) {
        if ((p == 0 && st >= 1) || (p == 1 && st == 3)) {
          int arow = st * 16 + lr;
          bf16x8 aM = *(const bf16x8*)((const char*)Mb + arow * 128 +
                         (((p * 4 + lg) * 16) ^ ((arow & 7) << 4)));
          bf16x8 bX = *(const bf16x8*)((const char*)Xall + n * 128 +
                         (((p * 4 + lg) * 16) ^ ((n & 7) << 4)));
          acc = __builtin_amdgcn_mfma_f32_16x16x32_bf16(aM, bX, acc, 0, 0, 0);
        }
      }
#pragma unroll
      for (int q = 0; q < 4; ++q) {
        int tq = lg * 4 + q;
        *(bf16_t*)((char*)Yb + n * 64 +
            ((((tq >> 3) * 16) ^ ((n & 3) << 4)) + (tq & 7) * 2)) = (bf16_t)acc[q];
      }
      f32x4 acc2 = (f32x4){0.f, 0.f, 0.f, 0.f};
      {
        bf16x8 aT = *(const bf16x8*)((const char*)Tdl + st * 1024 + lr * 64 +
                       ((lg * 16) ^ ((lr & 3) << 4)));
        bf16x8 bY = *(const bf16x8*)((const char*)Yb + n * 64 +
                       ((lg * 16) ^ ((n & 3) << 4)));
        acc2 = __builtin_amdgcn_mfma_f32_16x16x32_bf16(aT, bY, acc2, 0, 0, 0);
      }
      if (st < 3) {
#pragma unroll
        for (int q = 0; q < 4; ++q) {
          int s = st * 16 + lg * 4 + q;
          *(bf16_t*)((char*)Xall + n * 128 +
              ((((s >> 3) * 16) ^ ((n & 7) << 4)) + (s & 7) * 2)) = (bf16_t)acc2[q];
        }
      }
      if (isv) {
#pragma unroll
        for (int q = 0; q < 4; ++q) {
          int t = st * 16 + lg * 4 + q;
          dv[(size_t)(r0 + t) * VD + h * VV + n] = acc2[q];
        }
      } else {
        int kk = n - 256;
#pragma unroll
        for (int q = 0; q < 4; ++q) {
          int t = st * 16 + lg * 4 + q;
          Wn16[(cb * CL + t) * KK + kk] = (bf16_t)(-acc2[q]);
        }
      }
    }
  }
}

// Pass 2: MFMA state propagation. Grid (16 vtiles of 16, 12 bh), 256 thr.
__global__ __launch_bounds__(256, 1)
void k_chunk2(const float* __restrict__ dv, const bf16_t* __restrict__ Wn16,
              const bf16_t* __restrict__ khatT16, const float* __restrict__ bcum,
              bf16_t* __restrict__ states, bf16_t* __restrict__ Zt) {
  __shared__ __align__(16) bf16_t St[16 * 128];   // [v][k], XOR-swizzled
  __shared__ __align__(16) bf16_t Zl[16 * 64];    // [v][t], XOR-swizzled
  int tid = threadIdx.x;
  int vt = blockIdx.x, bh = blockIdx.y;
  int b = bh / HH, h = bh % HH;
  int wq = tid >> 6, l = tid & 63;
  int lr = l & 15, lg = l >> 4;

  f32x4 acc[2];
#pragma unroll
  for (int kf = 0; kf < 2; ++kf) acc[kf] = (f32x4){0.f, 0.f, 0.f, 0.f};

  for (int c = 0; c < NC; ++c) {
    size_t cb = (size_t)bh * NC + c;
    int r0 = b * TT + c * CL;
    float ebL = __expf(bcum[cb * CL + 63]);

#pragma unroll
    for (int kf = 0; kf < 2; ++kf)
#pragma unroll
      for (int q = 0; q < 4; ++q) {
        int k = wq * 32 + kf * 16 + lg * 4 + q;
        int v = lr;
        *(bf16_t*)((char*)St + v * 256 + ((k * 2) ^ ((v & 7) << 4))) = (bf16_t)acc[kf][q];
      }
    __syncthreads();

    {
      int v = tid >> 4, slot = tid & 15;
      bf16x8 val = *(const bf16x8*)((const char*)St + v * 256 + ((slot * 16) ^ ((v & 7) << 4)));
      *(bf16x8*)(states + ((size_t)cb * 256 + vt * 16 + v) * 128 + slot * 8) = val;
    }

    f32x4 zacc = (f32x4){0.f, 0.f, 0.f, 0.f};
#pragma unroll
    for (int q = 0; q < 4; ++q) {
      int t = wq * 16 + lg * 4 + q;
      zacc[q] = dv[(size_t)(r0 + t) * VD + h * VV + vt * 16 + lr];
    }
#pragma unroll
    for (int ks_ = 0; ks_ < 4; ++ks_) {
      bf16x8 aW = *(const bf16x8*)(Wn16 + (cb * CL + wq * 16 + lr) * KK + ks_ * 32 + lg * 8);
      int v = lr;
      bf16x8 bS = *(const bf16x8*)((const char*)St + v * 256 + (((ks_ * 32 + lg * 8) * 2) ^ ((v & 7) << 4)));
      zacc = __builtin_amdgcn_mfma_f32_16x16x32_bf16(aW, bS, zacc, 0, 0, 0);
    }
#pragma unroll
    for (int q = 0; q < 4; ++q) {
      int t = wq * 16 + lg * 4 + q;
      int v = lr;
      *(bf16_t*)((char*)Zl + v * 128 + ((t * 2) ^ ((v & 7) << 4))) = (bf16_t)zacc[q];
    }
    __syncthreads();

    if (tid < 128) {
      int v = tid >> 3, slot = tid & 7;
      bf16x8 val = *(const bf16x8*)((const char*)Zl + v * 128 + ((slot * 16) ^ ((v & 7) << 4)));
      *(bf16x8*)(Zt + ((size_t)cb * 256 + vt * 16 + v) * 64 + slot * 8) = val;
    }
#pragma unroll
    for (int kf = 0; kf < 2; ++kf)
#pragma unroll
      for (int q = 0; q < 4; ++q) acc[kf][q] *= ebL;
#pragma unroll
    for (int ts = 0; ts < 2; ++ts) {
      bf16x8 aK[2];
#pragma unroll
      for (int kf = 0; kf < 2; ++kf)
        aK[kf] = *(const bf16x8*)(khatT16 + (cb * KK + wq * 32 + kf * 16 + lr) * CL + ts * 32 + lg * 8);
      int v = lr;
      bf16x8 bZ = *(const bf16x8*)((const char*)Zl + v * 128 + (((ts * 32 + lg * 8) * 2) ^ ((v & 7) << 4)));
#pragma unroll
      for (int kf = 0; kf < 2; ++kf)
        acc[kf] = __builtin_amdgcn_mfma_f32_16x16x32_bf16(aK[kf], bZ, acc[kf], 0, 0, 0);
    }
  }
}

// Pass 3 (8-wave): o = e^{b_t} q^T S0 + P Z (MFMA) + fused gated RMSNorm.
__global__ __launch_bounds__(512, 2)
void k_chunk3(const bf16_t* __restrict__ qb16, const bf16_t* __restrict__ kb16,
              const bf16_t* __restrict__ Zt, const bf16_t* __restrict__ states,
              const float* __restrict__ bcum, const bf16_t* __restrict__ fgate,
              const float* __restrict__ onorm_w, bf16_t* __restrict__ ovd) {
  __shared__ __align__(16) bf16_t qs[64 * 128];   // [t][k] swizzled via pre-XOR source
  __shared__ __align__(16) bf16_t ksh[64 * 128];
  __shared__ __align__(16) bf16_t Pl[64 * 64];    // [t][s] swizzled
  __shared__ float bcs[64];
  __shared__ float sred[8][64];

  int tid = threadIdx.x;
  int c = blockIdx.x, bh = blockIdx.y;
  int b = bh / HH, h = bh % HH;
  int r0 = b * TT + c * CL;
  size_t cb = (size_t)bh * NC + c;
  int wq = tid >> 6, l = tid & 63;
  int lr = l & 15, lg = l >> 4;

  // hoisted global B-frag loads: latency hides under staging + P phase
  bf16x8 bSv[4][2], bZv[2][2];
#pragma unroll
  for (int vj = 0; vj < 2; ++vj) {
    int vrow = wq * 32 + vj * 16 + lr;
#pragma unroll
    for (int ks_ = 0; ks_ < 4; ++ks_)
      bSv[ks_][vj] = *(const bf16x8*)(states + ((size_t)cb * 256 + vrow) * 128 + ks_ * 32 + lg * 8);
#pragma unroll
    for (int ts = 0; ts < 2; ++ts)
      bZv[ts][vj] = *(const bf16x8*)(Zt + ((size_t)cb * 256 + vrow) * 64 + ts * 32 + lg * 8);
  }

  if (tid < 64) bcs[tid] = bcum[cb * CL + tid];
#pragma unroll
  for (int it = 0; it < 2; ++it) {
    int idx = it * 512 + tid;
    int t = idx >> 4, p = idx & 15;
    int kslot = p ^ (t & 7);
    gload_lds16(qb16 + (size_t)(r0 + t) * KD + h * KK + kslot * 8,
                qs + (size_t)idx * 8);
    gload_lds16(kb16 + (size_t)(r0 + t) * KD + h * KK + kslot * 8,
                ksh + (size_t)idx * 8);
  }
  __syncthreads();

  if (wq < 4) {
    f32x4 pacc[4];
#pragma unroll
    for (int sf = 0; sf < 4; ++sf) pacc[sf] = (f32x4){0.f, 0.f, 0.f, 0.f};
#pragma unroll
    for (int ks_ = 0; ks_ < 4; ++ks_) {
      int trow = wq * 16 + lr;
      bf16x8 aQ = *(const bf16x8*)((const char*)qs + trow * 256 + (((ks_ * 4 + lg) * 16) ^ ((trow & 7) << 4)));
#pragma unroll
      for (int sf = 0; sf < 4; ++sf) {
        int srow = sf * 16 + lr;
        bf16x8 bK = *(const bf16x8*)((const char*)ksh + srow * 256 + (((ks_ * 4 + lg) * 16) ^ ((srow & 7) << 4)));
        pacc[sf] = __builtin_amdgcn_mfma_f32_16x16x32_bf16(aQ, bK, pacc[sf], 0, 0, 0);
      }
    }
#pragma unroll
    for (int sf = 0; sf < 4; ++sf)
#pragma unroll
      for (int q = 0; q < 4; ++q) {
        int t = wq * 16 + lg * 4 + q;
        int s = sf * 16 + lr;
        float val = (s <= t) ? pacc[sf][q] * __expf(bcs[t] - bcs[s]) : 0.f;
        *(bf16_t*)((char*)Pl + t * 128 + ((s * 2) ^ ((t & 7) << 4))) = (bf16_t)val;
      }
  }
  __syncthreads();

  // O: wave wq covers v cols wq*32..+31
  f32x4 oacc[4][2];
#pragma unroll
  for (int ti = 0; ti < 4; ++ti)
#pragma unroll
    for (int vj = 0; vj < 2; ++vj) oacc[ti][vj] = (f32x4){0.f, 0.f, 0.f, 0.f};

#pragma unroll
  for (int ks_ = 0; ks_ < 4; ++ks_) {
    bf16x8 aQ[4];
#pragma unroll
    for (int ti = 0; ti < 4; ++ti) {
      int t = ti * 16 + lr;
      union { bf16x8 v; bf16_t e[8]; } u;
      u.v = *(const bf16x8*)((const char*)qs + t * 256 + (((ks_ * 4 + lg) * 16) ^ ((t & 7) << 4)));
      float eb = __expf(bcs[t]);
#pragma unroll
      for (int e = 0; e < 8; ++e) u.e[e] = (bf16_t)((float)u.e[e] * eb);
      aQ[ti] = u.v;
    }
#pragma unroll
    for (int vj = 0; vj < 2; ++vj)
#pragma unroll
      for (int ti = 0; ti < 4; ++ti)
        oacc[ti][vj] = __builtin_amdgcn_mfma_f32_16x16x32_bf16(aQ[ti], bSv[ks_][vj], oacc[ti][vj], 0, 0, 0);
  }
#pragma unroll
  for (int ts = 0; ts < 2; ++ts) {
    bf16x8 aP[4];
#pragma unroll
    for (int ti = 0; ti < 4; ++ti) {
      int t = ti * 16 + lr;
      aP[ti] = *(const bf16x8*)((const char*)Pl + t * 128 + (((ts * 4 + lg) * 16) ^ ((t & 7) << 4)));
    }
#pragma unroll
    for (int vj = 0; vj < 2; ++vj)
#pragma unroll
      for (int ti = 0; ti < 4; ++ti)
        oacc[ti][vj] = __builtin_amdgcn_mfma_f32_16x16x32_bf16(aP[ti], bZv[ts][vj], oacc[ti][vj], 0, 0, 0);
  }

  // ---- fused gated RMSNorm (8-wave reduce) ----
  float sum2[4][4];
#pragma unroll
  for (int ti = 0; ti < 4; ++ti)
#pragma unroll
    for (int q = 0; q < 4; ++q) {
      float s = 0.f;
#pragma unroll
      for (int vj = 0; vj < 2; ++vj) s += oacc[ti][vj][q] * oacc[ti][vj][q];
      sum2[ti][q] = s;
    }
#pragma unroll
  for (int mk = 1; mk < 16; mk <<= 1)
#pragma unroll
    for (int ti = 0; ti < 4; ++ti)
#pragma unroll
      for (int q = 0; q < 4; ++q)
        sum2[ti][q] += __shfl_xor(sum2[ti][q], mk, 64);
  if (lr == 0) {
#pragma unroll
    for (int ti = 0; ti < 4; ++ti)
#pragma unroll
      for (int q = 0; q < 4; ++q)
        sred[wq][ti * 16 + lg * 4 + q] = sum2[ti][q];
  }
  __syncthreads();

  float onv[2];
#pragma unroll
  for (int vj = 0; vj < 2; ++vj) onv[vj] = onorm_w[wq * 32 + vj * 16 + lr];
#pragma unroll
  for (int ti = 0; ti < 4; ++ti)
#pragma unroll
    for (int q = 0; q < 4; ++q) {
      int t = ti * 16 + lg * 4 + q;
      float tot = 0.f;
#pragma unroll
      for (int w = 0; w < 8; ++w) tot += sred[w][t];
      float rn = rsqrtf(tot * (1.f / VV) + 1e-5f);
#pragma unroll
      for (int vj = 0; vj < 2; ++vj) {
        int v = wq * 32 + vj * 16 + lr;
        float gate = (float)fgate[(size_t)(r0 + t) * NCAT + h * VV + v];
        float y = oacc[ti][vj][q] * rn * onv[vj] * (gate / (1.f + expf(-gate)));
        ovd[(size_t)(r0 + t) * VD + h * VV + v] = (bf16_t)y;
      }
    }
}

extern "C" void kernel_launch(void* const* d_in, const int* in_sizes, int n_in,
                              void* d_out, int out_size, void* d_ws, size_t ws_size,
                              hipStream_t stream) {
  const float* hidden = (const float*)d_in[0];
  const float* Wq = (const float*)d_in[1];
  const float* Wk = (const float*)d_in[2];
  const float* Wv = (const float*)d_in[3];
  const float* Wa = (const float*)d_in[4];
  const float* Wb = (const float*)d_in[5];
  const float* A_log = (const float*)d_in[6];
  const float* dt_bias = (const float*)d_in[7];
  const float* qconv = (const float*)d_in[8];
  const float* kconv = (const float*)d_in[9];
  const float* vconv = (const float*)d_in[10];
  const float* Wg = (const float*)d_in[11];
  const float* onorm = (const float*)d_in[12];
  const float* Wo = (const float*)d_in[13];
  float* out = (float*)d_out;

  char* ws = (char*)d_ws;
  size_t off = 0;
  auto alloc = [&](size_t bytes) {
    void* p = ws + off;
    off += (bytes + 255) & ~(size_t)255;
    return p;
  };
  const int M = BB * TT;  // 2048
  bf16_t* hbf   = (bf16_t*)alloc((size_t)M * CC * 2);       // aliased by Wn16/khatT16 later
  bf16_t* WcatT = (bf16_t*)alloc((size_t)NCAT * CC * 2);
  bf16_t* WoT   = (bf16_t*)alloc((size_t)CC * VD * 2);
  bf16_t* fall  = (bf16_t*)alloc((size_t)M * NCAT * 2);     // fused q|k|v|gate projection (bf16)
  bf16_t* states = (bf16_t*)alloc((size_t)12 * NC * VV * KK * 2);  // 12.6MB
  float*  kn    = (float*) alloc((size_t)M * KD * 4);       // aliased by Zt later
  float*  vn    = (float*) alloc((size_t)M * VD * 4);       // becomes Dv in pass 1
  float*  gdec  = (float*) alloc((size_t)M * HH * 4);
  float*  beta  = (float*) alloc((size_t)M * HH * 4);
  bf16_t* ovd   = (bf16_t*)alloc((size_t)M * VD * 2);
  bf16_t* qb16  = (bf16_t*)alloc((size_t)M * KD * 2);
  bf16_t* kb16  = (bf16_t*)alloc((size_t)M * KD * 2);
  float*  bcum  = (float*) alloc((size_t)12 * NC * CL * 4);

  // aliases (stream-ordered lifetime separation):
  bf16_t* Wn16    = (bf16_t*)hbf;                     // 12*16*64*128 bf16 = 3.15MB
  bf16_t* khatT16 = Wn16 + (size_t)12 * NC * CL * KK; // +3.15MB (hbf is 8.4MB)
  bf16_t* Zt      = (bf16_t*)kn;                      // 12*16*256*64 bf16 = 6.3MB

  // beta / g + hidden->bf16 cast (fused; must precede the projection GEMM)
  k_ab<<<M, 64, 0, stream>>>(hidden, Wa, Wb, A_log, dt_bias, gdec, beta, hbf);

  // pre-pass weight transposes
  k_transpose_cvt<<<dim3(KD / 32, CC / 32), dim3(32, 8), 0, stream>>>(Wq, WcatT, CC, KD);
  k_transpose_cvt<<<dim3(KD / 32, CC / 32), dim3(32, 8), 0, stream>>>(Wk, WcatT + (size_t)768 * CC, CC, KD);
  k_transpose_cvt<<<dim3(VD / 32, CC / 32), dim3(32, 8), 0, stream>>>(Wv, WcatT + (size_t)1536 * CC, CC, VD);
  k_transpose_cvt<<<dim3(VD / 32, CC / 32), dim3(32, 8), 0, stream>>>(Wg, WcatT + (size_t)3072 * CC, CC, VD);
  k_transpose_cvt<<<dim3(CC / 32, VD / 32), dim3(32, 8), 0, stream>>>(Wo, WoT, VD, CC);

  // fused projection GEMM: [2048,2048] x [4608,2048]^T -> [2048,4608] bf16
  // BN=96 -> grid 48x16 = 768 blocks = exactly 3.0 blocks/CU (no tail imbalance)
  k_gemm_bt<96, bf16_t><<<dim3(NCAT / 96, M / 128), 256, 0, stream>>>(hbf, WcatT, fall, M, NCAT, CC);

  // conv + silu (+norm for q,k)
  k_conv_silu<<<dim3(M, HH), 128, 0, stream>>>(fall, NCAT, 0, qconv, nullptr, qb16, KD, 1);
  k_conv_silu<<<dim3(M, HH), 128, 0, stream>>>(fall, NCAT, 768, kconv, nullptr, kb16, KD, 1);
  k_conv_silu<<<dim3(M, HH), 256, 0, stream>>>(fall, NCAT, 1536, vconv, vn, nullptr, VD, 0);

  // chunked gated delta rule (hbf dead -> Wn16/khatT16; kn dead -> Zt)
  k_chunk1<<<dim3(NC, 12), 512, 0, stream>>>(kb16, vn, gdec, beta, Wn16, khatT16, bcum);
  k_chunk2<<<dim3(16, 12), 256, 0, stream>>>(vn, Wn16, khatT16, bcum, states, Zt);
  k_chunk3<<<dim3(NC, 12), 512, 0, stream>>>(qb16, kb16, Zt, states, bcum, fall + 3072, onorm, ovd);

  // output projection (f32 out), BN=64 -> grid 32x16 = 512 = 2.0 blocks/CU
  k_gemm_bt<64, float><<<dim3(CC / 64, M / 128), 256, 0, stream>>>(ovd, WoT, out, M, CC, VD);
}

// Round 18
// 203.121 us; speedup vs baseline: 1.8654x; 1.0089x over previous
//
#include <hip/hip_runtime.h>
#include <hip/hip_bf16.h>
#include <math.h>

typedef __bf16 bf16_t;
typedef __attribute__((ext_vector_type(8))) __bf16 bf16x8;
typedef __attribute__((ext_vector_type(4))) float f32x4;

#define GAS __attribute__((address_space(1)))
#define LAS __attribute__((address_space(3)))

#define BB 2
#define TT 1024
#define CC 2048
#define HH 6
#define KK 128
#define VV 256
#define KD 768
#define VD 1536
#define NQKV 3072
#define NCAT 4608
#define NC 16     // chunks per sequence
#define CL 64     // chunk length

__device__ __forceinline__ void gload_lds16(const void* g, void* l) {
  __builtin_amdgcn_global_load_lds((const GAS void*)g, (LAS void*)l, 16, 0, 0);
}

// scalar read of swizzled [64][128] bf16 tile element (t, kk)
__device__ __forceinline__ float ksh_get(const bf16_t* ksh, int t, int kk) {
  return (float)*(const bf16_t*)((const char*)ksh + t * 256 +
           ((((kk >> 3) ^ (t & 7)) * 16) + (kk & 7) * 2));
}

// ---------- transpose [Kd,Nd] f32 -> [Nd,Kd] bf16 ----------
__global__ void k_transpose_cvt(const float* __restrict__ in, bf16_t* __restrict__ out,
                                int Kd, int Nd) {
  __shared__ float t[32][33];
  int n0 = blockIdx.x * 32, k0 = blockIdx.y * 32;
  int tx = threadIdx.x, ty = threadIdx.y;
#pragma unroll
  for (int i = 0; i < 32; i += 8)
    t[ty + i][tx] = in[(size_t)(k0 + ty + i) * Nd + n0 + tx];
  __syncthreads();
#pragma unroll
  for (int i = 0; i < 32; i += 8)
    out[(size_t)(n0 + ty + i) * Kd + k0 + tx] = (bf16_t)t[tx][ty + i];
}

// ---------- bf16 MFMA GEMM: C[M,N] = A[M,K] * B^T (B is [N,K]) ----------
// BM=128, BN template (128/96/64), BK=64, XOR-swizzled LDS via pre-swizzled
// global source -> conflict-free ds_read_b128. 2D-region XCD mapping for L2.
template <int BN, typename OT>
__global__ __launch_bounds__(256, 4)
void k_gemm_bt(const bf16_t* __restrict__ A, const bf16_t* __restrict__ B,
               OT* __restrict__ C, int M, int N, int K) {
  constexpr int NFRG = BN / 32;        // per-wave n fragments
  constexpr int NB_IT = BN / 32;       // B staging iterations (BN*8/256)
  __shared__ __align__(16) bf16_t As[128 * 64];
  __shared__ __align__(16) bf16_t Bs[BN * 64];
  int tid = threadIdx.x;
  int wave = tid >> 6, lane = tid & 63;
  int wm = wave >> 1, wn = wave & 1;

  // XCD-aware mapping. Preferred: each XCD owns a (gy/2)x(gx/4) 2D region
  // (better L2 working set than a row strip). Fallback: m204 bijective chunk.
  int gx = gridDim.x, gy = gridDim.y;
  int nwg = gx * gy;
  int lin = blockIdx.y * gx + blockIdx.x;
  int bx, by;
  if ((gx % 4 == 0) && (gy % 2 == 0) && (nwg % 8 == 0)) {
    int xcd = lin & 7, c = lin >> 3;
    int RX = gx >> 2;                 // region width
    by = (xcd >> 2) * (gy >> 1) + c / RX;
    bx = (xcd & 3) * RX + c % RX;
  } else {
    int q8 = nwg >> 3, r8 = nwg & 7;
    int xcd = lin & 7, off8 = lin >> 3;
    int wgid = (xcd < r8 ? xcd * (q8 + 1) : r8 * (q8 + 1) + (xcd - r8) * q8) + off8;
    bx = wgid % gx; by = wgid / gx;
  }

  const bf16_t* Abase = A + (size_t)by * 128 * K;
  const bf16_t* Bbase = B + (size_t)bx * BN * K;

  f32x4 acc[4][NFRG];
#pragma unroll
  for (int i = 0; i < 4; ++i)
#pragma unroll
    for (int j = 0; j < NFRG; ++j) acc[i][j] = (f32x4){0.f, 0.f, 0.f, 0.f};

  int kg = lane >> 4, lr = lane & 15;

  for (int k0 = 0; k0 < K; k0 += 64) {
#pragma unroll
    for (int it = 0; it < 4; ++it) {
      int idx = it * 256 + tid;
      int row = idx >> 3, slot = idx & 7;
      const bf16_t* ga = Abase + (size_t)row * K + k0 + ((slot ^ (row & 7)) * 8);
      gload_lds16(ga, As + (size_t)(it * 256 + wave * 64) * 8);
    }
#pragma unroll
    for (int it = 0; it < NB_IT; ++it) {
      int idx = it * 256 + tid;
      int row = idx >> 3, slot = idx & 7;
      const bf16_t* gb = Bbase + (size_t)row * K + k0 + ((slot ^ (row & 7)) * 8);
      gload_lds16(gb, Bs + (size_t)(it * 256 + wave * 64) * 8);
    }
    __syncthreads();
#pragma unroll
    for (int ks2 = 0; ks2 < 2; ++ks2) {
      int j = ks2 * 4 + kg;
      bf16x8 af[4], bfv[NFRG];
#pragma unroll
      for (int i = 0; i < 4; ++i) {
        int ra = wm * 64 + i * 16 + lr;
        af[i] = *(const bf16x8*)((const char*)As + ra * 128 + ((j ^ (ra & 7)) * 16));
      }
#pragma unroll
      for (int i = 0; i < NFRG; ++i) {
        int rb = wn * (BN / 2) + i * 16 + lr;
        bfv[i] = *(const bf16x8*)((const char*)Bs + rb * 128 + ((j ^ (rb & 7)) * 16));
      }
#pragma unroll
      for (int i = 0; i < 4; ++i)
#pragma unroll
        for (int jj = 0; jj < NFRG; ++jj)
          acc[i][jj] = __builtin_amdgcn_mfma_f32_16x16x32_bf16(af[i], bfv[jj], acc[i][jj], 0, 0, 0);
    }
    __syncthreads();
  }

#pragma unroll
  for (int i = 0; i < 4; ++i) {
    int r0 = by * 128 + wm * 64 + i * 16 + ((lane >> 4) << 2);
#pragma unroll
    for (int j = 0; j < NFRG; ++j) {
      int c = bx * BN + wn * (BN / 2) + j * 16 + (lane & 15);
      OT* Cp = C + (size_t)r0 * N + c;
#pragma unroll
      for (int q = 0; q < 4; ++q) Cp[(size_t)q * N] = (OT)acc[i][j][q];
    }
  }
}

// ---------- beta / g + fused hidden->bf16 cast ----------
__global__ __launch_bounds__(64)
void k_ab(const float* __restrict__ hidden, const float* __restrict__ Wa,
          const float* __restrict__ Wb, const float* __restrict__ A_log,
          const float* __restrict__ dt_bias, float* __restrict__ g_out,
          float* __restrict__ beta_out, bf16_t* __restrict__ hbf) {
  int row = blockIdx.x;
  int lane = threadIdx.x;
  float accA[6] = {0, 0, 0, 0, 0, 0};
  float accB[6] = {0, 0, 0, 0, 0, 0};
  const float* h = hidden + (size_t)row * CC;
  bf16_t* hb = hbf + (size_t)row * CC;
  for (int c = lane; c < CC; c += 64) {
    float x = h[c];
    hb[c] = (bf16_t)x;
    const float* wa = Wa + c * 6;
    const float* wb = Wb + c * 6;
#pragma unroll
    for (int j = 0; j < 6; ++j) {
      accA[j] += x * wa[j];
      accB[j] += x * wb[j];
    }
  }
#pragma unroll
  for (int j = 0; j < 6; ++j) {
    for (int off = 32; off; off >>= 1) {
      accA[j] += __shfl_down(accA[j], off);
      accB[j] += __shfl_down(accB[j], off);
    }
  }
  if (lane == 0) {
#pragma unroll
    for (int j = 0; j < 6; ++j) {
      float a = accA[j] + dt_bias[j];
      float sp = (a > 20.f) ? a : log1pf(expf(a));
      g_out[(size_t)row * 6 + j] = -expf(A_log[j]) * sp;
      beta_out[(size_t)row * 6 + j] = 1.f / (1.f + expf(-accB[j]));
    }
  }
}

// ---------- depthwise causal conv(4) + SiLU (+ optional L2 norm); bf16 input ----------
__global__ void k_conv_silu(const bf16_t* __restrict__ pre, int ldpre, int col0,
                            const float* __restrict__ w, float* __restrict__ out,
                            bf16_t* __restrict__ out16, int ld_out, int do_norm) {
  int row = blockIdx.x;     // b*T + t
  int t = row & (TT - 1);
  int h = blockIdx.y;
  int kk = threadIdx.x;
  int perH = blockDim.x;
  int ch = h * perH + kk;
  const float* wp = w + ch * 4;
  float y = 0.f;
#pragma unroll
  for (int i = 0; i < 4; ++i) {
    int tt = t - 3 + i;
    if (tt >= 0) y += wp[i] * (float)pre[(size_t)(row - 3 + i) * ldpre + col0 + ch];
  }
  float s = y / (1.f + expf(-y));
  if (do_norm) {
    float ss = s * s;
#pragma unroll
    for (int off = 32; off; off >>= 1) ss += __shfl_down(ss, off);
    __shared__ float red[2];
    if ((threadIdx.x & 63) == 0) red[threadIdx.x >> 6] = ss;
    __syncthreads();
    float nrm = sqrtf(red[0] + red[1]);
    s = s / (nrm + 1e-6f);
  }
  if (out) out[(size_t)row * ld_out + ch] = s;
  if (out16) out16[(size_t)row * ld_out + ch] = (bf16_t)s;
}

// ============ chunked gated delta rule ============
// Pass 1 (R8's UT transform, 8-wave version): 512 thr; phase D = 3 n-tiles/wave.
__global__ __launch_bounds__(512, 2)
void k_chunk1(const bf16_t* __restrict__ kb16, float* dv,
              const float* __restrict__ gdec, const float* __restrict__ beta,
              bf16_t* __restrict__ Wn16, bf16_t* __restrict__ khatT16,
              float* __restrict__ bcum) {
  __shared__ __align__(16) bf16_t ksh[64 * 128];    // 16KB [t][k] swizzled
  __shared__ __align__(16) bf16_t Mb[64 * 64];      // 8KB  [t][s] = -M, swizzled
  __shared__ __align__(16) bf16_t Tdl[4 * 16 * 32]; // 4KB  diag-block inverses, k:16..31 zero
  __shared__ __align__(16) bf16_t Yb[384 * 32];     // 24KB [n][k] Ytmp (B-frag layout), k:16..31 zero
  __shared__ __align__(16) bf16_t Xall[384 * 64];   // 48KB [n][s] solved X (B-frag layout)
  __shared__ float bc[64], bet[64];

  int tid = threadIdx.x;
  int bh = blockIdx.y, c = blockIdx.x;
  int b = bh / HH, h = bh % HH;
  int r0 = b * TT + c * CL;
  size_t cb = (size_t)bh * NC + c;
  int wq = tid >> 6, l = tid & 63;
  int lr = l & 15, lg = l >> 4;

  // ---- phase A ----
#pragma unroll
  for (int it = 0; it < 2; ++it) {
    int idx = it * 512 + tid;
    int t = idx >> 4, p = idx & 15;
    int kslot = p ^ (t & 7);
    gload_lds16(kb16 + (size_t)(r0 + t) * KD + h * KK + kslot * 8,
                ksh + (size_t)idx * 8);
  }
  if (tid < 64) {
    float val = gdec[(size_t)(r0 + tid) * HH + h];
    bet[tid] = beta[(size_t)(r0 + tid) * HH + h];
#pragma unroll
    for (int off = 1; off < 64; off <<= 1) {
      float o = __shfl_up(val, off, 64);
      if (tid >= off) val += o;
    }
    bc[tid] = val;
    bcum[cb * CL + tid] = val;
  }
  __syncthreads();
  float bL = bc[63];

  // ---- phase B ----
  {
    f32x4 z4 = (f32x4){0.f, 0.f, 0.f, 0.f};
#pragma unroll
    for (int i = 0; i < 6; ++i) ((f32x4*)Xall)[i * 512 + tid] = z4;
#pragma unroll
    for (int i = 0; i < 3; ++i) ((f32x4*)Yb)[i * 512 + tid] = z4;
    if (tid < 256) ((f32x4*)Tdl)[tid] = z4;
  }
  if (wq < 4) {
    f32x4 pacc[4];
#pragma unroll
    for (int sf = 0; sf < 4; ++sf) pacc[sf] = (f32x4){0.f, 0.f, 0.f, 0.f};
#pragma unroll
    for (int ks_ = 0; ks_ < 4; ++ks_) {
      int trow = wq * 16 + lr;
      bf16x8 aK = *(const bf16x8*)((const char*)ksh + trow * 256 + (((ks_ * 4 + lg) * 16) ^ ((trow & 7) << 4)));
#pragma unroll
      for (int sf = 0; sf < 4; ++sf) {
        int srow = sf * 16 + lr;
        bf16x8 bK = *(const bf16x8*)((const char*)ksh + srow * 256 + (((ks_ * 4 + lg) * 16) ^ ((srow & 7) << 4)));
        pacc[sf] = __builtin_amdgcn_mfma_f32_16x16x32_bf16(aK, bK, pacc[sf], 0, 0, 0);
      }
    }
#pragma unroll
    for (int sf = 0; sf < 4; ++sf)
#pragma unroll
      for (int q = 0; q < 4; ++q) {
        int t = wq * 16 + lg * 4 + q;
        int s = sf * 16 + lr;
        float val = (s < t) ? -bet[t] * __expf(bc[t] - bc[s]) * pacc[sf][q] : 0.f;
        *(bf16_t*)((char*)Mb + t * 128 + ((s * 2) ^ ((t & 7) << 4))) = (bf16_t)val;
      }
  }
  __syncthreads();

  // ---- phase C ----
  if (tid < 64) {
    int d = tid >> 4, cc = tid & 15;
    float x[16];
#pragma unroll
    for (int s = 0; s < 16; ++s) x[s] = (s == cc) ? 1.f : 0.f;
#pragma unroll
    for (int r = 1; r < 16; ++r) {
      float a = 0.f;
#pragma unroll
      for (int s = 0; s < r; ++s) {
        float m = (float)*(const bf16_t*)((const char*)Mb + (16 * d + r) * 128 +
                    (((16 * d + s) * 2) ^ ((r & 7) << 4)));
        a += m * x[s];
      }
      x[r] += a;
    }
#pragma unroll
    for (int r = 0; r < 16; ++r)
      *(bf16_t*)((char*)Tdl + d * 1024 + r * 64 +
          ((((cc >> 3) * 16) ^ ((r & 3) << 4)) + (cc & 7) * 2)) = (bf16_t)x[r];
  } else if (tid < 192) {
    int kk = tid - 64;
    bf16_t* kout = khatT16 + cb * (size_t)(KK * CL) + (size_t)kk * CL;
#pragma unroll
    for (int t8 = 0; t8 < 8; ++t8) {
      union { bf16x8 v; bf16_t e[8]; } u;
#pragma unroll
      for (int e = 0; e < 8; ++e) {
        int t = t8 * 8 + e;
        u.e[e] = (bf16_t)(__expf(bL - bc[t]) * ksh_get(ksh, t, kk));
      }
      *(bf16x8*)(kout + t8 * 8) = u.v;
    }
  }
  __syncthreads();

  // ---- phase D ----
  const int nbase = wq * 48;
#pragma unroll
  for (int st = 0; st < 4; ++st) {
#pragma unroll
    for (int nt = 0; nt < 3; ++nt) {
      const int n0 = nbase + nt * 16;
      const bool isv = (n0 < 256);
      const int n = n0 + lr;
      f32x4 acc = (f32x4){0.f, 0.f, 0.f, 0.f};
      if (isv) {
#pragma unroll
        for (int q = 0; q < 4; ++q) {
          int t = st * 16 + lg * 4 + q;
          acc[q] = bet[t] * dv[(size_t)(r0 + t) * VD + h * VV + n];
        }
      } else {
        int kk = n - 256;
#pragma unroll
        for (int q = 0; q < 4; ++q) {
          int t = st * 16 + lg * 4 + q;
          acc[q] = bet[t] * __expf(bc[t]) * ksh_get(ksh, t, kk);
        }
      }
#pragma unroll
      for (int p = 0; p < 2; ++p) {
        if ((p == 0 && st >= 1) || (p == 1 && st == 3)) {
          int arow = st * 16 + lr;
          bf16x8 aM = *(const bf16x8*)((const char*)Mb + arow * 128 +
                         (((p * 4 + lg) * 16) ^ ((arow & 7) << 4)));
          bf16x8 bX = *(const bf16x8*)((const char*)Xall + n * 128 +
                         (((p * 4 + lg) * 16) ^ ((n & 7) << 4)));
          acc = __builtin_amdgcn_mfma_f32_16x16x32_bf16(aM, bX, acc, 0, 0, 0);
        }
      }
#pragma unroll
      for (int q = 0; q < 4; ++q) {
        int tq = lg * 4 + q;
        *(bf16_t*)((char*)Yb + n * 64 +
            ((((tq >> 3) * 16) ^ ((n & 3) << 4)) + (tq & 7) * 2)) = (bf16_t)acc[q];
      }
      f32x4 acc2 = (f32x4){0.f, 0.f, 0.f, 0.f};
      {
        bf16x8 aT = *(const bf16x8*)((const char*)Tdl + st * 1024 + lr * 64 +
                       ((lg * 16) ^ ((lr & 3) << 4)));
        bf16x8 bY = *(const bf16x8*)((const char*)Yb + n * 64 +
                       ((lg * 16) ^ ((n & 3) << 4)));
        acc2 = __builtin_amdgcn_mfma_f32_16x16x32_bf16(aT, bY, acc2, 0, 0, 0);
      }
      if (st < 3) {
#pragma unroll
        for (int q = 0; q < 4; ++q) {
          int s = st * 16 + lg * 4 + q;
          *(bf16_t*)((char*)Xall + n * 128 +
              ((((s >> 3) * 16) ^ ((n & 7) << 4)) + (s & 7) * 2)) = (bf16_t)acc2[q];
        }
      }
      if (isv) {
#pragma unroll
        for (int q = 0; q < 4; ++q) {
          int t = st * 16 + lg * 4 + q;
          dv[(size_t)(r0 + t) * VD + h * VV + n] = acc2[q];
        }
      } else {
        int kk = n - 256;
#pragma unroll
        for (int q = 0; q < 4; ++q) {
          int t = st * 16 + lg * 4 + q;
          Wn16[(cb * CL + t) * KK + kk] = (bf16_t)(-acc2[q]);
        }
      }
    }
  }
}

// Pass 2: MFMA state propagation. Grid (16 vtiles of 16, 12 bh), 256 thr.
__global__ __launch_bounds__(256, 1)
void k_chunk2(const float* __restrict__ dv, const bf16_t* __restrict__ Wn16,
              const bf16_t* __restrict__ khatT16, const float* __restrict__ bcum,
              bf16_t* __restrict__ states, bf16_t* __restrict__ Zt) {
  __shared__ __align__(16) bf16_t St[16 * 128];   // [v][k], XOR-swizzled
  __shared__ __align__(16) bf16_t Zl[16 * 64];    // [v][t], XOR-swizzled
  int tid = threadIdx.x;
  int vt = blockIdx.x, bh = blockIdx.y;
  int b = bh / HH, h = bh % HH;
  int wq = tid >> 6, l = tid & 63;
  int lr = l & 15, lg = l >> 4;

  f32x4 acc[2];
#pragma unroll
  for (int kf = 0; kf < 2; ++kf) acc[kf] = (f32x4){0.f, 0.f, 0.f, 0.f};

  for (int c = 0; c < NC; ++c) {
    size_t cb = (size_t)bh * NC + c;
    int r0 = b * TT + c * CL;
    float ebL = __expf(bcum[cb * CL + 63]);

#pragma unroll
    for (int kf = 0; kf < 2; ++kf)
#pragma unroll
      for (int q = 0; q < 4; ++q) {
        int k = wq * 32 + kf * 16 + lg * 4 + q;
        int v = lr;
        *(bf16_t*)((char*)St + v * 256 + ((k * 2) ^ ((v & 7) << 4))) = (bf16_t)acc[kf][q];
      }
    __syncthreads();

    {
      int v = tid >> 4, slot = tid & 15;
      bf16x8 val = *(const bf16x8*)((const char*)St + v * 256 + ((slot * 16) ^ ((v & 7) << 4)));
      *(bf16x8*)(states + ((size_t)cb * 256 + vt * 16 + v) * 128 + slot * 8) = val;
    }

    f32x4 zacc = (f32x4){0.f, 0.f, 0.f, 0.f};
#pragma unroll
    for (int q = 0; q < 4; ++q) {
      int t = wq * 16 + lg * 4 + q;
      zacc[q] = dv[(size_t)(r0 + t) * VD + h * VV + vt * 16 + lr];
    }
#pragma unroll
    for (int ks_ = 0; ks_ < 4; ++ks_) {
      bf16x8 aW = *(const bf16x8*)(Wn16 + (cb * CL + wq * 16 + lr) * KK + ks_ * 32 + lg * 8);
      int v = lr;
      bf16x8 bS = *(const bf16x8*)((const char*)St + v * 256 + (((ks_ * 32 + lg * 8) * 2) ^ ((v & 7) << 4)));
      zacc = __builtin_amdgcn_mfma_f32_16x16x32_bf16(aW, bS, zacc, 0, 0, 0);
    }
#pragma unroll
    for (int q = 0; q < 4; ++q) {
      int t = wq * 16 + lg * 4 + q;
      int v = lr;
      *(bf16_t*)((char*)Zl + v * 128 + ((t * 2) ^ ((v & 7) << 4))) = (bf16_t)zacc[q];
    }
    __syncthreads();

    if (tid < 128) {
      int v = tid >> 3, slot = tid & 7;
      bf16x8 val = *(const bf16x8*)((const char*)Zl + v * 128 + ((slot * 16) ^ ((v & 7) << 4)));
      *(bf16x8*)(Zt + ((size_t)cb * 256 + vt * 16 + v) * 64 + slot * 8) = val;
    }
#pragma unroll
    for (int kf = 0; kf < 2; ++kf)
#pragma unroll
      for (int q = 0; q < 4; ++q) acc[kf][q] *= ebL;
#pragma unroll
    for (int ts = 0; ts < 2; ++ts) {
      bf16x8 aK[2];
#pragma unroll
      for (int kf = 0; kf < 2; ++kf)
        aK[kf] = *(const bf16x8*)(khatT16 + (cb * KK + wq * 32 + kf * 16 + lr) * CL + ts * 32 + lg * 8);
      int v = lr;
      bf16x8 bZ = *(const bf16x8*)((const char*)Zl + v * 128 + (((ts * 32 + lg * 8) * 2) ^ ((v & 7) << 4)));
#pragma unroll
      for (int kf = 0; kf < 2; ++kf)
        acc[kf] = __builtin_amdgcn_mfma_f32_16x16x32_bf16(aK[kf], bZ, acc[kf], 0, 0, 0);
    }
  }
}

// Pass 3 (8-wave): o = e^{b_t} q^T S0 + P Z (MFMA) + fused gated RMSNorm.
__global__ __launch_bounds__(512, 2)
void k_chunk3(const bf16_t* __restrict__ qb16, const bf16_t* __restrict__ kb16,
              const bf16_t* __restrict__ Zt, const bf16_t* __restrict__ states,
              const float* __restrict__ bcum, const bf16_t* __restrict__ fgate,
              const float* __restrict__ onorm_w, bf16_t* __restrict__ ovd) {
  __shared__ __align__(16) bf16_t qs[64 * 128];   // [t][k] swizzled via pre-XOR source
  __shared__ __align__(16) bf16_t ksh[64 * 128];
  __shared__ __align__(16) bf16_t Pl[64 * 64];    // [t][s] swizzled
  __shared__ float bcs[64];
  __shared__ float sred[8][64];

  int tid = threadIdx.x;
  int c = blockIdx.x, bh = blockIdx.y;
  int b = bh / HH, h = bh % HH;
  int r0 = b * TT + c * CL;
  size_t cb = (size_t)bh * NC + c;
  int wq = tid >> 6, l = tid & 63;
  int lr = l & 15, lg = l >> 4;

  // hoisted global B-frag loads: latency hides under staging + P phase
  bf16x8 bSv[4][2], bZv[2][2];
#pragma unroll
  for (int vj = 0; vj < 2; ++vj) {
    int vrow = wq * 32 + vj * 16 + lr;
#pragma unroll
    for (int ks_ = 0; ks_ < 4; ++ks_)
      bSv[ks_][vj] = *(const bf16x8*)(states + ((size_t)cb * 256 + vrow) * 128 + ks_ * 32 + lg * 8);
#pragma unroll
    for (int ts = 0; ts < 2; ++ts)
      bZv[ts][vj] = *(const bf16x8*)(Zt + ((size_t)cb * 256 + vrow) * 64 + ts * 32 + lg * 8);
  }

  if (tid < 64) bcs[tid] = bcum[cb * CL + tid];
#pragma unroll
  for (int it = 0; it < 2; ++it) {
    int idx = it * 512 + tid;
    int t = idx >> 4, p = idx & 15;
    int kslot = p ^ (t & 7);
    gload_lds16(qb16 + (size_t)(r0 + t) * KD + h * KK + kslot * 8,
                qs + (size_t)idx * 8);
    gload_lds16(kb16 + (size_t)(r0 + t) * KD + h * KK + kslot * 8,
                ksh + (size_t)idx * 8);
  }
  __syncthreads();

  if (wq < 4) {
    f32x4 pacc[4];
#pragma unroll
    for (int sf = 0; sf < 4; ++sf) pacc[sf] = (f32x4){0.f, 0.f, 0.f, 0.f};
#pragma unroll
    for (int ks_ = 0; ks_ < 4; ++ks_) {
      int trow = wq * 16 + lr;
      bf16x8 aQ = *(const bf16x8*)((const char*)qs + trow * 256 + (((ks_ * 4 + lg) * 16) ^ ((trow & 7) << 4)));
#pragma unroll
      for (int sf = 0; sf < 4; ++sf) {
        int srow = sf * 16 + lr;
        bf16x8 bK = *(const bf16x8*)((const char*)ksh + srow * 256 + (((ks_ * 4 + lg) * 16) ^ ((srow & 7) << 4)));
        pacc[sf] = __builtin_amdgcn_mfma_f32_16x16x32_bf16(aQ, bK, pacc[sf], 0, 0, 0);
      }
    }
#pragma unroll
    for (int sf = 0; sf < 4; ++sf)
#pragma unroll
      for (int q = 0; q < 4; ++q) {
        int t = wq * 16 + lg * 4 + q;
        int s = sf * 16 + lr;
        float val = (s <= t) ? pacc[sf][q] * __expf(bcs[t] - bcs[s]) : 0.f;
        *(bf16_t*)((char*)Pl + t * 128 + ((s * 2) ^ ((t & 7) << 4))) = (bf16_t)val;
      }
  }
  __syncthreads();

  // O: wave wq covers v cols wq*32..+31
  f32x4 oacc[4][2];
#pragma unroll
  for (int ti = 0; ti < 4; ++ti)
#pragma unroll
    for (int vj = 0; vj < 2; ++vj) oacc[ti][vj] = (f32x4){0.f, 0.f, 0.f, 0.f};

#pragma unroll
  for (int ks_ = 0; ks_ < 4; ++ks_) {
    bf16x8 aQ[4];
#pragma unroll
    for (int ti = 0; ti < 4; ++ti) {
      int t = ti * 16 + lr;
      union { bf16x8 v; bf16_t e[8]; } u;
      u.v = *(const bf16x8*)((const char*)qs + t * 256 + (((ks_ * 4 + lg) * 16) ^ ((t & 7) << 4)));
      float eb = __expf(bcs[t]);
#pragma unroll
      for (int e = 0; e < 8; ++e) u.e[e] = (bf16_t)((float)u.e[e] * eb);
      aQ[ti] = u.v;
    }
#pragma unroll
    for (int vj = 0; vj < 2; ++vj)
#pragma unroll
      for (int ti = 0; ti < 4; ++ti)
        oacc[ti][vj] = __builtin_amdgcn_mfma_f32_16x16x32_bf16(aQ[ti], bSv[ks_][vj], oacc[ti][vj], 0, 0, 0);
  }
#pragma unroll
  for (int ts = 0; ts < 2; ++ts) {
    bf16x8 aP[4];
#pragma unroll
    for (int ti = 0; ti < 4; ++ti) {
      int t = ti * 16 + lr;
      aP[ti] = *(const bf16x8*)((const char*)Pl + t * 128 + (((ts * 4 + lg) * 16) ^ ((t & 7) << 4)));
    }
#pragma unroll
    for (int vj = 0; vj < 2; ++vj)
#pragma unroll
      for (int ti = 0; ti < 4; ++ti)
        oacc[ti][vj] = __builtin_amdgcn_mfma_f32_16x16x32_bf16(aP[ti], bZv[ts][vj], oacc[ti][vj], 0, 0, 0);
  }

  // ---- fused gated RMSNorm (8-wave reduce) ----
  float sum2[4][4];
#pragma unroll
  for (int ti = 0; ti < 4; ++ti)
#pragma unroll
    for (int q = 0; q < 4; ++q) {
      float s = 0.f;
#pragma unroll
      for (int vj = 0; vj < 2; ++vj) s += oacc[ti][vj][q] * oacc[ti][vj][q];
      sum2[ti][q] = s;
    }
#pragma unroll
  for (int mk = 1; mk < 16; mk <<= 1)
#pragma unroll
    for (int ti = 0; ti < 4; ++ti)
#pragma unroll
      for (int q = 0; q < 4; ++q)
        sum2[ti][q] += __shfl_xor(sum2[ti][q], mk, 64);
  if (lr == 0) {
#pragma unroll
    for (int ti = 0; ti < 4; ++ti)
#pragma unroll
      for (int q = 0; q < 4; ++q)
        sred[wq][ti * 16 + lg * 4 + q] = sum2[ti][q];
  }
  __syncthreads();

  float onv[2];
#pragma unroll
  for (int vj = 0; vj < 2; ++vj) onv[vj] = onorm_w[wq * 32 + vj * 16 + lr];
#pragma unroll
  for (int ti = 0; ti < 4; ++ti)
#pragma unroll
    for (int q = 0; q < 4; ++q) {
      int t = ti * 16 + lg * 4 + q;
      float tot = 0.f;
#pragma unroll
      for (int w = 0; w < 8; ++w) tot += sred[w][t];
      float rn = rsqrtf(tot * (1.f / VV) + 1e-5f);
#pragma unroll
      for (int vj = 0; vj < 2; ++vj) {
        int v = wq * 32 + vj * 16 + lr;
        float gate = (float)fgate[(size_t)(r0 + t) * NCAT + h * VV + v];
        float y = oacc[ti][vj][q] * rn * onv[vj] * (gate / (1.f + expf(-gate)));
        ovd[(size_t)(r0 + t) * VD + h * VV + v] = (bf16_t)y;
      }
    }
}

extern "C" void kernel_launch(void* const* d_in, const int* in_sizes, int n_in,
                              void* d_out, int out_size, void* d_ws, size_t ws_size,
                              hipStream_t stream) {
  const float* hidden = (const float*)d_in[0];
  const float* Wq = (const float*)d_in[1];
  const float* Wk = (const float*)d_in[2];
  const float* Wv = (const float*)d_in[3];
  const float* Wa = (const float*)d_in[4];
  const float* Wb = (const float*)d_in[5];
  const float* A_log = (const float*)d_in[6];
  const float* dt_bias = (const float*)d_in[7];
  const float* qconv = (const float*)d_in[8];
  const float* kconv = (const float*)d_in[9];
  const float* vconv = (const float*)d_in[10];
  const float* Wg = (const float*)d_in[11];
  const float* onorm = (const float*)d_in[12];
  const float* Wo = (const float*)d_in[13];
  float* out = (float*)d_out;

  char* ws = (char*)d_ws;
  size_t off = 0;
  auto alloc = [&](size_t bytes) {
    void* p = ws + off;
    off += (bytes + 255) & ~(size_t)255;
    return p;
  };
  const int M = BB * TT;  // 2048
  bf16_t* hbf   = (bf16_t*)alloc((size_t)M * CC * 2);       // aliased by Wn16/khatT16 later
  bf16_t* WcatT = (bf16_t*)alloc((size_t)NCAT * CC * 2);
  bf16_t* WoT   = (bf16_t*)alloc((size_t)CC * VD * 2);
  bf16_t* fall  = (bf16_t*)alloc((size_t)M * NCAT * 2);     // fused q|k|v|gate projection (bf16)
  bf16_t* states = (bf16_t*)alloc((size_t)12 * NC * VV * KK * 2);  // 12.6MB
  float*  kn    = (float*) alloc((size_t)M * KD * 4);       // aliased by Zt later
  float*  vn    = (float*) alloc((size_t)M * VD * 4);       // becomes Dv in pass 1
  float*  gdec  = (float*) alloc((size_t)M * HH * 4);
  float*  beta  = (float*) alloc((size_t)M * HH * 4);
  bf16_t* ovd   = (bf16_t*)alloc((size_t)M * VD * 2);
  bf16_t* qb16  = (bf16_t*)alloc((size_t)M * KD * 2);
  bf16_t* kb16  = (bf16_t*)alloc((size_t)M * KD * 2);
  float*  bcum  = (float*) alloc((size_t)12 * NC * CL * 4);

  // aliases (stream-ordered lifetime separation):
  bf16_t* Wn16    = (bf16_t*)hbf;                     // 12*16*64*128 bf16 = 3.15MB
  bf16_t* khatT16 = Wn16 + (size_t)12 * NC * CL * KK; // +3.15MB (hbf is 8.4MB)
  bf16_t* Zt      = (bf16_t*)kn;                      // 12*16*256*64 bf16 = 6.3MB

  // beta / g + hidden->bf16 cast (fused; must precede the projection GEMM)
  k_ab<<<M, 64, 0, stream>>>(hidden, Wa, Wb, A_log, dt_bias, gdec, beta, hbf);

  // pre-pass weight transposes
  k_transpose_cvt<<<dim3(KD / 32, CC / 32), dim3(32, 8), 0, stream>>>(Wq, WcatT, CC, KD);
  k_transpose_cvt<<<dim3(KD / 32, CC / 32), dim3(32, 8), 0, stream>>>(Wk, WcatT + (size_t)768 * CC, CC, KD);
  k_transpose_cvt<<<dim3(VD / 32, CC / 32), dim3(32, 8), 0, stream>>>(Wv, WcatT + (size_t)1536 * CC, CC, VD);
  k_transpose_cvt<<<dim3(VD / 32, CC / 32), dim3(32, 8), 0, stream>>>(Wg, WcatT + (size_t)3072 * CC, CC, VD);
  k_transpose_cvt<<<dim3(CC / 32, VD / 32), dim3(32, 8), 0, stream>>>(Wo, WoT, VD, CC);

  // fused projection GEMM: [2048,2048] x [4608,2048]^T -> [2048,4608] bf16
  k_gemm_bt<96, bf16_t><<<dim3(NCAT / 96, M / 128), 256, 0, stream>>>(hbf, WcatT, fall, M, NCAT, CC);

  // conv + silu (+norm for q,k)
  k_conv_silu<<<dim3(M, HH), 128, 0, stream>>>(fall, NCAT, 0, qconv, nullptr, qb16, KD, 1);
  k_conv_silu<<<dim3(M, HH), 128, 0, stream>>>(fall, NCAT, 768, kconv, nullptr, kb16, KD, 1);
  k_conv_silu<<<dim3(M, HH), 256, 0, stream>>>(fall, NCAT, 1536, vconv, vn, nullptr, VD, 0);

  // chunked gated delta rule (hbf dead -> Wn16/khatT16; kn dead -> Zt)
  k_chunk1<<<dim3(NC, 12), 512, 0, stream>>>(kb16, vn, gdec, beta, Wn16, khatT16, bcum);
  k_chunk2<<<dim3(16, 12), 256, 0, stream>>>(vn, Wn16, khatT16, bcum, states, Zt);
  k_chunk3<<<dim3(NC, 12), 512, 0, stream>>>(qb16, kb16, Zt, states, bcum, fall + 3072, onorm, ovd);

  // output projection (f32 out), BN=64 -> grid 32x16 = 512 = 2.0 blocks/CU
  k_gemm_bt<64, float><<<dim3(CC / 64, M / 128), 256, 0, stream>>>(ovd, WoT, out, M, CC, VD);
}

// Round 19
// 199.467 us; speedup vs baseline: 1.8995x; 1.0183x over previous
//
#include <hip/hip_runtime.h>
#include <hip/hip_bf16.h>
#include <math.h>

typedef __bf16 bf16_t;
typedef __attribute__((ext_vector_type(8))) __bf16 bf16x8;
typedef __attribute__((ext_vector_type(4))) float f32x4;

#define GAS __attribute__((address_space(1)))
#define LAS __attribute__((address_space(3)))

#define BB 2
#define TT 1024
#define CC 2048
#define HH 6
#define KK 128
#define VV 256
#define KD 768
#define VD 1536
#define NQKV 3072
#define NCAT 4608
#define NC 16     // chunks per sequence
#define CL 64     // chunk length

__device__ __forceinline__ void gload_lds16(const void* g, void* l) {
  __builtin_amdgcn_global_load_lds((const GAS void*)g, (LAS void*)l, 16, 0, 0);
}

// scalar read of swizzled [64][128] bf16 tile element (t, kk)
__device__ __forceinline__ float ksh_get(const bf16_t* ksh, int t, int kk) {
  return (float)*(const bf16_t*)((const char*)ksh + t * 256 +
           ((((kk >> 3) ^ (t & 7)) * 16) + (kk & 7) * 2));
}

// ---------- transpose [Kd,Nd] f32 -> [Nd,Kd] bf16 ----------
__global__ void k_transpose_cvt(const float* __restrict__ in, bf16_t* __restrict__ out,
                                int Kd, int Nd) {
  __shared__ float t[32][33];
  int n0 = blockIdx.x * 32, k0 = blockIdx.y * 32;
  int tx = threadIdx.x, ty = threadIdx.y;
#pragma unroll
  for (int i = 0; i < 32; i += 8)
    t[ty + i][tx] = in[(size_t)(k0 + ty + i) * Nd + n0 + tx];
  __syncthreads();
#pragma unroll
  for (int i = 0; i < 32; i += 8)
    out[(size_t)(n0 + ty + i) * Kd + k0 + tx] = (bf16_t)t[tx][ty + i];
}

// ---------- bf16 MFMA GEMM: C[M,N] = A[M,K] * B^T (B is [N,K]) ----------
template <int BN, typename OT>
__global__ __launch_bounds__(256, 4)
void k_gemm_bt(const bf16_t* __restrict__ A, const bf16_t* __restrict__ B,
               OT* __restrict__ C, int M, int N, int K) {
  constexpr int NFRG = BN / 32;
  constexpr int NB_IT = BN / 32;
  __shared__ __align__(16) bf16_t As[128 * 64];
  __shared__ __align__(16) bf16_t Bs[BN * 64];
  int tid = threadIdx.x;
  int wave = tid >> 6, lane = tid & 63;
  int wm = wave >> 1, wn = wave & 1;

  // XCD-aware mapping: 2D region per XCD if divisible, else m204 chunk.
  int gx = gridDim.x, gy = gridDim.y;
  int nwg = gx * gy;
  int lin = blockIdx.y * gx + blockIdx.x;
  int bx, by;
  if ((gx % 4 == 0) && (gy % 2 == 0) && (nwg % 8 == 0)) {
    int xcd = lin & 7, c = lin >> 3;
    int RX = gx >> 2;
    by = (xcd >> 2) * (gy >> 1) + c / RX;
    bx = (xcd & 3) * RX + c % RX;
  } else {
    int q8 = nwg >> 3, r8 = nwg & 7;
    int xcd = lin & 7, off8 = lin >> 3;
    int wgid = (xcd < r8 ? xcd * (q8 + 1) : r8 * (q8 + 1) + (xcd - r8) * q8) + off8;
    bx = wgid % gx; by = wgid / gx;
  }

  const bf16_t* Abase = A + (size_t)by * 128 * K;
  const bf16_t* Bbase = B + (size_t)bx * BN * K;

  f32x4 acc[4][NFRG];
#pragma unroll
  for (int i = 0; i < 4; ++i)
#pragma unroll
    for (int j = 0; j < NFRG; ++j) acc[i][j] = (f32x4){0.f, 0.f, 0.f, 0.f};

  int kg = lane >> 4, lr = lane & 15;

  for (int k0 = 0; k0 < K; k0 += 64) {
#pragma unroll
    for (int it = 0; it < 4; ++it) {
      int idx = it * 256 + tid;
      int row = idx >> 3, slot = idx & 7;
      const bf16_t* ga = Abase + (size_t)row * K + k0 + ((slot ^ (row & 7)) * 8);
      gload_lds16(ga, As + (size_t)(it * 256 + wave * 64) * 8);
    }
#pragma unroll
    for (int it = 0; it < NB_IT; ++it) {
      int idx = it * 256 + tid;
      int row = idx >> 3, slot = idx & 7;
      const bf16_t* gb = Bbase + (size_t)row * K + k0 + ((slot ^ (row & 7)) * 8);
      gload_lds16(gb, Bs + (size_t)(it * 256 + wave * 64) * 8);
    }
    __syncthreads();
#pragma unroll
    for (int ks2 = 0; ks2 < 2; ++ks2) {
      int j = ks2 * 4 + kg;
      bf16x8 af[4], bfv[NFRG];
#pragma unroll
      for (int i = 0; i < 4; ++i) {
        int ra = wm * 64 + i * 16 + lr;
        af[i] = *(const bf16x8*)((const char*)As + ra * 128 + ((j ^ (ra & 7)) * 16));
      }
#pragma unroll
      for (int i = 0; i < NFRG; ++i) {
        int rb = wn * (BN / 2) + i * 16 + lr;
        bfv[i] = *(const bf16x8*)((const char*)Bs + rb * 128 + ((j ^ (rb & 7)) * 16));
      }
#pragma unroll
      for (int i = 0; i < 4; ++i)
#pragma unroll
        for (int jj = 0; jj < NFRG; ++jj)
          acc[i][jj] = __builtin_amdgcn_mfma_f32_16x16x32_bf16(af[i], bfv[jj], acc[i][jj], 0, 0, 0);
    }
    __syncthreads();
  }

#pragma unroll
  for (int i = 0; i < 4; ++i) {
    int r0 = by * 128 + wm * 64 + i * 16 + ((lane >> 4) << 2);
#pragma unroll
    for (int j = 0; j < NFRG; ++j) {
      int c = bx * BN + wn * (BN / 2) + j * 16 + (lane & 15);
      OT* Cp = C + (size_t)r0 * N + c;
#pragma unroll
      for (int q = 0; q < 4; ++q) Cp[(size_t)q * N] = (OT)acc[i][j][q];
    }
  }
}

// ---------- beta / g + fused hidden->bf16 cast ----------
__global__ __launch_bounds__(64)
void k_ab(const float* __restrict__ hidden, const float* __restrict__ Wa,
          const float* __restrict__ Wb, const float* __restrict__ A_log,
          const float* __restrict__ dt_bias, float* __restrict__ g_out,
          float* __restrict__ beta_out, bf16_t* __restrict__ hbf) {
  int row = blockIdx.x;
  int lane = threadIdx.x;
  float accA[6] = {0, 0, 0, 0, 0, 0};
  float accB[6] = {0, 0, 0, 0, 0, 0};
  const float* h = hidden + (size_t)row * CC;
  bf16_t* hb = hbf + (size_t)row * CC;
  for (int c = lane; c < CC; c += 64) {
    float x = h[c];
    hb[c] = (bf16_t)x;
    const float* wa = Wa + c * 6;
    const float* wb = Wb + c * 6;
#pragma unroll
    for (int j = 0; j < 6; ++j) {
      accA[j] += x * wa[j];
      accB[j] += x * wb[j];
    }
  }
#pragma unroll
  for (int j = 0; j < 6; ++j) {
    for (int off = 32; off; off >>= 1) {
      accA[j] += __shfl_down(accA[j], off);
      accB[j] += __shfl_down(accB[j], off);
    }
  }
  if (lane == 0) {
#pragma unroll
    for (int j = 0; j < 6; ++j) {
      float a = accA[j] + dt_bias[j];
      float sp = (a > 20.f) ? a : log1pf(expf(a));
      g_out[(size_t)row * 6 + j] = -expf(A_log[j]) * sp;
      beta_out[(size_t)row * 6 + j] = 1.f / (1.f + expf(-accB[j]));
    }
  }
}

// ---------- merged q+k conv: 256 thr, lower half q / upper half k; per-half L2 norm ----------
__global__ __launch_bounds__(256)
void k_conv_qk(const bf16_t* __restrict__ pre, const float* __restrict__ qconv,
               const float* __restrict__ kconv, bf16_t* __restrict__ qb16,
               bf16_t* __restrict__ kb16) {
  int row = blockIdx.x;     // b*T + t
  int t = row & (TT - 1);
  int h = blockIdx.y;
  int tid = threadIdx.x;
  int half = tid >> 7;      // 0 = q, 1 = k
  int kk = tid & 127;
  int col0 = half ? 768 : 0;
  const float* wp = (half ? kconv : qconv) + (h * 128 + kk) * 4;
  int ch = h * 128 + kk;
  float y = 0.f;
#pragma unroll
  for (int i = 0; i < 4; ++i) {
    int tt = t - 3 + i;
    if (tt >= 0) y += wp[i] * (float)pre[(size_t)(row - 3 + i) * NCAT + col0 + ch];
  }
  float s = y / (1.f + expf(-y));
  // per-half L2 norm (waves 0,1 = q; waves 2,3 = k)
  float ss = s * s;
#pragma unroll
  for (int off = 32; off; off >>= 1) ss += __shfl_down(ss, off);
  __shared__ float red[4];
  if ((tid & 63) == 0) red[tid >> 6] = ss;
  __syncthreads();
  float nrm = half ? sqrtf(red[2] + red[3]) : sqrtf(red[0] + red[1]);
  s = s / (nrm + 1e-6f);
  bf16_t* dst = half ? kb16 : qb16;
  dst[(size_t)row * KD + ch] = (bf16_t)s;
}

// ---------- v conv (no norm): f32 out ----------
__global__ __launch_bounds__(256)
void k_conv_v(const bf16_t* __restrict__ pre, const float* __restrict__ w,
              float* __restrict__ out) {
  int row = blockIdx.x;
  int t = row & (TT - 1);
  int h = blockIdx.y;
  int kk = threadIdx.x;
  int ch = h * 256 + kk;
  const float* wp = w + ch * 4;
  float y = 0.f;
#pragma unroll
  for (int i = 0; i < 4; ++i) {
    int tt = t - 3 + i;
    if (tt >= 0) y += wp[i] * (float)pre[(size_t)(row - 3 + i) * NCAT + 1536 + ch];
  }
  out[(size_t)row * VD + ch] = y / (1.f + expf(-y));
}

// ============ chunked gated delta rule ============
// Pass 1 (UT transform, 8-wave; M-MFMA split across all 8 waves).
__global__ __launch_bounds__(512, 2)
void k_chunk1(const bf16_t* __restrict__ kb16, float* dv,
              const float* __restrict__ gdec, const float* __restrict__ beta,
              bf16_t* __restrict__ Wn16, bf16_t* __restrict__ khatT16,
              float* __restrict__ bcum) {
  __shared__ __align__(16) bf16_t ksh[64 * 128];    // 16KB [t][k] swizzled
  __shared__ __align__(16) bf16_t Mb[64 * 64];      // 8KB  [t][s] = -M, swizzled
  __shared__ __align__(16) bf16_t Tdl[4 * 16 * 32]; // 4KB  diag-block inverses
  __shared__ __align__(16) bf16_t Yb[384 * 32];     // 24KB [n][k] Ytmp (B-frag layout)
  __shared__ __align__(16) bf16_t Xall[384 * 64];   // 48KB [n][s] solved X (B-frag layout)
  __shared__ float bc[64], bet[64];

  int tid = threadIdx.x;
  int bh = blockIdx.y, c = blockIdx.x;
  int b = bh / HH, h = bh % HH;
  int r0 = b * TT + c * CL;
  size_t cb = (size_t)bh * NC + c;
  int wq = tid >> 6, l = tid & 63;
  int lr = l & 15, lg = l >> 4;

  // ---- phase A ----
#pragma unroll
  for (int it = 0; it < 2; ++it) {
    int idx = it * 512 + tid;
    int t = idx >> 4, p = idx & 15;
    int kslot = p ^ (t & 7);
    gload_lds16(kb16 + (size_t)(r0 + t) * KD + h * KK + kslot * 8,
                ksh + (size_t)idx * 8);
  }
  if (tid < 64) {
    float val = gdec[(size_t)(r0 + tid) * HH + h];
    bet[tid] = beta[(size_t)(r0 + tid) * HH + h];
#pragma unroll
    for (int off = 1; off < 64; off <<= 1) {
      float o = __shfl_up(val, off, 64);
      if (tid >= off) val += o;
    }
    bc[tid] = val;
    bcum[cb * CL + tid] = val;
  }
  __syncthreads();
  float bL = bc[63];

  // ---- phase B: -M via MFMA (ALL 8 waves: tq = wq&3, sf half = wq>>2) ----
  {
    f32x4 z4 = (f32x4){0.f, 0.f, 0.f, 0.f};
#pragma unroll
    for (int i = 0; i < 6; ++i) ((f32x4*)Xall)[i * 512 + tid] = z4;
#pragma unroll
    for (int i = 0; i < 3; ++i) ((f32x4*)Yb)[i * 512 + tid] = z4;
    if (tid < 256) ((f32x4*)Tdl)[tid] = z4;
  }
  {
    int tq = wq & 3, sh = wq >> 2;
    f32x4 pacc[2];
#pragma unroll
    for (int sfi = 0; sfi < 2; ++sfi) pacc[sfi] = (f32x4){0.f, 0.f, 0.f, 0.f};
#pragma unroll
    for (int ks_ = 0; ks_ < 4; ++ks_) {
      int trow = tq * 16 + lr;
      bf16x8 aK = *(const bf16x8*)((const char*)ksh + trow * 256 + (((ks_ * 4 + lg) * 16) ^ ((trow & 7) << 4)));
#pragma unroll
      for (int sfi = 0; sfi < 2; ++sfi) {
        int srow = (sh * 2 + sfi) * 16 + lr;
        bf16x8 bK = *(const bf16x8*)((const char*)ksh + srow * 256 + (((ks_ * 4 + lg) * 16) ^ ((srow & 7) << 4)));
        pacc[sfi] = __builtin_amdgcn_mfma_f32_16x16x32_bf16(aK, bK, pacc[sfi], 0, 0, 0);
      }
    }
#pragma unroll
    for (int sfi = 0; sfi < 2; ++sfi)
#pragma unroll
      for (int q = 0; q < 4; ++q) {
        int t = tq * 16 + lg * 4 + q;
        int s = (sh * 2 + sfi) * 16 + lr;
        float val = (s < t) ? -bet[t] * __expf(bc[t] - bc[s]) * pacc[sfi][q] : 0.f;
        *(bf16_t*)((char*)Mb + t * 128 + ((s * 2) ^ ((t & 7) << 4))) = (bf16_t)val;
      }
  }
  __syncthreads();

  // ---- phase C: diag-block inverses (0..63) || khatT16 (64..191) ----
  if (tid < 64) {
    int d = tid >> 4, cc = tid & 15;
    float x[16];
#pragma unroll
    for (int s = 0; s < 16; ++s) x[s] = (s == cc) ? 1.f : 0.f;
#pragma unroll
    for (int r = 1; r < 16; ++r) {
      float a = 0.f;
#pragma unroll
      for (int s = 0; s < r; ++s) {
        float m = (float)*(const bf16_t*)((const char*)Mb + (16 * d + r) * 128 +
                    (((16 * d + s) * 2) ^ ((r & 7) << 4)));
        a += m * x[s];
      }
      x[r] += a;
    }
#pragma unroll
    for (int r = 0; r < 16; ++r)
      *(bf16_t*)((char*)Tdl + d * 1024 + r * 64 +
          ((((cc >> 3) * 16) ^ ((r & 3) << 4)) + (cc & 7) * 2)) = (bf16_t)x[r];
  } else if (tid < 192) {
    int kk = tid - 64;
    bf16_t* kout = khatT16 + cb * (size_t)(KK * CL) + (size_t)kk * CL;
#pragma unroll
    for (int t8 = 0; t8 < 8; ++t8) {
      union { bf16x8 v; bf16_t e[8]; } u;
#pragma unroll
      for (int e = 0; e < 8; ++e) {
        int t = t8 * 8 + e;
        u.e[e] = (bf16_t)(__expf(bL - bc[t]) * ksh_get(ksh, t, kk));
      }
      *(bf16x8*)(kout + t8 * 8) = u.v;
    }
  }
  __syncthreads();

  // ---- phase D: 4-stage block solve, 3 n-tiles per wave ----
  const int nbase = wq * 48;
#pragma unroll
  for (int st = 0; st < 4; ++st) {
#pragma unroll
    for (int nt = 0; nt < 3; ++nt) {
      const int n0 = nbase + nt * 16;
      const bool isv = (n0 < 256);
      const int n = n0 + lr;
      f32x4 acc = (f32x4){0.f, 0.f, 0.f, 0.f};
      if (isv) {
#pragma unroll
        for (int q = 0; q < 4; ++q) {
          int t = st * 16 + lg * 4 + q;
          acc[q] = bet[t] * dv[(size_t)(r0 + t) * VD + h * VV + n];
        }
      } else {
        int kk = n - 256;
#pragma unroll
        for (int q = 0; q < 4; ++q) {
          int t = st * 16 + lg * 4 + q;
          acc[q] = bet[t] * __expf(bc[t]) * ksh_get(ksh, t, kk);
        }
      }
#pragma unroll
      for (int p = 0; p < 2; ++p) {
        if ((p == 0 && st >= 1) || (p == 1 && st == 3)) {
          int arow = st * 16 + lr;
          bf16x8 aM = *(const bf16x8*)((const char*)Mb + arow * 128 +
                         (((p * 4 + lg) * 16) ^ ((arow & 7) << 4)));
          bf16x8 bX = *(const bf16x8*)((const char*)Xall + n * 128 +
                         (((p * 4 + lg) * 16) ^ ((n & 7) << 4)));
          acc = __builtin_amdgcn_mfma_f32_16x16x32_bf16(aM, bX, acc, 0, 0, 0);
        }
      }
#pragma unroll
      for (int q = 0; q < 4; ++q) {
        int tq = lg * 4 + q;
        *(bf16_t*)((char*)Yb + n * 64 +
            ((((tq >> 3) * 16) ^ ((n & 3) << 4)) + (tq & 7) * 2)) = (bf16_t)acc[q];
      }
      f32x4 acc2 = (f32x4){0.f, 0.f, 0.f, 0.f};
      {
        bf16x8 aT = *(const bf16x8*)((const char*)Tdl + st * 1024 + lr * 64 +
                       ((lg * 16) ^ ((lr & 3) << 4)));
        bf16x8 bY = *(const bf16x8*)((const char*)Yb + n * 64 +
                       ((lg * 16) ^ ((n & 3) << 4)));
        acc2 = __builtin_amdgcn_mfma_f32_16x16x32_bf16(aT, bY, acc2, 0, 0, 0);
      }
      if (st < 3) {
#pragma unroll
        for (int q = 0; q < 4; ++q) {
          int s = st * 16 + lg * 4 + q;
          *(bf16_t*)((char*)Xall + n * 128 +
              ((((s >> 3) * 16) ^ ((n & 7) << 4)) + (s & 7) * 2)) = (bf16_t)acc2[q];
        }
      }
      if (isv) {
#pragma unroll
        for (int q = 0; q < 4; ++q) {
          int t = st * 16 + lg * 4 + q;
          dv[(size_t)(r0 + t) * VD + h * VV + n] = acc2[q];
        }
      } else {
        int kk = n - 256;
#pragma unroll
        for (int q = 0; q < 4; ++q) {
          int t = st * 16 + lg * 4 + q;
          Wn16[(cb * CL + t) * KK + kk] = (bf16_t)(-acc2[q]);
        }
      }
    }
  }
}

// Pass 2: MFMA state propagation. Grid (16 vtiles of 16, 12 bh), 256 thr.
__global__ __launch_bounds__(256, 1)
void k_chunk2(const float* __restrict__ dv, const bf16_t* __restrict__ Wn16,
              const bf16_t* __restrict__ khatT16, const float* __restrict__ bcum,
              bf16_t* __restrict__ states, bf16_t* __restrict__ Zt) {
  __shared__ __align__(16) bf16_t St[16 * 128];   // [v][k], XOR-swizzled
  __shared__ __align__(16) bf16_t Zl[16 * 64];    // [v][t], XOR-swizzled
  int tid = threadIdx.x;
  int vt = blockIdx.x, bh = blockIdx.y;
  int b = bh / HH, h = bh % HH;
  int wq = tid >> 6, l = tid & 63;
  int lr = l & 15, lg = l >> 4;

  f32x4 acc[2];
#pragma unroll
  for (int kf = 0; kf < 2; ++kf) acc[kf] = (f32x4){0.f, 0.f, 0.f, 0.f};

  for (int c = 0; c < NC; ++c) {
    size_t cb = (size_t)bh * NC + c;
    int r0 = b * TT + c * CL;
    float ebL = __expf(bcum[cb * CL + 63]);

#pragma unroll
    for (int kf = 0; kf < 2; ++kf)
#pragma unroll
      for (int q = 0; q < 4; ++q) {
        int k = wq * 32 + kf * 16 + lg * 4 + q;
        int v = lr;
        *(bf16_t*)((char*)St + v * 256 + ((k * 2) ^ ((v & 7) << 4))) = (bf16_t)acc[kf][q];
      }
    __syncthreads();

    {
      int v = tid >> 4, slot = tid & 15;
      bf16x8 val = *(const bf16x8*)((const char*)St + v * 256 + ((slot * 16) ^ ((v & 7) << 4)));
      *(bf16x8*)(states + ((size_t)cb * 256 + vt * 16 + v) * 128 + slot * 8) = val;
    }

    f32x4 zacc = (f32x4){0.f, 0.f, 0.f, 0.f};
#pragma unroll
    for (int q = 0; q < 4; ++q) {
      int t = wq * 16 + lg * 4 + q;
      zacc[q] = dv[(size_t)(r0 + t) * VD + h * VV + vt * 16 + lr];
    }
#pragma unroll
    for (int ks_ = 0; ks_ < 4; ++ks_) {
      bf16x8 aW = *(const bf16x8*)(Wn16 + (cb * CL + wq * 16 + lr) * KK + ks_ * 32 + lg * 8);
      int v = lr;
      bf16x8 bS = *(const bf16x8*)((const char*)St + v * 256 + (((ks_ * 32 + lg * 8) * 2) ^ ((v & 7) << 4)));
      zacc = __builtin_amdgcn_mfma_f32_16x16x32_bf16(aW, bS, zacc, 0, 0, 0);
    }
#pragma unroll
    for (int q = 0; q < 4; ++q) {
      int t = wq * 16 + lg * 4 + q;
      int v = lr;
      *(bf16_t*)((char*)Zl + v * 128 + ((t * 2) ^ ((v & 7) << 4))) = (bf16_t)zacc[q];
    }
    __syncthreads();

    if (tid < 128) {
      int v = tid >> 3, slot = tid & 7;
      bf16x8 val = *(const bf16x8*)((const char*)Zl + v * 128 + ((slot * 16) ^ ((v & 7) << 4)));
      *(bf16x8*)(Zt + ((size_t)cb * 256 + vt * 16 + v) * 64 + slot * 8) = val;
    }
#pragma unroll
    for (int kf = 0; kf < 2; ++kf)
#pragma unroll
      for (int q = 0; q < 4; ++q) acc[kf][q] *= ebL;
#pragma unroll
    for (int ts = 0; ts < 2; ++ts) {
      bf16x8 aK[2];
#pragma unroll
      for (int kf = 0; kf < 2; ++kf)
        aK[kf] = *(const bf16x8*)(khatT16 + (cb * KK + wq * 32 + kf * 16 + lr) * CL + ts * 32 + lg * 8);
      int v = lr;
      bf16x8 bZ = *(const bf16x8*)((const char*)Zl + v * 128 + (((ts * 32 + lg * 8) * 2) ^ ((v & 7) << 4)));
#pragma unroll
      for (int kf = 0; kf < 2; ++kf)
        acc[kf] = __builtin_amdgcn_mfma_f32_16x16x32_bf16(aK[kf], bZ, acc[kf], 0, 0, 0);
    }
  }
}

// Pass 3 (8-wave; P split across all 8 waves): o = e^{b_t} q^T S0 + P Z + gated RMSNorm.
__global__ __launch_bounds__(512, 2)
void k_chunk3(const bf16_t* __restrict__ qb16, const bf16_t* __restrict__ kb16,
              const bf16_t* __restrict__ Zt, const bf16_t* __restrict__ states,
              const float* __restrict__ bcum, const bf16_t* __restrict__ fgate,
              const float* __restrict__ onorm_w, bf16_t* __restrict__ ovd) {
  __shared__ __align__(16) bf16_t qs[64 * 128];   // [t][k] swizzled via pre-XOR source
  __shared__ __align__(16) bf16_t ksh[64 * 128];
  __shared__ __align__(16) bf16_t Pl[64 * 64];    // [t][s] swizzled
  __shared__ float bcs[64];
  __shared__ float sred[8][64];

  int tid = threadIdx.x;
  int c = blockIdx.x, bh = blockIdx.y;
  int b = bh / HH, h = bh % HH;
  int r0 = b * TT + c * CL;
  size_t cb = (size_t)bh * NC + c;
  int wq = tid >> 6, l = tid & 63;
  int lr = l & 15, lg = l >> 4;

  // hoisted global B-frag loads: latency hides under staging + P phase
  bf16x8 bSv[4][2], bZv[2][2];
#pragma unroll
  for (int vj = 0; vj < 2; ++vj) {
    int vrow = wq * 32 + vj * 16 + lr;
#pragma unroll
    for (int ks_ = 0; ks_ < 4; ++ks_)
      bSv[ks_][vj] = *(const bf16x8*)(states + ((size_t)cb * 256 + vrow) * 128 + ks_ * 32 + lg * 8);
#pragma unroll
    for (int ts = 0; ts < 2; ++ts)
      bZv[ts][vj] = *(const bf16x8*)(Zt + ((size_t)cb * 256 + vrow) * 64 + ts * 32 + lg * 8);
  }

  if (tid < 64) bcs[tid] = bcum[cb * CL + tid];
#pragma unroll
  for (int it = 0; it < 2; ++it) {
    int idx = it * 512 + tid;
    int t = idx >> 4, p = idx & 15;
    int kslot = p ^ (t & 7);
    gload_lds16(qb16 + (size_t)(r0 + t) * KD + h * KK + kslot * 8,
                qs + (size_t)idx * 8);
    gload_lds16(kb16 + (size_t)(r0 + t) * KD + h * KK + kslot * 8,
                ksh + (size_t)idx * 8);
  }
  __syncthreads();

  // P = mask(q k^T) e^{b_t-b_s}: ALL 8 waves (tq = wq&3, sf half = wq>>2)
  {
    int tq = wq & 3, sh = wq >> 2;
    f32x4 pacc[2];
#pragma unroll
    for (int sfi = 0; sfi < 2; ++sfi) pacc[sfi] = (f32x4){0.f, 0.f, 0.f, 0.f};
#pragma unroll
    for (int ks_ = 0; ks_ < 4; ++ks_) {
      int trow = tq * 16 + lr;
      bf16x8 aQ = *(const bf16x8*)((const char*)qs + trow * 256 + (((ks_ * 4 + lg) * 16) ^ ((trow & 7) << 4)));
#pragma unroll
      for (int sfi = 0; sfi < 2; ++sfi) {
        int srow = (sh * 2 + sfi) * 16 + lr;
        bf16x8 bK = *(const bf16x8*)((const char*)ksh + srow * 256 + (((ks_ * 4 + lg) * 16) ^ ((srow & 7) << 4)));
        pacc[sfi] = __builtin_amdgcn_mfma_f32_16x16x32_bf16(aQ, bK, pacc[sfi], 0, 0, 0);
      }
    }
#pragma unroll
    for (int sfi = 0; sfi < 2; ++sfi)
#pragma unroll
      for (int q = 0; q < 4; ++q) {
        int t = tq * 16 + lg * 4 + q;
        int s = (sh * 2 + sfi) * 16 + lr;
        float val = (s <= t) ? pacc[sfi][q] * __expf(bcs[t] - bcs[s]) : 0.f;
        *(bf16_t*)((char*)Pl + t * 128 + ((s * 2) ^ ((t & 7) << 4))) = (bf16_t)val;
      }
  }
  __syncthreads();

  // O: wave wq covers v cols wq*32..+31
  f32x4 oacc[4][2];
#pragma unroll
  for (int ti = 0; ti < 4; ++ti)
#pragma unroll
    for (int vj = 0; vj < 2; ++vj) oacc[ti][vj] = (f32x4){0.f, 0.f, 0.f, 0.f};

#pragma unroll
  for (int ks_ = 0; ks_ < 4; ++ks_) {
    bf16x8 aQ[4];
#pragma unroll
    for (int ti = 0; ti < 4; ++ti) {
      int t = ti * 16 + lr;
      union { bf16x8 v; bf16_t e[8]; } u;
      u.v = *(const bf16x8*)((const char*)qs + t * 256 + (((ks_ * 4 + lg) * 16) ^ ((t & 7) << 4)));
      float eb = __expf(bcs[t]);
#pragma unroll
      for (int e = 0; e < 8; ++e) u.e[e] = (bf16_t)((float)u.e[e] * eb);
      aQ[ti] = u.v;
    }
#pragma unroll
    for (int vj = 0; vj < 2; ++vj)
#pragma unroll
      for (int ti = 0; ti < 4; ++ti)
        oacc[ti][vj] = __builtin_amdgcn_mfma_f32_16x16x32_bf16(aQ[ti], bSv[ks_][vj], oacc[ti][vj], 0, 0, 0);
  }
#pragma unroll
  for (int ts = 0; ts < 2; ++ts) {
    bf16x8 aP[4];
#pragma unroll
    for (int ti = 0; ti < 4; ++ti) {
      int t = ti * 16 + lr;
      aP[ti] = *(const bf16x8*)((const char*)Pl + t * 128 + (((ts * 4 + lg) * 16) ^ ((t & 7) << 4)));
    }
#pragma unroll
    for (int vj = 0; vj < 2; ++vj)
#pragma unroll
      for (int ti = 0; ti < 4; ++ti)
        oacc[ti][vj] = __builtin_amdgcn_mfma_f32_16x16x32_bf16(aP[ti], bZv[ts][vj], oacc[ti][vj], 0, 0, 0);
  }

  // ---- fused gated RMSNorm (8-wave reduce) ----
  float sum2[4][4];
#pragma unroll
  for (int ti = 0; ti < 4; ++ti)
#pragma unroll
    for (int q = 0; q < 4; ++q) {
      float s = 0.f;
#pragma unroll
      for (int vj = 0; vj < 2; ++vj) s += oacc[ti][vj][q] * oacc[ti][vj][q];
      sum2[ti][q] = s;
    }
#pragma unroll
  for (int mk = 1; mk < 16; mk <<= 1)
#pragma unroll
    for (int ti = 0; ti < 4; ++ti)
#pragma unroll
      for (int q = 0; q < 4; ++q)
        sum2[ti][q] += __shfl_xor(sum2[ti][q], mk, 64);
  if (lr == 0) {
#pragma unroll
    for (int ti = 0; ti < 4; ++ti)
#pragma unroll
      for (int q = 0; q < 4; ++q)
        sred[wq][ti * 16 + lg * 4 + q] = sum2[ti][q];
  }
  __syncthreads();

  float onv[2];
#pragma unroll
  for (int vj = 0; vj < 2; ++vj) onv[vj] = onorm_w[wq * 32 + vj * 16 + lr];
#pragma unroll
  for (int ti = 0; ti < 4; ++ti)
#pragma unroll
    for (int q = 0; q < 4; ++q) {
      int t = ti * 16 + lg * 4 + q;
      float tot = 0.f;
#pragma unroll
      for (int w = 0; w < 8; ++w) tot += sred[w][t];
      float rn = rsqrtf(tot * (1.f / VV) + 1e-5f);
#pragma unroll
      for (int vj = 0; vj < 2; ++vj) {
        int v = wq * 32 + vj * 16 + lr;
        float gate = (float)fgate[(size_t)(r0 + t) * NCAT + h * VV + v];
        float y = oacc[ti][vj][q] * rn * onv[vj] * (gate / (1.f + expf(-gate)));
        ovd[(size_t)(r0 + t) * VD + h * VV + v] = (bf16_t)y;
      }
    }
}

extern "C" void kernel_launch(void* const* d_in, const int* in_sizes, int n_in,
                              void* d_out, int out_size, void* d_ws, size_t ws_size,
                              hipStream_t stream) {
  const float* hidden = (const float*)d_in[0];
  const float* Wq = (const float*)d_in[1];
  const float* Wk = (const float*)d_in[2];
  const float* Wv = (const float*)d_in[3];
  const float* Wa = (const float*)d_in[4];
  const float* Wb = (const float*)d_in[5];
  const float* A_log = (const float*)d_in[6];
  const float* dt_bias = (const float*)d_in[7];
  const float* qconv = (const float*)d_in[8];
  const float* kconv = (const float*)d_in[9];
  const float* vconv = (const float*)d_in[10];
  const float* Wg = (const float*)d_in[11];
  const float* onorm = (const float*)d_in[12];
  const float* Wo = (const float*)d_in[13];
  float* out = (float*)d_out;

  char* ws = (char*)d_ws;
  size_t off = 0;
  auto alloc = [&](size_t bytes) {
    void* p = ws + off;
    off += (bytes + 255) & ~(size_t)255;
    return p;
  };
  const int M = BB * TT;  // 2048
  bf16_t* hbf   = (bf16_t*)alloc((size_t)M * CC * 2);       // aliased by Wn16/khatT16 later
  bf16_t* WcatT = (bf16_t*)alloc((size_t)NCAT * CC * 2);
  bf16_t* WoT   = (bf16_t*)alloc((size_t)CC * VD * 2);
  bf16_t* fall  = (bf16_t*)alloc((size_t)M * NCAT * 2);     // fused q|k|v|gate projection (bf16)
  bf16_t* states = (bf16_t*)alloc((size_t)12 * NC * VV * KK * 2);  // 12.6MB
  float*  kn    = (float*) alloc((size_t)M * KD * 4);       // aliased by Zt later
  float*  vn    = (float*) alloc((size_t)M * VD * 4);       // becomes Dv in pass 1
  float*  gdec  = (float*) alloc((size_t)M * HH * 4);
  float*  beta  = (float*) alloc((size_t)M * HH * 4);
  bf16_t* ovd   = (bf16_t*)alloc((size_t)M * VD * 2);
  bf16_t* qb16  = (bf16_t*)alloc((size_t)M * KD * 2);
  bf16_t* kb16  = (bf16_t*)alloc((size_t)M * KD * 2);
  float*  bcum  = (float*) alloc((size_t)12 * NC * CL * 4);

  // aliases (stream-ordered lifetime separation):
  bf16_t* Wn16    = (bf16_t*)hbf;                     // 12*16*64*128 bf16 = 3.15MB
  bf16_t* khatT16 = Wn16 + (size_t)12 * NC * CL * KK; // +3.15MB (hbf is 8.4MB)
  bf16_t* Zt      = (bf16_t*)kn;                      // 12*16*256*64 bf16 = 6.3MB

  // beta / g + hidden->bf16 cast (fused; must precede the projection GEMM)
  k_ab<<<M, 64, 0, stream>>>(hidden, Wa, Wb, A_log, dt_bias, gdec, beta, hbf);

  // pre-pass weight transposes
  k_transpose_cvt<<<dim3(KD / 32, CC / 32), dim3(32, 8), 0, stream>>>(Wq, WcatT, CC, KD);
  k_transpose_cvt<<<dim3(KD / 32, CC / 32), dim3(32, 8), 0, stream>>>(Wk, WcatT + (size_t)768 * CC, CC, KD);
  k_transpose_cvt<<<dim3(VD / 32, CC / 32), dim3(32, 8), 0, stream>>>(Wv, WcatT + (size_t)1536 * CC, CC, VD);
  k_transpose_cvt<<<dim3(VD / 32, CC / 32), dim3(32, 8), 0, stream>>>(Wg, WcatT + (size_t)3072 * CC, CC, VD);
  k_transpose_cvt<<<dim3(CC / 32, VD / 32), dim3(32, 8), 0, stream>>>(Wo, WoT, VD, CC);

  // fused projection GEMM: [2048,2048] x [4608,2048]^T -> [2048,4608] bf16
  k_gemm_bt<96, bf16_t><<<dim3(NCAT / 96, M / 128), 256, 0, stream>>>(hbf, WcatT, fall, M, NCAT, CC);

  // conv + silu (q+k merged w/ L2 norm; v separate)
  k_conv_qk<<<dim3(M, HH), 256, 0, stream>>>(fall, qconv, kconv, qb16, kb16);
  k_conv_v<<<dim3(M, HH), 256, 0, stream>>>(fall, vconv, vn);

  // chunked gated delta rule (hbf dead -> Wn16/khatT16; kn dead -> Zt)
  k_chunk1<<<dim3(NC, 12), 512, 0, stream>>>(kb16, vn, gdec, beta, Wn16, khatT16, bcum);
  k_chunk2<<<dim3(16, 12), 256, 0, stream>>>(vn, Wn16, khatT16, bcum, states, Zt);
  k_chunk3<<<dim3(NC, 12), 512, 0, stream>>>(qb16, kb16, Zt, states, bcum, fall + 3072, onorm, ovd);

  // output projection (f32 out), BN=64 -> grid 32x16 = 512 = 2.0 blocks/CU
  k_gemm_bt<64, float><<<dim3(CC / 64, M / 128), 256, 0, stream>>>(ovd, WoT, out, M, CC, VD);
}

// Round 20
// 192.018 us; speedup vs baseline: 1.9732x; 1.0388x over previous
//
#include <hip/hip_runtime.h>
#include <hip/hip_bf16.h>
#include <math.h>

typedef __bf16 bf16_t;
typedef __attribute__((ext_vector_type(8))) __bf16 bf16x8;
typedef __attribute__((ext_vector_type(4))) float f32x4;

#define GAS __attribute__((address_space(1)))
#define LAS __attribute__((address_space(3)))

#define BB 2
#define TT 1024
#define CC 2048
#define HH 6
#define KK 128
#define VV 256
#define KD 768
#define VD 1536
#define NQKV 3072
#define NCAT 4608
#define NC 16     // chunks per sequence
#define CL 64     // chunk length

__device__ __forceinline__ void gload_lds16(const void* g, void* l) {
  __builtin_amdgcn_global_load_lds((const GAS void*)g, (LAS void*)l, 16, 0, 0);
}

// scalar read of swizzled [64][128] bf16 tile element (t, kk)
__device__ __forceinline__ float ksh_get(const bf16_t* ksh, int t, int kk) {
  return (float)*(const bf16_t*)((const char*)ksh + t * 256 +
           ((((kk >> 3) ^ (t & 7)) * 16) + (kk & 7) * 2));
}

// ---------- merged transpose: all 5 weights in one launch ----------
// jobs: 0 Wq->WcatT[0]      (Kd=CC, Nd=KD)  1536 blocks
//       1 Wk->WcatT[768*CC] (Kd=CC, Nd=KD)  1536
//       2 Wv->WcatT[1536*CC](Kd=CC, Nd=VD)  3072
//       3 Wg->WcatT[3072*CC](Kd=CC, Nd=VD)  3072
//       4 Wo->WoT           (Kd=VD, Nd=CC)  3072    total 12288
__global__ void k_transpose_all(const float* __restrict__ Wq, const float* __restrict__ Wk,
                                const float* __restrict__ Wv, const float* __restrict__ Wg,
                                const float* __restrict__ Wo, bf16_t* __restrict__ WcatT,
                                bf16_t* __restrict__ WoT) {
  __shared__ float t[32][33];
  int r = blockIdx.x;
  const float* src; bf16_t* dst; int Kd, Nd;
  if (r < 1536)      { src = Wq; dst = WcatT;                      Kd = CC; Nd = KD; }
  else if (r < 3072) { src = Wk; dst = WcatT + (size_t)768 * CC;   Kd = CC; Nd = KD; r -= 1536; }
  else if (r < 6144) { src = Wv; dst = WcatT + (size_t)1536 * CC;  Kd = CC; Nd = VD; r -= 3072; }
  else if (r < 9216) { src = Wg; dst = WcatT + (size_t)3072 * CC;  Kd = CC; Nd = VD; r -= 6144; }
  else               { src = Wo; dst = WoT;                        Kd = VD; Nd = CC; r -= 9216; }
  int nx = Nd >> 5;
  int n0 = (r % nx) * 32, k0 = (r / nx) * 32;
  int tx = threadIdx.x, ty = threadIdx.y;
#pragma unroll
  for (int i = 0; i < 32; i += 8)
    t[ty + i][tx] = src[(size_t)(k0 + ty + i) * Nd + n0 + tx];
  __syncthreads();
#pragma unroll
  for (int i = 0; i < 32; i += 8)
    dst[(size_t)(n0 + ty + i) * Kd + k0 + tx] = (bf16_t)t[tx][ty + i];
}

// ---------- bf16 MFMA GEMM: C[M,N] = A[M,K] * B^T (B is [N,K]) ----------
template <int BN, typename OT>
__global__ __launch_bounds__(256, 4)
void k_gemm_bt(const bf16_t* __restrict__ A, const bf16_t* __restrict__ B,
               OT* __restrict__ C, int M, int N, int K) {
  constexpr int NFRG = BN / 32;
  constexpr int NB_IT = BN / 32;
  __shared__ __align__(16) bf16_t As[128 * 64];
  __shared__ __align__(16) bf16_t Bs[BN * 64];
  int tid = threadIdx.x;
  int wave = tid >> 6, lane = tid & 63;
  int wm = wave >> 1, wn = wave & 1;

  // XCD-aware mapping: 2D region per XCD if divisible, else m204 chunk.
  int gx = gridDim.x, gy = gridDim.y;
  int nwg = gx * gy;
  int lin = blockIdx.y * gx + blockIdx.x;
  int bx, by;
  if ((gx % 4 == 0) && (gy % 2 == 0) && (nwg % 8 == 0)) {
    int xcd = lin & 7, c = lin >> 3;
    int RX = gx >> 2;
    by = (xcd >> 2) * (gy >> 1) + c / RX;
    bx = (xcd & 3) * RX + c % RX;
  } else {
    int q8 = nwg >> 3, r8 = nwg & 7;
    int xcd = lin & 7, off8 = lin >> 3;
    int wgid = (xcd < r8 ? xcd * (q8 + 1) : r8 * (q8 + 1) + (xcd - r8) * q8) + off8;
    bx = wgid % gx; by = wgid / gx;
  }

  const bf16_t* Abase = A + (size_t)by * 128 * K;
  const bf16_t* Bbase = B + (size_t)bx * BN * K;

  f32x4 acc[4][NFRG];
#pragma unroll
  for (int i = 0; i < 4; ++i)
#pragma unroll
    for (int j = 0; j < NFRG; ++j) acc[i][j] = (f32x4){0.f, 0.f, 0.f, 0.f};

  int kg = lane >> 4, lr = lane & 15;

  for (int k0 = 0; k0 < K; k0 += 64) {
#pragma unroll
    for (int it = 0; it < 4; ++it) {
      int idx = it * 256 + tid;
      int row = idx >> 3, slot = idx & 7;
      const bf16_t* ga = Abase + (size_t)row * K + k0 + ((slot ^ (row & 7)) * 8);
      gload_lds16(ga, As + (size_t)(it * 256 + wave * 64) * 8);
    }
#pragma unroll
    for (int it = 0; it < NB_IT; ++it) {
      int idx = it * 256 + tid;
      int row = idx >> 3, slot = idx & 7;
      const bf16_t* gb = Bbase + (size_t)row * K + k0 + ((slot ^ (row & 7)) * 8);
      gload_lds16(gb, Bs + (size_t)(it * 256 + wave * 64) * 8);
    }
    __syncthreads();
#pragma unroll
    for (int ks2 = 0; ks2 < 2; ++ks2) {
      int j = ks2 * 4 + kg;
      bf16x8 af[4], bfv[NFRG];
#pragma unroll
      for (int i = 0; i < 4; ++i) {
        int ra = wm * 64 + i * 16 + lr;
        af[i] = *(const bf16x8*)((const char*)As + ra * 128 + ((j ^ (ra & 7)) * 16));
      }
#pragma unroll
      for (int i = 0; i < NFRG; ++i) {
        int rb = wn * (BN / 2) + i * 16 + lr;
        bfv[i] = *(const bf16x8*)((const char*)Bs + rb * 128 + ((j ^ (rb & 7)) * 16));
      }
#pragma unroll
      for (int i = 0; i < 4; ++i)
#pragma unroll
        for (int jj = 0; jj < NFRG; ++jj)
          acc[i][jj] = __builtin_amdgcn_mfma_f32_16x16x32_bf16(af[i], bfv[jj], acc[i][jj], 0, 0, 0);
    }
    __syncthreads();
  }

#pragma unroll
  for (int i = 0; i < 4; ++i) {
    int r0 = by * 128 + wm * 64 + i * 16 + ((lane >> 4) << 2);
#pragma unroll
    for (int j = 0; j < NFRG; ++j) {
      int c = bx * BN + wn * (BN / 2) + j * 16 + (lane & 15);
      OT* Cp = C + (size_t)r0 * N + c;
#pragma unroll
      for (int q = 0; q < 4; ++q) Cp[(size_t)q * N] = (OT)acc[i][j][q];
    }
  }
}

// ---------- beta / g + fused hidden->bf16 cast ----------
__global__ __launch_bounds__(64)
void k_ab(const float* __restrict__ hidden, const float* __restrict__ Wa,
          const float* __restrict__ Wb, const float* __restrict__ A_log,
          const float* __restrict__ dt_bias, float* __restrict__ g_out,
          float* __restrict__ beta_out, bf16_t* __restrict__ hbf) {
  int row = blockIdx.x;
  int lane = threadIdx.x;
  float accA[6] = {0, 0, 0, 0, 0, 0};
  float accB[6] = {0, 0, 0, 0, 0, 0};
  const float* h = hidden + (size_t)row * CC;
  bf16_t* hb = hbf + (size_t)row * CC;
  for (int c = lane; c < CC; c += 64) {
    float x = h[c];
    hb[c] = (bf16_t)x;
    const float* wa = Wa + c * 6;
    const float* wb = Wb + c * 6;
#pragma unroll
    for (int j = 0; j < 6; ++j) {
      accA[j] += x * wa[j];
      accB[j] += x * wb[j];
    }
  }
#pragma unroll
  for (int j = 0; j < 6; ++j) {
    for (int off = 32; off; off >>= 1) {
      accA[j] += __shfl_down(accA[j], off);
      accB[j] += __shfl_down(accB[j], off);
    }
  }
  if (lane == 0) {
#pragma unroll
    for (int j = 0; j < 6; ++j) {
      float a = accA[j] + dt_bias[j];
      float sp = (a > 20.f) ? a : log1pf(expf(a));
      g_out[(size_t)row * 6 + j] = -expf(A_log[j]) * sp;
      beta_out[(size_t)row * 6 + j] = 1.f / (1.f + expf(-accB[j]));
    }
  }
}

// ---------- merged q+k+v conv: 512 thr (128 q | 128 k | 256 v) ----------
__global__ __launch_bounds__(512)
void k_conv_qkv(const bf16_t* __restrict__ pre, const float* __restrict__ qconv,
                const float* __restrict__ kconv, const float* __restrict__ vconv,
                bf16_t* __restrict__ qb16, bf16_t* __restrict__ kb16,
                float* __restrict__ vn) {
  int row = blockIdx.x;     // b*T + t
  int t = row & (TT - 1);
  int h = blockIdx.y;
  int tid = threadIdx.x;
  __shared__ float red[8];

  float s = 0.f;
  if (tid < 256) {
    int half = tid >> 7;        // 0 = q, 1 = k
    int kk = tid & 127;
    int col0 = half ? 768 : 0;
    int ch = h * 128 + kk;
    const float* wp = (half ? kconv : qconv) + ch * 4;
    float y = 0.f;
#pragma unroll
    for (int i = 0; i < 4; ++i) {
      int tt = t - 3 + i;
      if (tt >= 0) y += wp[i] * (float)pre[(size_t)(row - 3 + i) * NCAT + col0 + ch];
    }
    s = y / (1.f + expf(-y));
  } else {
    int kk = tid - 256;
    int ch = h * 256 + kk;
    const float* wp = vconv + ch * 4;
    float y = 0.f;
#pragma unroll
    for (int i = 0; i < 4; ++i) {
      int tt = t - 3 + i;
      if (tt >= 0) y += wp[i] * (float)pre[(size_t)(row - 3 + i) * NCAT + 1536 + ch];
    }
    float sv = y / (1.f + expf(-y));
    vn[(size_t)row * VD + ch] = sv;
  }
  // q/k L2 norm: waves 0,1 = q; waves 2,3 = k (v waves write unused slots)
  float ss = s * s;
#pragma unroll
  for (int off = 32; off; off >>= 1) ss += __shfl_down(ss, off);
  if ((tid & 63) == 0) red[tid >> 6] = ss;
  __syncthreads();
  if (tid < 256) {
    int half = tid >> 7;
    int kk = tid & 127;
    int ch = h * 128 + kk;
    float nrm = half ? sqrtf(red[2] + red[3]) : sqrtf(red[0] + red[1]);
    float sn = s / (nrm + 1e-6f);
    bf16_t* dst = half ? kb16 : qb16;
    dst[(size_t)row * KD + ch] = (bf16_t)sn;
  }
}

// ============ chunked gated delta rule ============
// Pass 1 (UT transform, 8-wave; M-MFMA split across all 8 waves).
__global__ __launch_bounds__(512, 2)
void k_chunk1(const bf16_t* __restrict__ kb16, float* dv,
              const float* __restrict__ gdec, const float* __restrict__ beta,
              bf16_t* __restrict__ Wn16, bf16_t* __restrict__ khatT16,
              float* __restrict__ bcum) {
  __shared__ __align__(16) bf16_t ksh[64 * 128];    // 16KB [t][k] swizzled
  __shared__ __align__(16) bf16_t Mb[64 * 64];      // 8KB  [t][s] = -M, swizzled
  __shared__ __align__(16) bf16_t Tdl[4 * 16 * 32]; // 4KB  diag-block inverses
  __shared__ __align__(16) bf16_t Yb[384 * 32];     // 24KB [n][k] Ytmp (B-frag layout)
  __shared__ __align__(16) bf16_t Xall[384 * 64];   // 48KB [n][s] solved X (B-frag layout)
  __shared__ float bc[64], bet[64];

  int tid = threadIdx.x;
  int bh = blockIdx.y, c = blockIdx.x;
  int b = bh / HH, h = bh % HH;
  int r0 = b * TT + c * CL;
  size_t cb = (size_t)bh * NC + c;
  int wq = tid >> 6, l = tid & 63;
  int lr = l & 15, lg = l >> 4;

  // ---- phase A ----
#pragma unroll
  for (int it = 0; it < 2; ++it) {
    int idx = it * 512 + tid;
    int t = idx >> 4, p = idx & 15;
    int kslot = p ^ (t & 7);
    gload_lds16(kb16 + (size_t)(r0 + t) * KD + h * KK + kslot * 8,
                ksh + (size_t)idx * 8);
  }
  if (tid < 64) {
    float val = gdec[(size_t)(r0 + tid) * HH + h];
    bet[tid] = beta[(size_t)(r0 + tid) * HH + h];
#pragma unroll
    for (int off = 1; off < 64; off <<= 1) {
      float o = __shfl_up(val, off, 64);
      if (tid >= off) val += o;
    }
    bc[tid] = val;
    bcum[cb * CL + tid] = val;
  }
  __syncthreads();
  float bL = bc[63];

  // ---- phase B: -M via MFMA (ALL 8 waves) ----
  {
    f32x4 z4 = (f32x4){0.f, 0.f, 0.f, 0.f};
#pragma unroll
    for (int i = 0; i < 6; ++i) ((f32x4*)Xall)[i * 512 + tid] = z4;
#pragma unroll
    for (int i = 0; i < 3; ++i) ((f32x4*)Yb)[i * 512 + tid] = z4;
    if (tid < 256) ((f32x4*)Tdl)[tid] = z4;
  }
  {
    int tq = wq & 3, sh = wq >> 2;
    f32x4 pacc[2];
#pragma unroll
    for (int sfi = 0; sfi < 2; ++sfi) pacc[sfi] = (f32x4){0.f, 0.f, 0.f, 0.f};
#pragma unroll
    for (int ks_ = 0; ks_ < 4; ++ks_) {
      int trow = tq * 16 + lr;
      bf16x8 aK = *(const bf16x8*)((const char*)ksh + trow * 256 + (((ks_ * 4 + lg) * 16) ^ ((trow & 7) << 4)));
#pragma unroll
      for (int sfi = 0; sfi < 2; ++sfi) {
        int srow = (sh * 2 + sfi) * 16 + lr;
        bf16x8 bK = *(const bf16x8*)((const char*)ksh + srow * 256 + (((ks_ * 4 + lg) * 16) ^ ((srow & 7) << 4)));
        pacc[sfi] = __builtin_amdgcn_mfma_f32_16x16x32_bf16(aK, bK, pacc[sfi], 0, 0, 0);
      }
    }
#pragma unroll
    for (int sfi = 0; sfi < 2; ++sfi)
#pragma unroll
      for (int q = 0; q < 4; ++q) {
        int t = tq * 16 + lg * 4 + q;
        int s = (sh * 2 + sfi) * 16 + lr;
        float val = (s < t) ? -bet[t] * __expf(bc[t] - bc[s]) * pacc[sfi][q] : 0.f;
        *(bf16_t*)((char*)Mb + t * 128 + ((s * 2) ^ ((t & 7) << 4))) = (bf16_t)val;
      }
  }
  __syncthreads();

  // ---- phase C: diag-block inverses (0..63) || khatT16 (64..191) ----
  if (tid < 64) {
    int d = tid >> 4, cc = tid & 15;
    float x[16];
#pragma unroll
    for (int s = 0; s < 16; ++s) x[s] = (s == cc) ? 1.f : 0.f;
#pragma unroll
    for (int r = 1; r < 16; ++r) {
      float a = 0.f;
#pragma unroll
      for (int s = 0; s < r; ++s) {
        float m = (float)*(const bf16_t*)((const char*)Mb + (16 * d + r) * 128 +
                    (((16 * d + s) * 2) ^ ((r & 7) << 4)));
        a += m * x[s];
      }
      x[r] += a;
    }
#pragma unroll
    for (int r = 0; r < 16; ++r)
      *(bf16_t*)((char*)Tdl + d * 1024 + r * 64 +
          ((((cc >> 3) * 16) ^ ((r & 3) << 4)) + (cc & 7) * 2)) = (bf16_t)x[r];
  } else if (tid < 192) {
    int kk = tid - 64;
    bf16_t* kout = khatT16 + cb * (size_t)(KK * CL) + (size_t)kk * CL;
#pragma unroll
    for (int t8 = 0; t8 < 8; ++t8) {
      union { bf16x8 v; bf16_t e[8]; } u;
#pragma unroll
      for (int e = 0; e < 8; ++e) {
        int t = t8 * 8 + e;
        u.e[e] = (bf16_t)(__expf(bL - bc[t]) * ksh_get(ksh, t, kk));
      }
      *(bf16x8*)(kout + t8 * 8) = u.v;
    }
  }
  __syncthreads();

  // ---- phase D: 4-stage block solve, 3 n-tiles per wave ----
  const int nbase = wq * 48;
#pragma unroll
  for (int st = 0; st < 4; ++st) {
#pragma unroll
    for (int nt = 0; nt < 3; ++nt) {
      const int n0 = nbase + nt * 16;
      const bool isv = (n0 < 256);
      const int n = n0 + lr;
      f32x4 acc = (f32x4){0.f, 0.f, 0.f, 0.f};
      if (isv) {
#pragma unroll
        for (int q = 0; q < 4; ++q) {
          int t = st * 16 + lg * 4 + q;
          acc[q] = bet[t] * dv[(size_t)(r0 + t) * VD + h * VV + n];
        }
      } else {
        int kk = n - 256;
#pragma unroll
        for (int q = 0; q < 4; ++q) {
          int t = st * 16 + lg * 4 + q;
          acc[q] = bet[t] * __expf(bc[t]) * ksh_get(ksh, t, kk);
        }
      }
#pragma unroll
      for (int p = 0; p < 2; ++p) {
        if ((p == 0 && st >= 1) || (p == 1 && st == 3)) {
          int arow = st * 16 + lr;
          bf16x8 aM = *(const bf16x8*)((const char*)Mb + arow * 128 +
                         (((p * 4 + lg) * 16) ^ ((arow & 7) << 4)));
          bf16x8 bX = *(const bf16x8*)((const char*)Xall + n * 128 +
                         (((p * 4 + lg) * 16) ^ ((n & 7) << 4)));
          acc = __builtin_amdgcn_mfma_f32_16x16x32_bf16(aM, bX, acc, 0, 0, 0);
        }
      }
#pragma unroll
      for (int q = 0; q < 4; ++q) {
        int tq = lg * 4 + q;
        *(bf16_t*)((char*)Yb + n * 64 +
            ((((tq >> 3) * 16) ^ ((n & 3) << 4)) + (tq & 7) * 2)) = (bf16_t)acc[q];
      }
      f32x4 acc2 = (f32x4){0.f, 0.f, 0.f, 0.f};
      {
        bf16x8 aT = *(const bf16x8*)((const char*)Tdl + st * 1024 + lr * 64 +
                       ((lg * 16) ^ ((lr & 3) << 4)));
        bf16x8 bY = *(const bf16x8*)((const char*)Yb + n * 64 +
                       ((lg * 16) ^ ((n & 3) << 4)));
        acc2 = __builtin_amdgcn_mfma_f32_16x16x32_bf16(aT, bY, acc2, 0, 0, 0);
      }
      if (st < 3) {
#pragma unroll
        for (int q = 0; q < 4; ++q) {
          int s = st * 16 + lg * 4 + q;
          *(bf16_t*)((char*)Xall + n * 128 +
              ((((s >> 3) * 16) ^ ((n & 7) << 4)) + (s & 7) * 2)) = (bf16_t)acc2[q];
        }
      }
      if (isv) {
#pragma unroll
        for (int q = 0; q < 4; ++q) {
          int t = st * 16 + lg * 4 + q;
          dv[(size_t)(r0 + t) * VD + h * VV + n] = acc2[q];
        }
      } else {
        int kk = n - 256;
#pragma unroll
        for (int q = 0; q < 4; ++q) {
          int t = st * 16 + lg * 4 + q;
          Wn16[(cb * CL + t) * KK + kk] = (bf16_t)(-acc2[q]);
        }
      }
    }
  }
}

// Pass 2: MFMA state propagation. Grid (16 vtiles of 16, 12 bh), 256 thr.
__global__ __launch_bounds__(256, 1)
void k_chunk2(const float* __restrict__ dv, const bf16_t* __restrict__ Wn16,
              const bf16_t* __restrict__ khatT16, const float* __restrict__ bcum,
              bf16_t* __restrict__ states, bf16_t* __restrict__ Zt) {
  __shared__ __align__(16) bf16_t St[16 * 128];   // [v][k], XOR-swizzled
  __shared__ __align__(16) bf16_t Zl[16 * 64];    // [v][t], XOR-swizzled
  int tid = threadIdx.x;
  int vt = blockIdx.x, bh = blockIdx.y;
  int b = bh / HH, h = bh % HH;
  int wq = tid >> 6, l = tid & 63;
  int lr = l & 15, lg = l >> 4;

  f32x4 acc[2];
#pragma unroll
  for (int kf = 0; kf < 2; ++kf) acc[kf] = (f32x4){0.f, 0.f, 0.f, 0.f};

  for (int c = 0; c < NC; ++c) {
    size_t cb = (size_t)bh * NC + c;
    int r0 = b * TT + c * CL;
    float ebL = __expf(bcum[cb * CL + 63]);

#pragma unroll
    for (int kf = 0; kf < 2; ++kf)
#pragma unroll
      for (int q = 0; q < 4; ++q) {
        int k = wq * 32 + kf * 16 + lg * 4 + q;
        int v = lr;
        *(bf16_t*)((char*)St + v * 256 + ((k * 2) ^ ((v & 7) << 4))) = (bf16_t)acc[kf][q];
      }
    __syncthreads();

    {
      int v = tid >> 4, slot = tid & 15;
      bf16x8 val = *(const bf16x8*)((const char*)St + v * 256 + ((slot * 16) ^ ((v & 7) << 4)));
      *(bf16x8*)(states + ((size_t)cb * 256 + vt * 16 + v) * 128 + slot * 8) = val;
    }

    f32x4 zacc = (f32x4){0.f, 0.f, 0.f, 0.f};
#pragma unroll
    for (int q = 0; q < 4; ++q) {
      int t = wq * 16 + lg * 4 + q;
      zacc[q] = dv[(size_t)(r0 + t) * VD + h * VV + vt * 16 + lr];
    }
#pragma unroll
    for (int ks_ = 0; ks_ < 4; ++ks_) {
      bf16x8 aW = *(const bf16x8*)(Wn16 + (cb * CL + wq * 16 + lr) * KK + ks_ * 32 + lg * 8);
      int v = lr;
      bf16x8 bS = *(const bf16x8*)((const char*)St + v * 256 + (((ks_ * 32 + lg * 8) * 2) ^ ((v & 7) << 4)));
      zacc = __builtin_amdgcn_mfma_f32_16x16x32_bf16(aW, bS, zacc, 0, 0, 0);
    }
#pragma unroll
    for (int q = 0; q < 4; ++q) {
      int t = wq * 16 + lg * 4 + q;
      int v = lr;
      *(bf16_t*)((char*)Zl + v * 128 + ((t * 2) ^ ((v & 7) << 4))) = (bf16_t)zacc[q];
    }
    __syncthreads();

    if (tid < 128) {
      int v = tid >> 3, slot = tid & 7;
      bf16x8 val = *(const bf16x8*)((const char*)Zl + v * 128 + ((slot * 16) ^ ((v & 7) << 4)));
      *(bf16x8*)(Zt + ((size_t)cb * 256 + vt * 16 + v) * 64 + slot * 8) = val;
    }
#pragma unroll
    for (int kf = 0; kf < 2; ++kf)
#pragma unroll
      for (int q = 0; q < 4; ++q) acc[kf][q] *= ebL;
#pragma unroll
    for (int ts = 0; ts < 2; ++ts) {
      bf16x8 aK[2];
#pragma unroll
      for (int kf = 0; kf < 2; ++kf)
        aK[kf] = *(const bf16x8*)(khatT16 + (cb * KK + wq * 32 + kf * 16 + lr) * CL + ts * 32 + lg * 8);
      int v = lr;
      bf16x8 bZ = *(const bf16x8*)((const char*)Zl + v * 128 + (((ts * 32 + lg * 8) * 2) ^ ((v & 7) << 4)));
#pragma unroll
      for (int kf = 0; kf < 2; ++kf)
        acc[kf] = __builtin_amdgcn_mfma_f32_16x16x32_bf16(aK[kf], bZ, acc[kf], 0, 0, 0);
    }
  }
}

// Pass 3 (8-wave; P split across all 8 waves): o = e^{b_t} q^T S0 + P Z + gated RMSNorm.
__global__ __launch_bounds__(512, 2)
void k_chunk3(const bf16_t* __restrict__ qb16, const bf16_t* __restrict__ kb16,
              const bf16_t* __restrict__ Zt, const bf16_t* __restrict__ states,
              const float* __restrict__ bcum, const bf16_t* __restrict__ fgate,
              const float* __restrict__ onorm_w, bf16_t* __restrict__ ovd) {
  __shared__ __align__(16) bf16_t qs[64 * 128];   // [t][k] swizzled via pre-XOR source
  __shared__ __align__(16) bf16_t ksh[64 * 128];
  __shared__ __align__(16) bf16_t Pl[64 * 64];    // [t][s] swizzled
  __shared__ float bcs[64];
  __shared__ float sred[8][64];

  int tid = threadIdx.x;
  int c = blockIdx.x, bh = blockIdx.y;
  int b = bh / HH, h = bh % HH;
  int r0 = b * TT + c * CL;
  size_t cb = (size_t)bh * NC + c;
  int wq = tid >> 6, l = tid & 63;
  int lr = l & 15, lg = l >> 4;

  // hoisted global B-frag loads: latency hides under staging + P phase
  bf16x8 bSv[4][2], bZv[2][2];
#pragma unroll
  for (int vj = 0; vj < 2; ++vj) {
    int vrow = wq * 32 + vj * 16 + lr;
#pragma unroll
    for (int ks_ = 0; ks_ < 4; ++ks_)
      bSv[ks_][vj] = *(const bf16x8*)(states + ((size_t)cb * 256 + vrow) * 128 + ks_ * 32 + lg * 8);
#pragma unroll
    for (int ts = 0; ts < 2; ++ts)
      bZv[ts][vj] = *(const bf16x8*)(Zt + ((size_t)cb * 256 + vrow) * 64 + ts * 32 + lg * 8);
  }

  if (tid < 64) bcs[tid] = bcum[cb * CL + tid];
#pragma unroll
  for (int it = 0; it < 2; ++it) {
    int idx = it * 512 + tid;
    int t = idx >> 4, p = idx & 15;
    int kslot = p ^ (t & 7);
    gload_lds16(qb16 + (size_t)(r0 + t) * KD + h * KK + kslot * 8,
                qs + (size_t)idx * 8);
    gload_lds16(kb16 + (size_t)(r0 + t) * KD + h * KK + kslot * 8,
                ksh + (size_t)idx * 8);
  }
  __syncthreads();

  // P = mask(q k^T) e^{b_t-b_s}: ALL 8 waves (tq = wq&3, sf half = wq>>2)
  {
    int tq = wq & 3, sh = wq >> 2;
    f32x4 pacc[2];
#pragma unroll
    for (int sfi = 0; sfi < 2; ++sfi) pacc[sfi] = (f32x4){0.f, 0.f, 0.f, 0.f};
#pragma unroll
    for (int ks_ = 0; ks_ < 4; ++ks_) {
      int trow = tq * 16 + lr;
      bf16x8 aQ = *(const bf16x8*)((const char*)qs + trow * 256 + (((ks_ * 4 + lg) * 16) ^ ((trow & 7) << 4)));
#pragma unroll
      for (int sfi = 0; sfi < 2; ++sfi) {
        int srow = (sh * 2 + sfi) * 16 + lr;
        bf16x8 bK = *(const bf16x8*)((const char*)ksh + srow * 256 + (((ks_ * 4 + lg) * 16) ^ ((srow & 7) << 4)));
        pacc[sfi] = __builtin_amdgcn_mfma_f32_16x16x32_bf16(aQ, bK, pacc[sfi], 0, 0, 0);
      }
    }
#pragma unroll
    for (int sfi = 0; sfi < 2; ++sfi)
#pragma unroll
      for (int q = 0; q < 4; ++q) {
        int t = tq * 16 + lg * 4 + q;
        int s = (sh * 2 + sfi) * 16 + lr;
        float val = (s <= t) ? pacc[sfi][q] * __expf(bcs[t] - bcs[s]) : 0.f;
        *(bf16_t*)((char*)Pl + t * 128 + ((s * 2) ^ ((t & 7) << 4))) = (bf16_t)val;
      }
  }
  __syncthreads();

  // O: wave wq covers v cols wq*32..+31
  f32x4 oacc[4][2];
#pragma unroll
  for (int ti = 0; ti < 4; ++ti)
#pragma unroll
    for (int vj = 0; vj < 2; ++vj) oacc[ti][vj] = (f32x4){0.f, 0.f, 0.f, 0.f};

#pragma unroll
  for (int ks_ = 0; ks_ < 4; ++ks_) {
    bf16x8 aQ[4];
#pragma unroll
    for (int ti = 0; ti < 4; ++ti) {
      int t = ti * 16 + lr;
      union { bf16x8 v; bf16_t e[8]; } u;
      u.v = *(const bf16x8*)((const char*)qs + t * 256 + (((ks_ * 4 + lg) * 16) ^ ((t & 7) << 4)));
      float eb = __expf(bcs[t]);
#pragma unroll
      for (int e = 0; e < 8; ++e) u.e[e] = (bf16_t)((float)u.e[e] * eb);
      aQ[ti] = u.v;
    }
#pragma unroll
    for (int vj = 0; vj < 2; ++vj)
#pragma unroll
      for (int ti = 0; ti < 4; ++ti)
        oacc[ti][vj] = __builtin_amdgcn_mfma_f32_16x16x32_bf16(aQ[ti], bSv[ks_][vj], oacc[ti][vj], 0, 0, 0);
  }
#pragma unroll
  for (int ts = 0; ts < 2; ++ts) {
    bf16x8 aP[4];
#pragma unroll
    for (int ti = 0; ti < 4; ++ti) {
      int t = ti * 16 + lr;
      aP[ti] = *(const bf16x8*)((const char*)Pl + t * 128 + (((ts * 4 + lg) * 16) ^ ((t & 7) << 4)));
    }
#pragma unroll
    for (int vj = 0; vj < 2; ++vj)
#pragma unroll
      for (int ti = 0; ti < 4; ++ti)
        oacc[ti][vj] = __builtin_amdgcn_mfma_f32_16x16x32_bf16(aP[ti], bZv[ts][vj], oacc[ti][vj], 0, 0, 0);
  }

  // ---- fused gated RMSNorm (8-wave reduce) ----
  float sum2[4][4];
#pragma unroll
  for (int ti = 0; ti < 4; ++ti)
#pragma unroll
    for (int q = 0; q < 4; ++q) {
      float s = 0.f;
#pragma unroll
      for (int vj = 0; vj < 2; ++vj) s += oacc[ti][vj][q] * oacc[ti][vj][q];
      sum2[ti][q] = s;
    }
#pragma unroll
  for (int mk = 1; mk < 16; mk <<= 1)
#pragma unroll
    for (int ti = 0; ti < 4; ++ti)
#pragma unroll
      for (int q = 0; q < 4; ++q)
        sum2[ti][q] += __shfl_xor(sum2[ti][q], mk, 64);
  if (lr == 0) {
#pragma unroll
    for (int ti = 0; ti < 4; ++ti)
#pragma unroll
      for (int q = 0; q < 4; ++q)
        sred[wq][ti * 16 + lg * 4 + q] = sum2[ti][q];
  }
  __syncthreads();

  float onv[2];
#pragma unroll
  for (int vj = 0; vj < 2; ++vj) onv[vj] = onorm_w[wq * 32 + vj * 16 + lr];
#pragma unroll
  for (int ti = 0; ti < 4; ++ti)
#pragma unroll
    for (int q = 0; q < 4; ++q) {
      int t = ti * 16 + lg * 4 + q;
      float tot = 0.f;
#pragma unroll
      for (int w = 0; w < 8; ++w) tot += sred[w][t];
      float rn = rsqrtf(tot * (1.f / VV) + 1e-5f);
#pragma unroll
      for (int vj = 0; vj < 2; ++vj) {
        int v = wq * 32 + vj * 16 + lr;
        float gate = (float)fgate[(size_t)(r0 + t) * NCAT + h * VV + v];
        float y = oacc[ti][vj][q] * rn * onv[vj] * (gate / (1.f + expf(-gate)));
        ovd[(size_t)(r0 + t) * VD + h * VV + v] = (bf16_t)y;
      }
    }
}

extern "C" void kernel_launch(void* const* d_in, const int* in_sizes, int n_in,
                              void* d_out, int out_size, void* d_ws, size_t ws_size,
                              hipStream_t stream) {
  const float* hidden = (const float*)d_in[0];
  const float* Wq = (const float*)d_in[1];
  const float* Wk = (const float*)d_in[2];
  const float* Wv = (const float*)d_in[3];
  const float* Wa = (const float*)d_in[4];
  const float* Wb = (const float*)d_in[5];
  const float* A_log = (const float*)d_in[6];
  const float* dt_bias = (const float*)d_in[7];
  const float* qconv = (const float*)d_in[8];
  const float* kconv = (const float*)d_in[9];
  const float* vconv = (const float*)d_in[10];
  const float* Wg = (const float*)d_in[11];
  const float* onorm = (const float*)d_in[12];
  const float* Wo = (const float*)d_in[13];
  float* out = (float*)d_out;

  char* ws = (char*)d_ws;
  size_t off = 0;
  auto alloc = [&](size_t bytes) {
    void* p = ws + off;
    off += (bytes + 255) & ~(size_t)255;
    return p;
  };
  const int M = BB * TT;  // 2048
  bf16_t* hbf   = (bf16_t*)alloc((size_t)M * CC * 2);       // aliased by Wn16/khatT16 later
  bf16_t* WcatT = (bf16_t*)alloc((size_t)NCAT * CC * 2);
  bf16_t* WoT   = (bf16_t*)alloc((size_t)CC * VD * 2);
  bf16_t* fall  = (bf16_t*)alloc((size_t)M * NCAT * 2);     // fused q|k|v|gate projection (bf16)
  bf16_t* states = (bf16_t*)alloc((size_t)12 * NC * VV * KK * 2);  // 12.6MB
  float*  kn    = (float*) alloc((size_t)M * KD * 4);       // aliased by Zt later
  float*  vn    = (float*) alloc((size_t)M * VD * 4);       // becomes Dv in pass 1
  float*  gdec  = (float*) alloc((size_t)M * HH * 4);
  float*  beta  = (float*) alloc((size_t)M * HH * 4);
  bf16_t* ovd   = (bf16_t*)alloc((size_t)M * VD * 2);
  bf16_t* qb16  = (bf16_t*)alloc((size_t)M * KD * 2);
  bf16_t* kb16  = (bf16_t*)alloc((size_t)M * KD * 2);
  float*  bcum  = (float*) alloc((size_t)12 * NC * CL * 4);

  // aliases (stream-ordered lifetime separation):
  bf16_t* Wn16    = (bf16_t*)hbf;                     // 12*16*64*128 bf16 = 3.15MB
  bf16_t* khatT16 = Wn16 + (size_t)12 * NC * CL * KK; // +3.15MB (hbf is 8.4MB)
  bf16_t* Zt      = (bf16_t*)kn;                      // 12*16*256*64 bf16 = 6.3MB

  // beta / g + hidden->bf16 cast (fused; must precede the projection GEMM)
  k_ab<<<M, 64, 0, stream>>>(hidden, Wa, Wb, A_log, dt_bias, gdec, beta, hbf);

  // all 5 weight transposes in one launch
  k_transpose_all<<<12288, dim3(32, 8), 0, stream>>>(Wq, Wk, Wv, Wg, Wo, WcatT, WoT);

  // fused projection GEMM: [2048,2048] x [4608,2048]^T -> [2048,4608] bf16
  k_gemm_bt<96, bf16_t><<<dim3(NCAT / 96, M / 128), 256, 0, stream>>>(hbf, WcatT, fall, M, NCAT, CC);

  // merged conv + silu (q,k with L2 norm; v plain)
  k_conv_qkv<<<dim3(M, HH), 512, 0, stream>>>(fall, qconv, kconv, vconv, qb16, kb16, vn);

  // chunked gated delta rule (hbf dead -> Wn16/khatT16; kn dead -> Zt)
  k_chunk1<<<dim3(NC, 12), 512, 0, stream>>>(kb16, vn, gdec, beta, Wn16, khatT16, bcum);
  k_chunk2<<<dim3(16, 12), 256, 0, stream>>>(vn, Wn16, khatT16, bcum, states, Zt);
  k_chunk3<<<dim3(NC, 12), 512, 0, stream>>>(qb16, kb16, Zt, states, bcum, fall + 3072, onorm, ovd);

  // output projection (f32 out), BN=64 -> grid 32x16 = 512 = 2.0 blocks/CU
  k_gemm_bt<64, float><<<dim3(CC / 64, M / 128), 256, 0, stream>>>(ovd, WoT, out, M, CC, VD);
}